// Round 1
// baseline (1347.370 us; speedup 1.0000x reference)
//
#include <hip/hip_runtime.h>
#include <math.h>

#define N_NODES 50000
#define HC1 256      // 4 heads * 64 ch
#define H1 4
#define C2 40
#define C2P 64       // padded
#define E0 800000
#define ET 850000
#define NEG_SLOPE 0.2f
#define EPS_A 1e-16f

// ---------------- utility ----------------

__global__ void fill_kernel(float* __restrict__ p, int n, float v) {
    int i = blockIdx.x * blockDim.x + threadIdx.x;
    if (i < n) p[i] = v;
}

__device__ inline void edge_sd(const int* __restrict__ ei, int e, int& s, int& d) {
    if (e < E0) { s = ei[e]; d = ei[E0 + e]; }
    else { s = e - E0; d = s; }  // appended self-loops
}

__device__ inline void atomic_max_float(float* addr, float val) {
    // IEEE trick: positive floats compare as ints, negative reversed as uints
    if (val >= 0.f) atomicMax((int*)addr, __float_as_int(val));
    else            atomicMin((unsigned int*)addr, (unsigned int)__float_as_int(val));
}

// ---------------- GEMM: C[M,Nc] = A[M,K] * B[K,Nc], fp32, row-major ----------------
// BM=128, BN=64, BK=16, 256 threads, 8x4 micro-tile.
#define BM 128
#define BN 64
#define BK 16

__global__ __launch_bounds__(256) void gemm_kernel(const float* __restrict__ A,
                                                   const float* __restrict__ B,
                                                   float* __restrict__ C,
                                                   int M, int Nc, int K) {
    __shared__ float As[BK][BM + 4];   // stride 132 floats (16B-aligned rows)
    __shared__ float Bs[BK][BN + 4];   // stride 68
    const int t  = threadIdx.x;
    const int bm = blockIdx.x * BM;
    const int bn = blockIdx.y * BN;
    const int tx = t & 15;             // 16 col groups of 4
    const int ty = t >> 4;             // 16 row groups of 8
    const int m0 = ty * 8;
    const int n0 = tx * 4;
    float acc[8][4] = {};

    for (int k0 = 0; k0 < K; k0 += BK) {
        // A tile: 128 rows x 16 k -> 512 float4, 2 per thread, transpose into As[k][m]
#pragma unroll
        for (int u = 0; u < 2; ++u) {
            int idx = t + u * 256;           // 0..511
            int row = idx >> 2;              // 0..127
            int kk4 = (idx & 3) * 4;
            int grow = bm + row;
            float4 v = make_float4(0.f, 0.f, 0.f, 0.f);
            if (grow < M) v = *(const float4*)(A + (size_t)grow * K + k0 + kk4);
            As[kk4 + 0][row] = v.x;
            As[kk4 + 1][row] = v.y;
            As[kk4 + 2][row] = v.z;
            As[kk4 + 3][row] = v.w;
        }
        // B tile: 16 x 64 -> 256 float4, 1 per thread
        {
            int row = t >> 4;                // 0..15
            int c4  = (t & 15) * 4;
            float4 v = *(const float4*)(B + (size_t)(k0 + row) * Nc + bn + c4);
            *(float4*)&Bs[row][c4] = v;
        }
        __syncthreads();
#pragma unroll
        for (int kk = 0; kk < BK; ++kk) {
            float a[8], b[4];
            *(float4*)&a[0] = *(const float4*)&As[kk][m0];
            *(float4*)&a[4] = *(const float4*)&As[kk][m0 + 4];
            *(float4*)&b[0] = *(const float4*)&Bs[kk][n0];
#pragma unroll
            for (int i = 0; i < 8; ++i)
#pragma unroll
                for (int j = 0; j < 4; ++j)
                    acc[i][j] += a[i] * b[j];
        }
        __syncthreads();
    }
#pragma unroll
    for (int i = 0; i < 8; ++i) {
        int grow = bm + m0 + i;
        if (grow < M)
            *(float4*)(C + (size_t)grow * Nc + bn + n0) = *(float4*)&acc[i][0];
    }
}

// ---------------- layer 1 ----------------

// one block (256 thr) per node; each 64-lane wave reduces one head's 64 channels
__global__ __launch_bounds__(256) void att_dots1_kernel(const float* __restrict__ h,
                                                        const float* __restrict__ as_,
                                                        const float* __restrict__ ad_,
                                                        float* __restrict__ a_src,
                                                        float* __restrict__ a_dst) {
    int n = blockIdx.x;
    int t = threadIdx.x;
    float hv = h[(size_t)n * HC1 + t];
    float vs = hv * as_[t];
    float vd = hv * ad_[t];
    for (int o = 32; o; o >>= 1) { vs += __shfl_down(vs, o); vd += __shfl_down(vd, o); }
    if ((t & 63) == 0) {
        int hd = t >> 6;
        a_src[n * H1 + hd] = vs;
        a_dst[n * H1 + hd] = vd;
    }
}

__global__ void edge_logits1_kernel(const int* __restrict__ ei,
                                    const float* __restrict__ a_src,
                                    const float* __restrict__ a_dst,
                                    float* __restrict__ alpha, float* __restrict__ m1) {
    int tid = blockIdx.x * blockDim.x + threadIdx.x;
    if (tid >= ET * H1) return;
    int e = tid >> 2, hd = tid & 3;
    int s, d; edge_sd(ei, e, s, d);
    float el = a_src[s * H1 + hd] + a_dst[d * H1 + hd];
    el = el > 0.f ? el : NEG_SLOPE * el;
    alpha[tid] = el;
    atomic_max_float(&m1[d * H1 + hd], el);
}

__global__ void edge_exp1_kernel(const int* __restrict__ ei,
                                 float* __restrict__ alpha,
                                 const float* __restrict__ m1,
                                 float* __restrict__ denom) {
    int tid = blockIdx.x * blockDim.x + threadIdx.x;
    if (tid >= ET * H1) return;
    int e = tid >> 2, hd = tid & 3;
    int s, d; edge_sd(ei, e, s, d);
    float a = expf(alpha[tid] - m1[d * H1 + hd]);
    alpha[tid] = a;
    atomicAdd(&denom[d * H1 + hd], a);
}

__global__ void edge_norm1_kernel(const int* __restrict__ ei,
                                  float* __restrict__ alpha,
                                  const float* __restrict__ denom) {
    int tid = blockIdx.x * blockDim.x + threadIdx.x;
    if (tid >= ET * H1) return;
    int e = tid >> 2, hd = tid & 3;
    int s, d; edge_sd(ei, e, s, d);
    alpha[tid] = alpha[tid] / (denom[d * H1 + hd] + EPS_A);
}

// block = one edge per grid-stride step: 256 threads = 256 channels (head = t>>6)
__global__ __launch_bounds__(256) void agg1_kernel(const int* __restrict__ ei,
                                                   const float* __restrict__ alpha,
                                                   const float* __restrict__ h,
                                                   float* __restrict__ out1) {
    int t = threadIdx.x;
    for (int e = blockIdx.x; e < ET; e += gridDim.x) {
        int s, d; edge_sd(ei, e, s, d);
        float al = alpha[e * H1 + (t >> 6)];
        float v = al * h[(size_t)s * HC1 + t];
        atomicAdd(&out1[(size_t)d * HC1 + t], v);
    }
}

__global__ void elu_bias_kernel(float* __restrict__ out1, const float* __restrict__ b1) {
    int tid = blockIdx.x * blockDim.x + threadIdx.x;
    if (tid >= N_NODES * HC1) return;
    float v = out1[tid] + b1[tid & 255];
    out1[tid] = v > 0.f ? v : expm1f(v);
}

// ---------------- layer 2 ----------------

__global__ void pad_w2_kernel(const float* __restrict__ W2, float* __restrict__ W2p) {
    int tid = blockIdx.x * blockDim.x + threadIdx.x;
    if (tid >= 256 * C2P) return;
    int k = tid >> 6, j = tid & 63;
    W2p[tid] = (j < C2) ? W2[k * C2 + j] : 0.f;
}

// one node per 64-lane wave (lanes >= 40 idle)
__global__ __launch_bounds__(256) void att_dots2_kernel(const float* __restrict__ h2,
                                                        const float* __restrict__ as2,
                                                        const float* __restrict__ ad2,
                                                        float* __restrict__ a_src,
                                                        float* __restrict__ a_dst) {
    int t = threadIdx.x;
    int lane = t & 63;
    int n = blockIdx.x * 4 + (t >> 6);
    float vs = 0.f, vd = 0.f;
    if (n < N_NODES && lane < C2) {
        float hv = h2[(size_t)n * C2P + lane];
        vs = hv * as2[lane];
        vd = hv * ad2[lane];
    }
    for (int o = 32; o; o >>= 1) { vs += __shfl_down(vs, o); vd += __shfl_down(vd, o); }
    if (n < N_NODES && lane == 0) { a_src[n] = vs; a_dst[n] = vd; }
}

__global__ void edge_logits2_kernel(const int* __restrict__ ei,
                                    const float* __restrict__ a_src,
                                    const float* __restrict__ a_dst,
                                    float* __restrict__ e2, float* __restrict__ m2) {
    int e = blockIdx.x * blockDim.x + threadIdx.x;
    if (e >= ET) return;
    int s, d; edge_sd(ei, e, s, d);
    float el = a_src[s] + a_dst[d];
    el = el > 0.f ? el : NEG_SLOPE * el;
    e2[e] = el;
    atomic_max_float(&m2[d], el);
}

__global__ void edge_exp2_kernel(const int* __restrict__ ei,
                                 float* __restrict__ e2,
                                 const float* __restrict__ m2,
                                 float* __restrict__ denom2) {
    int e = blockIdx.x * blockDim.x + threadIdx.x;
    if (e >= ET) return;
    int s, d; edge_sd(ei, e, s, d);
    float a = expf(e2[e] - m2[d]);
    e2[e] = a;
    atomicAdd(&denom2[d], a);
}

__global__ void agg2_kernel(const int* __restrict__ ei,
                            const float* __restrict__ e2,
                            const float* __restrict__ denom2,
                            const float* __restrict__ h2,
                            float* __restrict__ out2) {
    int stride = gridDim.x * blockDim.x;
    for (int i = blockIdx.x * blockDim.x + threadIdx.x; i < ET * 64; i += stride) {
        int e = i >> 6, c = i & 63;
        if (c >= C2) continue;
        int s, d; edge_sd(ei, e, s, d);
        float al = e2[e] / (denom2[d] + EPS_A);
        atomicAdd(&out2[(size_t)d * C2 + c], al * h2[(size_t)s * C2P + c]);
    }
}

// one node per wave: bias + log_softmax over 40 classes
__global__ __launch_bounds__(256) void lsm_kernel(const float* __restrict__ out2,
                                                  const float* __restrict__ b2,
                                                  float* __restrict__ out) {
    int t = threadIdx.x;
    int lane = t & 63;
    int n = blockIdx.x * 4 + (t >> 6);
    bool act = (n < N_NODES) && (lane < C2);
    float v = act ? out2[(size_t)n * C2 + lane] + b2[lane] : -INFINITY;
    float mx = v;
    for (int o = 32; o; o >>= 1) mx = fmaxf(mx, __shfl_xor(mx, o));
    float ex = act ? expf(v - mx) : 0.f;
    for (int o = 32; o; o >>= 1) ex += __shfl_xor(ex, o);
    if (act) out[(size_t)n * C2 + lane] = v - mx - logf(ex);
}

// ---------------- launcher ----------------

extern "C" void kernel_launch(void* const* d_in, const int* in_sizes, int n_in,
                              void* d_out, int out_size, void* d_ws, size_t ws_size,
                              hipStream_t stream) {
    const float* x   = (const float*)d_in[0];
    const int*   ei  = (const int*)d_in[1];
    const float* W1  = (const float*)d_in[2];
    const float* as1 = (const float*)d_in[3];
    const float* ad1 = (const float*)d_in[4];
    const float* b1  = (const float*)d_in[5];
    const float* W2  = (const float*)d_in[6];
    const float* as2 = (const float*)d_in[7];
    const float* ad2 = (const float*)d_in[8];
    const float* b2  = (const float*)d_in[9];

    float* out   = (float*)d_out;
    float* alpha = out + (size_t)N_NODES * C2;   // [ET, 4] final output region

    float* ws     = (float*)d_ws;
    float* h1_lin = ws;                          // 12,800,000 f (reused as h2_lin later)
    float* out1   = h1_lin + 12800000;           // 12,800,000 f
    float* out2   = out1 + 12800000;             // 2,000,000 f
    float* a_src1 = out2 + 2000000;              // 200,000 f
    float* a_dst1 = a_src1 + 200000;
    float* m1     = a_dst1 + 200000;
    float* denom1 = m1 + 200000;
    float* a_src2 = denom1 + 200000;             // 50,000 f
    float* a_dst2 = a_src2 + 50000;
    float* m2     = a_dst2 + 50000;
    float* denom2 = m2 + 50000;
    float* e2buf  = denom2 + 50000;              // 850,000 f
    float* W2p    = e2buf + 850000;              // 16,384 f
    float* h2_lin = h1_lin;                      // alias (h1_lin dead after agg1)

    const int TB = 256;
    // --- init ---
    fill_kernel<<<(200000 + TB - 1) / TB, TB, 0, stream>>>(m1, 200000, -INFINITY);
    fill_kernel<<<(200000 + TB - 1) / TB, TB, 0, stream>>>(denom1, 200000, 0.f);
    fill_kernel<<<(12800000 + TB - 1) / TB, TB, 0, stream>>>(out1, 12800000, 0.f);
    fill_kernel<<<(50000 + TB - 1) / TB, TB, 0, stream>>>(m2, 50000, -INFINITY);
    fill_kernel<<<(50000 + TB - 1) / TB, TB, 0, stream>>>(denom2, 50000, 0.f);
    fill_kernel<<<(2000000 + TB - 1) / TB, TB, 0, stream>>>(out2, 2000000, 0.f);
    pad_w2_kernel<<<(256 * C2P + TB - 1) / TB, TB, 0, stream>>>(W2, W2p);

    // --- layer 1 ---
    gemm_kernel<<<dim3((N_NODES + BM - 1) / BM, HC1 / BN), TB, 0, stream>>>(
        x, W1, h1_lin, N_NODES, HC1, 256);
    att_dots1_kernel<<<N_NODES, TB, 0, stream>>>(h1_lin, as1, ad1, a_src1, a_dst1);
    edge_logits1_kernel<<<(ET * H1 + TB - 1) / TB, TB, 0, stream>>>(ei, a_src1, a_dst1, alpha, m1);
    edge_exp1_kernel<<<(ET * H1 + TB - 1) / TB, TB, 0, stream>>>(ei, alpha, m1, denom1);
    edge_norm1_kernel<<<(ET * H1 + TB - 1) / TB, TB, 0, stream>>>(ei, alpha, denom1);
    agg1_kernel<<<8192, TB, 0, stream>>>(ei, alpha, h1_lin, out1);
    elu_bias_kernel<<<(N_NODES * HC1 + TB - 1) / TB, TB, 0, stream>>>(out1, b1);

    // --- layer 2 ---
    gemm_kernel<<<dim3((N_NODES + BM - 1) / BM, C2P / BN), TB, 0, stream>>>(
        out1, W2p, h2_lin, N_NODES, C2P, 256);
    att_dots2_kernel<<<(N_NODES + 3) / 4, TB, 0, stream>>>(h2_lin, as2, ad2, a_src2, a_dst2);
    edge_logits2_kernel<<<(ET + TB - 1) / TB, TB, 0, stream>>>(ei, a_src2, a_dst2, e2buf, m2);
    edge_exp2_kernel<<<(ET + TB - 1) / TB, TB, 0, stream>>>(ei, e2buf, m2, denom2);
    agg2_kernel<<<8192, TB, 0, stream>>>(ei, e2buf, denom2, h2_lin, out2);
    lsm_kernel<<<(N_NODES + 3) / 4, TB, 0, stream>>>(out2, b2, out);
}

// Round 2
// 888.160 us; speedup vs baseline: 1.5170x; 1.5170x over previous
//
#include <hip/hip_runtime.h>
#include <math.h>

#define N_NODES 50000
#define HC1 256      // 4 heads * 64 ch
#define H1 4
#define C2 40
#define C2P 64       // padded
#define E0 800000
#define ET 850000
#define NEG_SLOPE 0.2f
#define EPS_A 1e-16f

// ---------------- utility ----------------

__global__ void fill_int_kernel(int* __restrict__ p, int n, int v) {
    int i = blockIdx.x * blockDim.x + threadIdx.x;
    if (i < n) p[i] = v;
}

__device__ inline int edge_src(const int* __restrict__ ei, int e) {
    return (e < E0) ? ei[e] : (e - E0);
}
__device__ inline int edge_dst(const int* __restrict__ ei, int e) {
    return (e < E0) ? ei[E0 + e] : (e - E0);
}

// ---------------- CSR build (per-launch; inputs restored every call) ----------------

__global__ void hist_kernel(const int* __restrict__ ei, int* __restrict__ deg) {
    int e = blockIdx.x * blockDim.x + threadIdx.x;
    if (e >= ET) return;
    atomicAdd(&deg[edge_dst(ei, e)], 1);
}

// exclusive scan of deg[0..N_NODES) in 3 stages, B=256
__global__ __launch_bounds__(256) void scan_block_kernel(const int* __restrict__ deg,
                                                         int* __restrict__ excl,
                                                         int* __restrict__ bsum) {
    __shared__ int tmp[256];
    int t = threadIdx.x;
    int i = blockIdx.x * 256 + t;
    int v = (i < N_NODES) ? deg[i] : 0;
    tmp[t] = v;
    __syncthreads();
#pragma unroll
    for (int o = 1; o < 256; o <<= 1) {
        int x = (t >= o) ? tmp[t - o] : 0;
        __syncthreads();
        tmp[t] += x;
        __syncthreads();
    }
    if (i < N_NODES) excl[i] = tmp[t] - v;
    if (t == 255) bsum[blockIdx.x] = tmp[255];
}

#define NSCAN_B 196   // ceil(50000/256)

__global__ __launch_bounds__(256) void scan_top_kernel(int* __restrict__ bsum) {
    __shared__ int tmp[256];
    int t = threadIdx.x;
    int v = (t < NSCAN_B) ? bsum[t] : 0;
    tmp[t] = v;
    __syncthreads();
#pragma unroll
    for (int o = 1; o < 256; o <<= 1) {
        int x = (t >= o) ? tmp[t - o] : 0;
        __syncthreads();
        tmp[t] += x;
        __syncthreads();
    }
    if (t < NSCAN_B) bsum[t] = tmp[t] - v;   // exclusive
}

__global__ __launch_bounds__(256) void scan_add_kernel(int* __restrict__ offsets,
                                                       int* __restrict__ cursor,
                                                       const int* __restrict__ bsum) {
    int i = blockIdx.x * 256 + threadIdx.x;
    if (i < N_NODES) {
        int v = offsets[i] + bsum[blockIdx.x];
        offsets[i] = v;
        cursor[i] = v;
    }
    if (i == 0) offsets[N_NODES] = ET;
}

__global__ void scatter_kernel(const int* __restrict__ ei, int* __restrict__ cursor,
                               int* __restrict__ csr_e) {
    int e = blockIdx.x * blockDim.x + threadIdx.x;
    if (e >= ET) return;
    int d = edge_dst(ei, e);
    int pos = atomicAdd(&cursor[d], 1);
    csr_e[pos] = e;
}

// ---------------- GEMM: C[M,Nc] = A[M,K] * B[K,Nc], fp32, row-major ----------------
#define BM 128
#define BN 64
#define BK 16

__global__ __launch_bounds__(256) void gemm_kernel(const float* __restrict__ A,
                                                   const float* __restrict__ B,
                                                   float* __restrict__ C,
                                                   int M, int Nc, int K) {
    __shared__ float As[BK][BM + 4];
    __shared__ float Bs[BK][BN + 4];
    const int t  = threadIdx.x;
    const int bm = blockIdx.x * BM;
    const int bn = blockIdx.y * BN;
    const int tx = t & 15;
    const int ty = t >> 4;
    const int m0 = ty * 8;
    const int n0 = tx * 4;
    float acc[8][4] = {};

    for (int k0 = 0; k0 < K; k0 += BK) {
#pragma unroll
        for (int u = 0; u < 2; ++u) {
            int idx = t + u * 256;
            int row = idx >> 2;
            int kk4 = (idx & 3) * 4;
            int grow = bm + row;
            float4 v = make_float4(0.f, 0.f, 0.f, 0.f);
            if (grow < M) v = *(const float4*)(A + (size_t)grow * K + k0 + kk4);
            As[kk4 + 0][row] = v.x;
            As[kk4 + 1][row] = v.y;
            As[kk4 + 2][row] = v.z;
            As[kk4 + 3][row] = v.w;
        }
        {
            int row = t >> 4;
            int c4  = (t & 15) * 4;
            float4 v = *(const float4*)(B + (size_t)(k0 + row) * Nc + bn + c4);
            *(float4*)&Bs[row][c4] = v;
        }
        __syncthreads();
#pragma unroll
        for (int kk = 0; kk < BK; ++kk) {
            float a[8], b[4];
            *(float4*)&a[0] = *(const float4*)&As[kk][m0];
            *(float4*)&a[4] = *(const float4*)&As[kk][m0 + 4];
            *(float4*)&b[0] = *(const float4*)&Bs[kk][n0];
#pragma unroll
            for (int i = 0; i < 8; ++i)
#pragma unroll
                for (int j = 0; j < 4; ++j)
                    acc[i][j] += a[i] * b[j];
        }
        __syncthreads();
    }
#pragma unroll
    for (int i = 0; i < 8; ++i) {
        int grow = bm + m0 + i;
        if (grow < M)
            *(float4*)(C + (size_t)grow * Nc + bn + n0) = *(float4*)&acc[i][0];
    }
}

// ---------------- layer 1 ----------------

__global__ __launch_bounds__(256) void att_dots1_kernel(const float* __restrict__ h,
                                                        const float* __restrict__ as_,
                                                        const float* __restrict__ ad_,
                                                        float* __restrict__ a_src,
                                                        float* __restrict__ a_dst) {
    int n = blockIdx.x;
    int t = threadIdx.x;
    float hv = h[(size_t)n * HC1 + t];
    float vs = hv * as_[t];
    float vd = hv * ad_[t];
    for (int o = 32; o; o >>= 1) { vs += __shfl_down(vs, o); vd += __shfl_down(vd, o); }
    if ((t & 63) == 0) {
        int hd = t >> 6;
        a_src[n * H1 + hd] = vs;
        a_dst[n * H1 + hd] = vd;
    }
}

// per-dst softmax over in-edges: block = dst node, wave w = head w. No atomics.
__global__ __launch_bounds__(256) void softmax1_csr_kernel(const int* __restrict__ ei,
                                                           const int* __restrict__ off,
                                                           const int* __restrict__ csr_e,
                                                           const float* __restrict__ a_src,
                                                           const float* __restrict__ a_dst,
                                                           float* __restrict__ alpha) {
    int d = blockIdx.x;
    int t = threadIdx.x;
    int hd = t >> 6;
    int lane = t & 63;
    int beg = off[d], end = off[d + 1];
    float ad = a_dst[d * H1 + hd];

    float mx = -INFINITY;
    for (int idx = beg + lane; idx < end; idx += 64) {
        int e = csr_e[idx];
        int s = edge_src(ei, e);
        float el = a_src[s * H1 + hd] + ad;
        el = el > 0.f ? el : NEG_SLOPE * el;
        mx = fmaxf(mx, el);
    }
#pragma unroll
    for (int o = 32; o; o >>= 1) mx = fmaxf(mx, __shfl_xor(mx, o));

    float sum = 0.f;
    for (int idx = beg + lane; idx < end; idx += 64) {
        int e = csr_e[idx];
        int s = edge_src(ei, e);
        float el = a_src[s * H1 + hd] + ad;
        el = el > 0.f ? el : NEG_SLOPE * el;
        sum += expf(el - mx);
    }
#pragma unroll
    for (int o = 32; o; o >>= 1) sum += __shfl_xor(sum, o);
    float inv = 1.f / (sum + EPS_A);

    for (int idx = beg + lane; idx < end; idx += 64) {
        int e = csr_e[idx];
        int s = edge_src(ei, e);
        float el = a_src[s * H1 + hd] + ad;
        el = el > 0.f ? el : NEG_SLOPE * el;
        alpha[e * H1 + hd] = expf(el - mx) * inv;
    }
}

// gather aggregation: block = dst node, thread = channel; fused bias + ELU
__global__ __launch_bounds__(256) void agg1_csr_kernel(const int* __restrict__ ei,
                                                       const int* __restrict__ off,
                                                       const int* __restrict__ csr_e,
                                                       const float* __restrict__ alpha,
                                                       const float* __restrict__ h,
                                                       const float* __restrict__ b1,
                                                       float* __restrict__ out1) {
    int d = blockIdx.x;
    int t = threadIdx.x;
    int beg = off[d], end = off[d + 1];
    float acc = 0.f;
    for (int idx = beg; idx < end; ++idx) {
        int e = csr_e[idx];
        int s = edge_src(ei, e);
        float al = alpha[e * H1 + (t >> 6)];
        acc += al * h[(size_t)s * HC1 + t];
    }
    float v = acc + b1[t];
    out1[(size_t)d * HC1 + t] = v > 0.f ? v : expm1f(v);
}

// ---------------- layer 2 ----------------

__global__ void pad_w2_kernel(const float* __restrict__ W2, float* __restrict__ W2p) {
    int tid = blockIdx.x * blockDim.x + threadIdx.x;
    if (tid >= 256 * C2P) return;
    int k = tid >> 6, j = tid & 63;
    W2p[tid] = (j < C2) ? W2[k * C2 + j] : 0.f;
}

__global__ __launch_bounds__(256) void att_dots2_kernel(const float* __restrict__ h2,
                                                        const float* __restrict__ as2,
                                                        const float* __restrict__ ad2,
                                                        float* __restrict__ a_src,
                                                        float* __restrict__ a_dst) {
    int t = threadIdx.x;
    int lane = t & 63;
    int n = blockIdx.x * 4 + (t >> 6);
    float vs = 0.f, vd = 0.f;
    if (n < N_NODES && lane < C2) {
        float hv = h2[(size_t)n * C2P + lane];
        vs = hv * as2[lane];
        vd = hv * ad2[lane];
    }
    for (int o = 32; o; o >>= 1) { vs += __shfl_down(vs, o); vd += __shfl_down(vd, o); }
    if (n < N_NODES && lane == 0) { a_src[n] = vs; a_dst[n] = vd; }
}

// per-dst softmax (1 head): wave = dst node; writes NORMALIZED alpha into e2
__global__ __launch_bounds__(256) void softmax2_csr_kernel(const int* __restrict__ ei,
                                                           const int* __restrict__ off,
                                                           const int* __restrict__ csr_e,
                                                           const float* __restrict__ a_src,
                                                           const float* __restrict__ a_dst,
                                                           float* __restrict__ e2) {
    int t = threadIdx.x;
    int lane = t & 63;
    int d = blockIdx.x * 4 + (t >> 6);
    if (d >= N_NODES) return;
    int beg = off[d], end = off[d + 1];
    float ad = a_dst[d];

    float mx = -INFINITY;
    for (int idx = beg + lane; idx < end; idx += 64) {
        int e = csr_e[idx];
        float el = a_src[edge_src(ei, e)] + ad;
        el = el > 0.f ? el : NEG_SLOPE * el;
        mx = fmaxf(mx, el);
    }
#pragma unroll
    for (int o = 32; o; o >>= 1) mx = fmaxf(mx, __shfl_xor(mx, o));

    float sum = 0.f;
    for (int idx = beg + lane; idx < end; idx += 64) {
        int e = csr_e[idx];
        float el = a_src[edge_src(ei, e)] + ad;
        el = el > 0.f ? el : NEG_SLOPE * el;
        sum += expf(el - mx);
    }
#pragma unroll
    for (int o = 32; o; o >>= 1) sum += __shfl_xor(sum, o);
    float inv = 1.f / (sum + EPS_A);

    for (int idx = beg + lane; idx < end; idx += 64) {
        int e = csr_e[idx];
        float el = a_src[edge_src(ei, e)] + ad;
        el = el > 0.f ? el : NEG_SLOPE * el;
        e2[e] = expf(el - mx) * inv;
    }
}

// aggregation + bias + log_softmax fused: wave = dst node, lane = class
__global__ __launch_bounds__(256) void agg2_lsm_kernel(const int* __restrict__ ei,
                                                       const int* __restrict__ off,
                                                       const int* __restrict__ csr_e,
                                                       const float* __restrict__ e2,
                                                       const float* __restrict__ h2,
                                                       const float* __restrict__ b2,
                                                       float* __restrict__ out) {
    int t = threadIdx.x;
    int lane = t & 63;
    int d = blockIdx.x * 4 + (t >> 6);
    if (d >= N_NODES) return;
    int beg = off[d], end = off[d + 1];
    float acc = 0.f;
    for (int idx = beg; idx < end; ++idx) {
        int e = csr_e[idx];
        int s = edge_src(ei, e);
        acc += e2[e] * h2[(size_t)s * C2P + lane];   // cols >= C2 are zeros (padded W2)
    }
    bool act = lane < C2;
    float v = act ? acc + b2[lane] : -INFINITY;
    float mx = v;
#pragma unroll
    for (int o = 32; o; o >>= 1) mx = fmaxf(mx, __shfl_xor(mx, o));
    float ex = act ? expf(v - mx) : 0.f;
#pragma unroll
    for (int o = 32; o; o >>= 1) ex += __shfl_xor(ex, o);
    if (act) out[(size_t)d * C2 + lane] = v - mx - logf(ex);
}

// ---------------- launcher ----------------

extern "C" void kernel_launch(void* const* d_in, const int* in_sizes, int n_in,
                              void* d_out, int out_size, void* d_ws, size_t ws_size,
                              hipStream_t stream) {
    const float* x   = (const float*)d_in[0];
    const int*   ei  = (const int*)d_in[1];
    const float* W1  = (const float*)d_in[2];
    const float* as1 = (const float*)d_in[3];
    const float* ad1 = (const float*)d_in[4];
    const float* b1  = (const float*)d_in[5];
    const float* W2  = (const float*)d_in[6];
    const float* as2 = (const float*)d_in[7];
    const float* ad2 = (const float*)d_in[8];
    const float* b2  = (const float*)d_in[9];

    float* out   = (float*)d_out;
    float* alpha = out + (size_t)N_NODES * C2;   // [ET, 4] final output region

    float* ws     = (float*)d_ws;
    float* h1_lin = ws;                          // 12,800,000 f (reused as h2_lin)
    float* out1   = h1_lin + 12800000;           // 12,800,000 f
    float* a_src1 = out1 + 12800000;             // 200,000 f
    float* a_dst1 = a_src1 + 200000;             // 200,000 f
    float* a_src2 = a_dst1 + 200000;             // 50,000 f
    float* a_dst2 = a_src2 + 50000;              // 50,000 f
    float* e2buf  = a_dst2 + 50000;              // 850,000 f
    float* W2p    = e2buf + 850000;              // 16,384 f
    int*   deg    = (int*)(W2p + 16384);         // 50,000 i
    int*   offs   = deg + 50000;                 // 50,001 i
    int*   cursor = offs + 50001;                // 50,000 i
    int*   bsum   = cursor + 50000;              // 256 i
    int*   csr_e  = bsum + 256;                  // 850,000 i
    float* h2_lin = h1_lin;                      // alias (h1_lin dead after agg1)

    const int TB = 256;
    const int EB = (ET + TB - 1) / TB;

    // --- CSR build ---
    fill_int_kernel<<<(N_NODES + TB - 1) / TB, TB, 0, stream>>>(deg, N_NODES, 0);
    hist_kernel<<<EB, TB, 0, stream>>>(ei, deg);
    scan_block_kernel<<<NSCAN_B, TB, 0, stream>>>(deg, offs, bsum);
    scan_top_kernel<<<1, TB, 0, stream>>>(bsum);
    scan_add_kernel<<<NSCAN_B, TB, 0, stream>>>(offs, cursor, bsum);
    scatter_kernel<<<EB, TB, 0, stream>>>(ei, cursor, csr_e);

    pad_w2_kernel<<<(256 * C2P + TB - 1) / TB, TB, 0, stream>>>(W2, W2p);

    // --- layer 1 ---
    gemm_kernel<<<dim3((N_NODES + BM - 1) / BM, HC1 / BN), TB, 0, stream>>>(
        x, W1, h1_lin, N_NODES, HC1, 256);
    att_dots1_kernel<<<N_NODES, TB, 0, stream>>>(h1_lin, as1, ad1, a_src1, a_dst1);
    softmax1_csr_kernel<<<N_NODES, TB, 0, stream>>>(ei, offs, csr_e, a_src1, a_dst1, alpha);
    agg1_csr_kernel<<<N_NODES, TB, 0, stream>>>(ei, offs, csr_e, alpha, h1_lin, b1, out1);

    // --- layer 2 ---
    gemm_kernel<<<dim3((N_NODES + BM - 1) / BM, C2P / BN), TB, 0, stream>>>(
        out1, W2p, h2_lin, N_NODES, C2P, 256);
    att_dots2_kernel<<<(N_NODES + 3) / 4, TB, 0, stream>>>(h2_lin, as2, ad2, a_src2, a_dst2);
    softmax2_csr_kernel<<<(N_NODES + 3) / 4, TB, 0, stream>>>(ei, offs, csr_e, a_src2, a_dst2, e2buf);
    agg2_lsm_kernel<<<(N_NODES + 3) / 4, TB, 0, stream>>>(ei, offs, csr_e, e2buf, h2_lin, b2, out);
}

// Round 3
// 594.609 us; speedup vs baseline: 2.2660x; 1.4937x over previous
//
#include <hip/hip_runtime.h>
#include <math.h>

#define N_NODES 50000
#define HC1 256      // 4 heads * 64 ch
#define H1 4
#define C2 40
#define C2P 64       // padded
#define E0 800000
#define ET 850000
#define NEG_SLOPE 0.2f
#define EPS_A 1e-16f

// ---------------- utility ----------------

__global__ void fill_int_kernel(int* __restrict__ p, int n, int v) {
    int i = blockIdx.x * blockDim.x + threadIdx.x;
    if (i < n) p[i] = v;
}

__device__ inline int edge_src(const int* __restrict__ ei, int e) {
    return (e < E0) ? ei[e] : (e - E0);
}
__device__ inline int edge_dst(const int* __restrict__ ei, int e) {
    return (e < E0) ? ei[E0 + e] : (e - E0);
}

// ---------------- CSR build ----------------

__global__ void hist_kernel(const int* __restrict__ ei, int* __restrict__ deg) {
    int e = blockIdx.x * blockDim.x + threadIdx.x;
    if (e >= ET) return;
    atomicAdd(&deg[edge_dst(ei, e)], 1);
}

__global__ __launch_bounds__(256) void scan_block_kernel(const int* __restrict__ deg,
                                                         int* __restrict__ excl,
                                                         int* __restrict__ bsum) {
    __shared__ int tmp[256];
    int t = threadIdx.x;
    int i = blockIdx.x * 256 + t;
    int v = (i < N_NODES) ? deg[i] : 0;
    tmp[t] = v;
    __syncthreads();
#pragma unroll
    for (int o = 1; o < 256; o <<= 1) {
        int x = (t >= o) ? tmp[t - o] : 0;
        __syncthreads();
        tmp[t] += x;
        __syncthreads();
    }
    if (i < N_NODES) excl[i] = tmp[t] - v;
    if (t == 255) bsum[blockIdx.x] = tmp[255];
}

#define NSCAN_B 196   // ceil(50000/256)

__global__ __launch_bounds__(256) void scan_top_kernel(int* __restrict__ bsum) {
    __shared__ int tmp[256];
    int t = threadIdx.x;
    int v = (t < NSCAN_B) ? bsum[t] : 0;
    tmp[t] = v;
    __syncthreads();
#pragma unroll
    for (int o = 1; o < 256; o <<= 1) {
        int x = (t >= o) ? tmp[t - o] : 0;
        __syncthreads();
        tmp[t] += x;
        __syncthreads();
    }
    if (t < NSCAN_B) bsum[t] = tmp[t] - v;   // exclusive
}

__global__ __launch_bounds__(256) void scan_add_kernel(int* __restrict__ offsets,
                                                       int* __restrict__ cursor,
                                                       const int* __restrict__ bsum) {
    int i = blockIdx.x * 256 + threadIdx.x;
    if (i < N_NODES) {
        int v = offsets[i] + bsum[blockIdx.x];
        offsets[i] = v;
        cursor[i] = v;
    }
    if (i == 0) offsets[N_NODES] = ET;
}

// writes BOTH edge id and src id in CSR order
__global__ void scatter_kernel(const int* __restrict__ ei, int* __restrict__ cursor,
                               int* __restrict__ csr_e, int* __restrict__ csr_s) {
    int e = blockIdx.x * blockDim.x + threadIdx.x;
    if (e >= ET) return;
    int d = edge_dst(ei, e);
    int pos = atomicAdd(&cursor[d], 1);
    csr_e[pos] = e;
    csr_s[pos] = edge_src(ei, e);
}

// ---------------- GEMM: C[M,Nc] = A[M,K] * B[K,Nc], fp32, row-major ----------------
#define BM 128
#define BN 64
#define BK 16

__global__ __launch_bounds__(256) void gemm_kernel(const float* __restrict__ A,
                                                   const float* __restrict__ B,
                                                   float* __restrict__ C,
                                                   int M, int Nc, int K) {
    __shared__ float As[BK][BM + 4];
    __shared__ float Bs[BK][BN + 4];
    const int t  = threadIdx.x;
    const int bm = blockIdx.x * BM;
    const int bn = blockIdx.y * BN;
    const int tx = t & 15;
    const int ty = t >> 4;
    const int m0 = ty * 8;
    const int n0 = tx * 4;
    float acc[8][4] = {};

    for (int k0 = 0; k0 < K; k0 += BK) {
#pragma unroll
        for (int u = 0; u < 2; ++u) {
            int idx = t + u * 256;
            int row = idx >> 2;
            int kk4 = (idx & 3) * 4;
            int grow = bm + row;
            float4 v = make_float4(0.f, 0.f, 0.f, 0.f);
            if (grow < M) v = *(const float4*)(A + (size_t)grow * K + k0 + kk4);
            As[kk4 + 0][row] = v.x;
            As[kk4 + 1][row] = v.y;
            As[kk4 + 2][row] = v.z;
            As[kk4 + 3][row] = v.w;
        }
        {
            int row = t >> 4;
            int c4  = (t & 15) * 4;
            float4 v = *(const float4*)(B + (size_t)(k0 + row) * Nc + bn + c4);
            *(float4*)&Bs[row][c4] = v;
        }
        __syncthreads();
#pragma unroll
        for (int kk = 0; kk < BK; ++kk) {
            float a[8], b[4];
            *(float4*)&a[0] = *(const float4*)&As[kk][m0];
            *(float4*)&a[4] = *(const float4*)&As[kk][m0 + 4];
            *(float4*)&b[0] = *(const float4*)&Bs[kk][n0];
#pragma unroll
            for (int i = 0; i < 8; ++i)
#pragma unroll
                for (int j = 0; j < 4; ++j)
                    acc[i][j] += a[i] * b[j];
        }
        __syncthreads();
    }
#pragma unroll
    for (int i = 0; i < 8; ++i) {
        int grow = bm + m0 + i;
        if (grow < M)
            *(float4*)(C + (size_t)grow * Nc + bn + n0) = *(float4*)&acc[i][0];
    }
}

// ---------------- layer 1 ----------------

__global__ __launch_bounds__(256) void att_dots1_kernel(const float* __restrict__ h,
                                                        const float* __restrict__ as_,
                                                        const float* __restrict__ ad_,
                                                        float* __restrict__ a_src,
                                                        float* __restrict__ a_dst) {
    int n = blockIdx.x;
    int t = threadIdx.x;
    float hv = h[(size_t)n * HC1 + t];
    float vs = hv * as_[t];
    float vd = hv * ad_[t];
    for (int o = 32; o; o >>= 1) { vs += __shfl_down(vs, o); vd += __shfl_down(vd, o); }
    if ((t & 63) == 0) {
        int hd = t >> 6;
        a_src[n * H1 + hd] = vs;
        a_dst[n * H1 + hd] = vd;
    }
}

// per-dst softmax: block = dst node, wave w = head w. Writes alpha (edge order,
// required output) AND alpha_csr (CSR order, for agg1).
__global__ __launch_bounds__(256) void softmax1_csr_kernel(const int* __restrict__ off,
                                                           const int* __restrict__ csr_e,
                                                           const int* __restrict__ csr_s,
                                                           const float* __restrict__ a_src,
                                                           const float* __restrict__ a_dst,
                                                           float* __restrict__ alpha,
                                                           float* __restrict__ alpha_csr) {
    int d = blockIdx.x;
    int t = threadIdx.x;
    int hd = t >> 6;
    int lane = t & 63;
    int beg = off[d], end = off[d + 1];
    float ad = a_dst[d * H1 + hd];

    float mx = -INFINITY;
    for (int idx = beg + lane; idx < end; idx += 64) {
        int s = csr_s[idx];
        float el = a_src[s * H1 + hd] + ad;
        el = el > 0.f ? el : NEG_SLOPE * el;
        mx = fmaxf(mx, el);
    }
#pragma unroll
    for (int o = 32; o; o >>= 1) mx = fmaxf(mx, __shfl_xor(mx, o));

    float sum = 0.f;
    for (int idx = beg + lane; idx < end; idx += 64) {
        int s = csr_s[idx];
        float el = a_src[s * H1 + hd] + ad;
        el = el > 0.f ? el : NEG_SLOPE * el;
        sum += expf(el - mx);
    }
#pragma unroll
    for (int o = 32; o; o >>= 1) sum += __shfl_xor(sum, o);
    float inv = 1.f / (sum + EPS_A);

    for (int idx = beg + lane; idx < end; idx += 64) {
        int s = csr_s[idx];
        int e = csr_e[idx];
        float el = a_src[s * H1 + hd] + ad;
        el = el > 0.f ? el : NEG_SLOPE * el;
        float a = expf(el - mx) * inv;
        alpha[e * H1 + hd] = a;
        alpha_csr[idx * H1 + hd] = a;
    }
}

// gather aggregation: block = dst node, thread = channel. LDS-staged edge list,
// unrolled x4 for MLP. Fused bias + ELU.
#define CH1 64
__global__ __launch_bounds__(256) void agg1_csr_kernel(const int* __restrict__ off,
                                                       const int* __restrict__ csr_s,
                                                       const float* __restrict__ alpha_csr,
                                                       const float* __restrict__ h,
                                                       const float* __restrict__ b1,
                                                       float* __restrict__ out1) {
    __shared__ int   s_src[CH1];
    __shared__ float s_al[CH1][H1];
    int d = blockIdx.x;
    int t = threadIdx.x;
    int hd = t >> 6;
    int beg = off[d], end = off[d + 1];
    float acc = 0.f;
    for (int cb = beg; cb < end; cb += CH1) {
        int cnt = min(CH1, end - cb);
        if (t < cnt) {
            s_src[t] = csr_s[cb + t];
            *(float4*)&s_al[t][0] = *(const float4*)&alpha_csr[(cb + t) * H1];
        }
        __syncthreads();
        int j = 0;
        for (; j + 4 <= cnt; j += 4) {
            int s0 = s_src[j], s1 = s_src[j + 1], s2 = s_src[j + 2], s3 = s_src[j + 3];
            float a0 = s_al[j][hd], a1 = s_al[j + 1][hd];
            float a2 = s_al[j + 2][hd], a3 = s_al[j + 3][hd];
            float h0 = h[(size_t)s0 * HC1 + t];
            float h1v = h[(size_t)s1 * HC1 + t];
            float h2v = h[(size_t)s2 * HC1 + t];
            float h3 = h[(size_t)s3 * HC1 + t];
            acc += a0 * h0 + a1 * h1v + a2 * h2v + a3 * h3;
        }
        for (; j < cnt; ++j)
            acc += s_al[j][hd] * h[(size_t)s_src[j] * HC1 + t];
        __syncthreads();
    }
    float v = acc + b1[t];
    out1[(size_t)d * HC1 + t] = v > 0.f ? v : expm1f(v);
}

// ---------------- layer 2 ----------------

__global__ void pad_w2_kernel(const float* __restrict__ W2, float* __restrict__ W2p) {
    int tid = blockIdx.x * blockDim.x + threadIdx.x;
    if (tid >= 256 * C2P) return;
    int k = tid >> 6, j = tid & 63;
    W2p[tid] = (j < C2) ? W2[k * C2 + j] : 0.f;
}

__global__ __launch_bounds__(256) void att_dots2_kernel(const float* __restrict__ h2,
                                                        const float* __restrict__ as2,
                                                        const float* __restrict__ ad2,
                                                        float* __restrict__ a_src,
                                                        float* __restrict__ a_dst) {
    int t = threadIdx.x;
    int lane = t & 63;
    int n = blockIdx.x * 4 + (t >> 6);
    float vs = 0.f, vd = 0.f;
    if (n < N_NODES && lane < C2) {
        float hv = h2[(size_t)n * C2P + lane];
        vs = hv * as2[lane];
        vd = hv * ad2[lane];
    }
    for (int o = 32; o; o >>= 1) { vs += __shfl_down(vs, o); vd += __shfl_down(vd, o); }
    if (n < N_NODES && lane == 0) { a_src[n] = vs; a_dst[n] = vd; }
}

// per-dst softmax (1 head): wave = dst node; writes NORMALIZED alpha in CSR order
__global__ __launch_bounds__(256) void softmax2_csr_kernel(const int* __restrict__ off,
                                                           const int* __restrict__ csr_s,
                                                           const float* __restrict__ a_src,
                                                           const float* __restrict__ a_dst,
                                                           float* __restrict__ a2_csr) {
    int t = threadIdx.x;
    int lane = t & 63;
    int d = blockIdx.x * 4 + (t >> 6);
    if (d >= N_NODES) return;
    int beg = off[d], end = off[d + 1];
    float ad = a_dst[d];

    float mx = -INFINITY;
    for (int idx = beg + lane; idx < end; idx += 64) {
        float el = a_src[csr_s[idx]] + ad;
        el = el > 0.f ? el : NEG_SLOPE * el;
        mx = fmaxf(mx, el);
    }
#pragma unroll
    for (int o = 32; o; o >>= 1) mx = fmaxf(mx, __shfl_xor(mx, o));

    float sum = 0.f;
    for (int idx = beg + lane; idx < end; idx += 64) {
        float el = a_src[csr_s[idx]] + ad;
        el = el > 0.f ? el : NEG_SLOPE * el;
        sum += expf(el - mx);
    }
#pragma unroll
    for (int o = 32; o; o >>= 1) sum += __shfl_xor(sum, o);
    float inv = 1.f / (sum + EPS_A);

    for (int idx = beg + lane; idx < end; idx += 64) {
        float el = a_src[csr_s[idx]] + ad;
        el = el > 0.f ? el : NEG_SLOPE * el;
        a2_csr[idx] = expf(el - mx) * inv;
    }
}

// aggregation + bias + log_softmax fused: wave = dst, lane = class.
// Lane-parallel prefetch of (src, alpha), broadcast via __shfl, unrolled x4.
__global__ __launch_bounds__(256) void agg2_lsm_kernel(const int* __restrict__ off,
                                                       const int* __restrict__ csr_s,
                                                       const float* __restrict__ a2_csr,
                                                       const float* __restrict__ h2,
                                                       const float* __restrict__ b2,
                                                       float* __restrict__ out) {
    int t = threadIdx.x;
    int lane = t & 63;
    int d = blockIdx.x * 4 + (t >> 6);
    if (d >= N_NODES) return;
    int beg = off[d], end = off[d + 1];
    float acc = 0.f;
    for (int cb = beg; cb < end; cb += 64) {
        int cnt = min(64, end - cb);
        int my_s = 0; float my_a = 0.f;
        if (lane < cnt) {
            my_s = csr_s[cb + lane];
            my_a = a2_csr[cb + lane];
        }
        int j = 0;
        for (; j + 4 <= cnt; j += 4) {
            int s0 = __shfl(my_s, j), s1 = __shfl(my_s, j + 1);
            int s2 = __shfl(my_s, j + 2), s3 = __shfl(my_s, j + 3);
            float a0 = __shfl(my_a, j), a1 = __shfl(my_a, j + 1);
            float a2 = __shfl(my_a, j + 2), a3 = __shfl(my_a, j + 3);
            float h0 = h2[(size_t)s0 * C2P + lane];
            float h1v = h2[(size_t)s1 * C2P + lane];
            float h2v = h2[(size_t)s2 * C2P + lane];
            float h3 = h2[(size_t)s3 * C2P + lane];
            acc += a0 * h0 + a1 * h1v + a2 * h2v + a3 * h3;
        }
        for (; j < cnt; ++j)
            acc += __shfl(my_a, j) * h2[(size_t)__shfl(my_s, j) * C2P + lane];
    }
    bool act = lane < C2;
    float v = act ? acc + b2[lane] : -INFINITY;
    float mx = v;
#pragma unroll
    for (int o = 32; o; o >>= 1) mx = fmaxf(mx, __shfl_xor(mx, o));
    float ex = act ? expf(v - mx) : 0.f;
#pragma unroll
    for (int o = 32; o; o >>= 1) ex += __shfl_xor(ex, o);
    if (act) out[(size_t)d * C2 + lane] = v - mx - logf(ex);
}

// ---------------- launcher ----------------

extern "C" void kernel_launch(void* const* d_in, const int* in_sizes, int n_in,
                              void* d_out, int out_size, void* d_ws, size_t ws_size,
                              hipStream_t stream) {
    const float* x   = (const float*)d_in[0];
    const int*   ei  = (const int*)d_in[1];
    const float* W1  = (const float*)d_in[2];
    const float* as1 = (const float*)d_in[3];
    const float* ad1 = (const float*)d_in[4];
    const float* b1  = (const float*)d_in[5];
    const float* W2  = (const float*)d_in[6];
    const float* as2 = (const float*)d_in[7];
    const float* ad2 = (const float*)d_in[8];
    const float* b2  = (const float*)d_in[9];

    float* out   = (float*)d_out;
    float* alpha = out + (size_t)N_NODES * C2;   // [ET, 4] final output region

    float* ws      = (float*)d_ws;
    float* h1_lin  = ws;                          // 12,800,000 f (reused as h2_lin)
    float* out1    = h1_lin + 12800000;           // 12,800,000 f
    float* a_src1  = out1 + 12800000;             // 200,000 f
    float* a_dst1  = a_src1 + 200000;             // 200,000 f
    float* a_src2  = a_dst1 + 200000;             // 50,000 f
    float* a_dst2  = a_src2 + 50000;              // 50,000 f
    float* al1_csr = a_dst2 + 50000;              // 3,400,000 f
    float* a2_csr  = al1_csr + 3400000;           // 850,000 f
    float* W2p     = a2_csr + 850000;             // 16,384 f
    int*   deg     = (int*)(W2p + 16384);         // 50,000 i
    int*   offs    = deg + 50000;                 // 50,001 i
    int*   cursor  = offs + 50001;                // 50,000 i
    int*   bsum    = cursor + 50000;              // 256 i
    int*   csr_e   = bsum + 256;                  // 850,000 i
    int*   csr_s   = csr_e + 850000;              // 850,000 i
    float* h2_lin  = h1_lin;                      // alias (h1_lin dead after agg1)

    const int TB = 256;
    const int EB = (ET + TB - 1) / TB;

    // --- CSR build ---
    fill_int_kernel<<<(N_NODES + TB - 1) / TB, TB, 0, stream>>>(deg, N_NODES, 0);
    hist_kernel<<<EB, TB, 0, stream>>>(ei, deg);
    scan_block_kernel<<<NSCAN_B, TB, 0, stream>>>(deg, offs, bsum);
    scan_top_kernel<<<1, TB, 0, stream>>>(bsum);
    scan_add_kernel<<<NSCAN_B, TB, 0, stream>>>(offs, cursor, bsum);
    scatter_kernel<<<EB, TB, 0, stream>>>(ei, cursor, csr_e, csr_s);

    pad_w2_kernel<<<(256 * C2P + TB - 1) / TB, TB, 0, stream>>>(W2, W2p);

    // --- layer 1 ---
    gemm_kernel<<<dim3((N_NODES + BM - 1) / BM, HC1 / BN), TB, 0, stream>>>(
        x, W1, h1_lin, N_NODES, HC1, 256);
    att_dots1_kernel<<<N_NODES, TB, 0, stream>>>(h1_lin, as1, ad1, a_src1, a_dst1);
    softmax1_csr_kernel<<<N_NODES, TB, 0, stream>>>(offs, csr_e, csr_s, a_src1, a_dst1,
                                                    alpha, al1_csr);
    agg1_csr_kernel<<<N_NODES, TB, 0, stream>>>(offs, csr_s, al1_csr, h1_lin, b1, out1);

    // --- layer 2 ---
    gemm_kernel<<<dim3((N_NODES + BM - 1) / BM, C2P / BN), TB, 0, stream>>>(
        out1, W2p, h2_lin, N_NODES, C2P, 256);
    att_dots2_kernel<<<(N_NODES + 3) / 4, TB, 0, stream>>>(h2_lin, as2, ad2, a_src2, a_dst2);
    softmax2_csr_kernel<<<(N_NODES + 3) / 4, TB, 0, stream>>>(offs, csr_s, a_src2, a_dst2, a2_csr);
    agg2_lsm_kernel<<<(N_NODES + 3) / 4, TB, 0, stream>>>(offs, csr_s, a2_csr, h2_lin, b2, out);
}

// Round 4
// 550.965 us; speedup vs baseline: 2.4455x; 1.0792x over previous
//
#include <hip/hip_runtime.h>
#include <math.h>

#define N_NODES 50000
#define HC1 256      // 4 heads * 64 ch
#define H1 4
#define C2 40
#define C2P 64       // padded
#define E0 800000
#define ET 850000
#define NEG_SLOPE 0.2f
#define EPS_A 1e-16f

// ---------------- bf16 helpers (OCP bf16 = top 16 bits of fp32, RNE) ----------------

__device__ inline unsigned short f2bf(float f) {
    unsigned u = __float_as_uint(f);
    return (unsigned short)((u + 0x7FFFu + ((u >> 16) & 1u)) >> 16);
}
__device__ inline float bf2f(unsigned short h) { return __uint_as_float(((unsigned)h) << 16); }
__device__ inline float bf_lo(unsigned q) { return __uint_as_float(q << 16); }
__device__ inline float bf_hi(unsigned q) { return __uint_as_float(q & 0xFFFF0000u); }

// ---------------- utility ----------------

__global__ void fill_int_kernel(int* __restrict__ p, int n, int v) {
    int i = blockIdx.x * blockDim.x + threadIdx.x;
    if (i < n) p[i] = v;
}

__device__ inline int edge_src(const int* __restrict__ ei, int e) {
    return (e < E0) ? ei[e] : (e - E0);
}
__device__ inline int edge_dst(const int* __restrict__ ei, int e) {
    return (e < E0) ? ei[E0 + e] : (e - E0);
}

// ---------------- CSR build ----------------

__global__ void hist_kernel(const int* __restrict__ ei, int* __restrict__ deg) {
    int e = blockIdx.x * blockDim.x + threadIdx.x;
    if (e >= ET) return;
    atomicAdd(&deg[edge_dst(ei, e)], 1);
}

__global__ __launch_bounds__(256) void scan_block_kernel(const int* __restrict__ deg,
                                                         int* __restrict__ excl,
                                                         int* __restrict__ bsum) {
    __shared__ int tmp[256];
    int t = threadIdx.x;
    int i = blockIdx.x * 256 + t;
    int v = (i < N_NODES) ? deg[i] : 0;
    tmp[t] = v;
    __syncthreads();
#pragma unroll
    for (int o = 1; o < 256; o <<= 1) {
        int x = (t >= o) ? tmp[t - o] : 0;
        __syncthreads();
        tmp[t] += x;
        __syncthreads();
    }
    if (i < N_NODES) excl[i] = tmp[t] - v;
    if (t == 255) bsum[blockIdx.x] = tmp[255];
}

#define NSCAN_B 196   // ceil(50000/256)

__global__ __launch_bounds__(256) void scan_top_kernel(int* __restrict__ bsum) {
    __shared__ int tmp[256];
    int t = threadIdx.x;
    int v = (t < NSCAN_B) ? bsum[t] : 0;
    tmp[t] = v;
    __syncthreads();
#pragma unroll
    for (int o = 1; o < 256; o <<= 1) {
        int x = (t >= o) ? tmp[t - o] : 0;
        __syncthreads();
        tmp[t] += x;
        __syncthreads();
    }
    if (t < NSCAN_B) bsum[t] = tmp[t] - v;   // exclusive
}

__global__ __launch_bounds__(256) void scan_add_kernel(int* __restrict__ offsets,
                                                       int* __restrict__ cursor,
                                                       const int* __restrict__ bsum) {
    int i = blockIdx.x * 256 + threadIdx.x;
    if (i < N_NODES) {
        int v = offsets[i] + bsum[blockIdx.x];
        offsets[i] = v;
        cursor[i] = v;
    }
    if (i == 0) offsets[N_NODES] = ET;
}

__global__ void scatter_kernel(const int* __restrict__ ei, int* __restrict__ cursor,
                               int* __restrict__ csr_e, int* __restrict__ csr_s) {
    int e = blockIdx.x * blockDim.x + threadIdx.x;
    if (e >= ET) return;
    int d = edge_dst(ei, e);
    int pos = atomicAdd(&cursor[d], 1);
    csr_e[pos] = e;
    csr_s[pos] = edge_src(ei, e);
}

// ---------------- GEMM: Cbf[M,Nc] = bf16(A[M,K] * B[K,Nc]), fp32 inputs ----------------
#define BM 128
#define BN 64
#define BK 16

__global__ __launch_bounds__(256) void gemm_bf_kernel(const float* __restrict__ A,
                                                      const float* __restrict__ B,
                                                      unsigned short* __restrict__ Cbf,
                                                      int M, int Nc, int K) {
    __shared__ float As[BK][BM + 4];
    __shared__ float Bs[BK][BN + 4];
    const int t  = threadIdx.x;
    const int bm = blockIdx.x * BM;
    const int bn = blockIdx.y * BN;
    const int tx = t & 15;
    const int ty = t >> 4;
    const int m0 = ty * 8;
    const int n0 = tx * 4;
    float acc[8][4] = {};

    for (int k0 = 0; k0 < K; k0 += BK) {
#pragma unroll
        for (int u = 0; u < 2; ++u) {
            int idx = t + u * 256;
            int row = idx >> 2;
            int kk4 = (idx & 3) * 4;
            int grow = bm + row;
            float4 v = make_float4(0.f, 0.f, 0.f, 0.f);
            if (grow < M) v = *(const float4*)(A + (size_t)grow * K + k0 + kk4);
            As[kk4 + 0][row] = v.x;
            As[kk4 + 1][row] = v.y;
            As[kk4 + 2][row] = v.z;
            As[kk4 + 3][row] = v.w;
        }
        {
            int row = t >> 4;
            int c4  = (t & 15) * 4;
            float4 v = *(const float4*)(B + (size_t)(k0 + row) * Nc + bn + c4);
            *(float4*)&Bs[row][c4] = v;
        }
        __syncthreads();
#pragma unroll
        for (int kk = 0; kk < BK; ++kk) {
            float a[8], b[4];
            *(float4*)&a[0] = *(const float4*)&As[kk][m0];
            *(float4*)&a[4] = *(const float4*)&As[kk][m0 + 4];
            *(float4*)&b[0] = *(const float4*)&Bs[kk][n0];
#pragma unroll
            for (int i = 0; i < 8; ++i)
#pragma unroll
                for (int j = 0; j < 4; ++j)
                    acc[i][j] += a[i] * b[j];
        }
        __syncthreads();
    }
#pragma unroll
    for (int i = 0; i < 8; ++i) {
        int grow = bm + m0 + i;
        if (grow < M) {
            ushort4 w;
            w.x = f2bf(acc[i][0]); w.y = f2bf(acc[i][1]);
            w.z = f2bf(acc[i][2]); w.w = f2bf(acc[i][3]);
            *(ushort4*)(Cbf + (size_t)grow * Nc + bn + n0) = w;
        }
    }
}

// ---------------- layer 1 ----------------

__global__ __launch_bounds__(256) void att_dots1_kernel(const unsigned short* __restrict__ h1bf,
                                                        const float* __restrict__ as_,
                                                        const float* __restrict__ ad_,
                                                        float* __restrict__ a_src,
                                                        float* __restrict__ a_dst) {
    int n = blockIdx.x;
    int t = threadIdx.x;
    float hv = bf2f(h1bf[(size_t)n * HC1 + t]);
    float vs = hv * as_[t];
    float vd = hv * ad_[t];
    for (int o = 32; o; o >>= 1) { vs += __shfl_down(vs, o); vd += __shfl_down(vd, o); }
    if ((t & 63) == 0) {
        int hd = t >> 6;
        a_src[n * H1 + hd] = vs;
        a_dst[n * H1 + hd] = vd;
    }
}

// per-dst softmax: block = dst, wave w = head w. Register-caches logits (1 gather pass
// for deg<=256; recompute fallback beyond). Writes alpha (edge order) + alpha_csr.
#define ELC 4
__global__ __launch_bounds__(256) void softmax1_csr_kernel(const int* __restrict__ off,
                                                           const int* __restrict__ csr_e,
                                                           const int* __restrict__ csr_s,
                                                           const float* __restrict__ a_src,
                                                           const float* __restrict__ a_dst,
                                                           float* __restrict__ alpha,
                                                           float* __restrict__ alpha_csr) {
    int d = blockIdx.x;
    int t = threadIdx.x;
    int hd = t >> 6;
    int lane = t & 63;
    int beg = off[d], end = off[d + 1];
    float ad = a_dst[d * H1 + hd];

    float elc[ELC];
    float mx = -INFINITY;
    int c = 0;
    for (int idx = beg + lane; idx < end; idx += 64, ++c) {
        int s = csr_s[idx];
        float el = a_src[s * H1 + hd] + ad;
        el = el > 0.f ? el : NEG_SLOPE * el;
        if (c < ELC) elc[c] = el;
        mx = fmaxf(mx, el);
    }
#pragma unroll
    for (int o = 32; o; o >>= 1) mx = fmaxf(mx, __shfl_xor(mx, o));

    float sum = 0.f;
    c = 0;
    for (int idx = beg + lane; idx < end; idx += 64, ++c) {
        float el;
        if (c < ELC) el = elc[c];
        else {
            el = a_src[csr_s[idx] * H1 + hd] + ad;
            el = el > 0.f ? el : NEG_SLOPE * el;
        }
        sum += expf(el - mx);
    }
#pragma unroll
    for (int o = 32; o; o >>= 1) sum += __shfl_xor(sum, o);
    float inv = 1.f / (sum + EPS_A);

    c = 0;
    for (int idx = beg + lane; idx < end; idx += 64, ++c) {
        float el;
        if (c < ELC) el = elc[c];
        else {
            el = a_src[csr_s[idx] * H1 + hd] + ad;
            el = el > 0.f ? el : NEG_SLOPE * el;
        }
        float a = expf(el - mx) * inv;
        alpha[csr_e[idx] * H1 + hd] = a;
        alpha_csr[(size_t)idx * H1 + hd] = a;
    }
}

// gather aggregation from bf16 h1: block = 128 thr = one dst, thread t handles
// channels 2t,2t+1 via one packed uint load (4 B/lane coalesced). Fused bias+ELU.
#define CH1 64
__global__ __launch_bounds__(128) void agg1_csr_kernel(const int* __restrict__ off,
                                                       const int* __restrict__ csr_s,
                                                       const float* __restrict__ alpha_csr,
                                                       const unsigned* __restrict__ h1bf,
                                                       const float* __restrict__ b1,
                                                       float* __restrict__ out1) {
    __shared__ int   s_src[CH1];
    __shared__ float s_al[CH1][H1];
    int d = blockIdx.x;
    int t = threadIdx.x;              // 0..127
    int head = t >> 5;                // channel 2t -> head (2t)>>6 = t>>5
    int beg = off[d], end = off[d + 1];
    float acc0 = 0.f, acc1 = 0.f;
    for (int cb = beg; cb < end; cb += CH1) {
        int cnt = min(CH1, end - cb);
        __syncthreads();
        if (t < cnt) {
            s_src[t] = csr_s[cb + t];
            *(float4*)&s_al[t][0] = *(const float4*)&alpha_csr[(size_t)(cb + t) * H1];
        }
        __syncthreads();
        int j = 0;
        for (; j + 4 <= cnt; j += 4) {
            int s0 = s_src[j], s1 = s_src[j + 1], s2 = s_src[j + 2], s3 = s_src[j + 3];
            float a0 = s_al[j][head], a1 = s_al[j + 1][head];
            float a2 = s_al[j + 2][head], a3 = s_al[j + 3][head];
            unsigned q0 = h1bf[(size_t)s0 * 128 + t];
            unsigned q1 = h1bf[(size_t)s1 * 128 + t];
            unsigned q2 = h1bf[(size_t)s2 * 128 + t];
            unsigned q3 = h1bf[(size_t)s3 * 128 + t];
            acc0 += a0 * bf_lo(q0) + a1 * bf_lo(q1) + a2 * bf_lo(q2) + a3 * bf_lo(q3);
            acc1 += a0 * bf_hi(q0) + a1 * bf_hi(q1) + a2 * bf_hi(q2) + a3 * bf_hi(q3);
        }
        for (; j < cnt; ++j) {
            unsigned q = h1bf[(size_t)s_src[j] * 128 + t];
            float a = s_al[j][head];
            acc0 += a * bf_lo(q);
            acc1 += a * bf_hi(q);
        }
    }
    float2 bb = *(const float2*)&b1[2 * t];
    float v0 = acc0 + bb.x, v1 = acc1 + bb.y;
    v0 = v0 > 0.f ? v0 : expm1f(v0);
    v1 = v1 > 0.f ? v1 : expm1f(v1);
    *(float2*)&out1[(size_t)d * HC1 + 2 * t] = make_float2(v0, v1);
}

// ---------------- layer 2 ----------------

__global__ void pad_w2_kernel(const float* __restrict__ W2, float* __restrict__ W2p) {
    int tid = blockIdx.x * blockDim.x + threadIdx.x;
    if (tid >= 256 * C2P) return;
    int k = tid >> 6, j = tid & 63;
    W2p[tid] = (j < C2) ? W2[k * C2 + j] : 0.f;
}

__global__ __launch_bounds__(256) void att_dots2_kernel(const unsigned short* __restrict__ h2bf,
                                                        const float* __restrict__ as2,
                                                        const float* __restrict__ ad2,
                                                        float* __restrict__ a_src,
                                                        float* __restrict__ a_dst) {
    int t = threadIdx.x;
    int lane = t & 63;
    int n = blockIdx.x * 4 + (t >> 6);
    float vs = 0.f, vd = 0.f;
    if (n < N_NODES && lane < C2) {
        float hv = bf2f(h2bf[(size_t)n * C2P + lane]);
        vs = hv * as2[lane];
        vd = hv * ad2[lane];
    }
    for (int o = 32; o; o >>= 1) { vs += __shfl_down(vs, o); vd += __shfl_down(vd, o); }
    if (n < N_NODES && lane == 0) { a_src[n] = vs; a_dst[n] = vd; }
}

__global__ __launch_bounds__(256) void softmax2_csr_kernel(const int* __restrict__ off,
                                                           const int* __restrict__ csr_s,
                                                           const float* __restrict__ a_src,
                                                           const float* __restrict__ a_dst,
                                                           float* __restrict__ a2_csr) {
    int t = threadIdx.x;
    int lane = t & 63;
    int d = blockIdx.x * 4 + (t >> 6);
    if (d >= N_NODES) return;
    int beg = off[d], end = off[d + 1];
    float ad = a_dst[d];

    float elc[ELC];
    float mx = -INFINITY;
    int c = 0;
    for (int idx = beg + lane; idx < end; idx += 64, ++c) {
        float el = a_src[csr_s[idx]] + ad;
        el = el > 0.f ? el : NEG_SLOPE * el;
        if (c < ELC) elc[c] = el;
        mx = fmaxf(mx, el);
    }
#pragma unroll
    for (int o = 32; o; o >>= 1) mx = fmaxf(mx, __shfl_xor(mx, o));

    float sum = 0.f;
    c = 0;
    for (int idx = beg + lane; idx < end; idx += 64, ++c) {
        float el;
        if (c < ELC) el = elc[c];
        else {
            el = a_src[csr_s[idx]] + ad;
            el = el > 0.f ? el : NEG_SLOPE * el;
        }
        sum += expf(el - mx);
    }
#pragma unroll
    for (int o = 32; o; o >>= 1) sum += __shfl_xor(sum, o);
    float inv = 1.f / (sum + EPS_A);

    c = 0;
    for (int idx = beg + lane; idx < end; idx += 64, ++c) {
        float el;
        if (c < ELC) el = elc[c];
        else {
            el = a_src[csr_s[idx]] + ad;
            el = el > 0.f ? el : NEG_SLOPE * el;
        }
        a2_csr[idx] = expf(el - mx) * inv;
    }
}

// aggregation + bias + log_softmax fused, bf16 gathers: wave = dst.
// Half-wave h (lane>>5) handles edge j+h; lane li=lane&31 handles channels 2li,2li+1
// via one packed uint (4 B/lane). Halves combined by shfl_xor(32) at the end.
__global__ __launch_bounds__(256) void agg2_lsm_kernel(const int* __restrict__ off,
                                                       const int* __restrict__ csr_s,
                                                       const float* __restrict__ a2_csr,
                                                       const unsigned* __restrict__ h2bf,
                                                       const float* __restrict__ b2,
                                                       float* __restrict__ out) {
    int t = threadIdx.x;
    int lane = t & 63;
    int half = lane >> 5;
    int li = lane & 31;
    int d = blockIdx.x * 4 + (t >> 6);
    if (d >= N_NODES) return;
    int beg = off[d], end = off[d + 1];
    float acc0 = 0.f, acc1 = 0.f;
    for (int cb = beg; cb < end; cb += 64) {
        int cnt = min(64, end - cb);
        int my_s = 0; float my_a = 0.f;
        if (lane < cnt) {
            my_s = csr_s[cb + lane];
            my_a = a2_csr[cb + lane];
        }
        for (int j = 0; j < cnt; j += 2) {
            int jj = j + half;
            int s = __shfl(my_s, jj);
            float a = __shfl(my_a, jj);
            if (jj < cnt) {
                unsigned q = h2bf[(size_t)s * 32 + li];
                acc0 += a * bf_lo(q);
                acc1 += a * bf_hi(q);
            }
        }
    }
    acc0 += __shfl_xor(acc0, 32);
    acc1 += __shfl_xor(acc1, 32);
    // classes 2li, 2li+1 valid iff li < 20
    bool act = li < 20;
    float v0 = act ? acc0 + b2[2 * li]     : -INFINITY;
    float v1 = act ? acc1 + b2[2 * li + 1] : -INFINITY;
    float mx = fmaxf(v0, v1);
#pragma unroll
    for (int o = 16; o; o >>= 1) mx = fmaxf(mx, __shfl_xor(mx, o));
    float ex = act ? expf(v0 - mx) + expf(v1 - mx) : 0.f;
#pragma unroll
    for (int o = 16; o; o >>= 1) ex += __shfl_xor(ex, o);
    float ls = logf(ex);
    if (act && half == 0)
        *(float2*)&out[(size_t)d * C2 + 2 * li] = make_float2(v0 - mx - ls, v1 - mx - ls);
}

// ---------------- launcher ----------------

extern "C" void kernel_launch(void* const* d_in, const int* in_sizes, int n_in,
                              void* d_out, int out_size, void* d_ws, size_t ws_size,
                              hipStream_t stream) {
    const float* x   = (const float*)d_in[0];
    const int*   ei  = (const int*)d_in[1];
    const float* W1  = (const float*)d_in[2];
    const float* as1 = (const float*)d_in[3];
    const float* ad1 = (const float*)d_in[4];
    const float* b1  = (const float*)d_in[5];
    const float* W2  = (const float*)d_in[6];
    const float* as2 = (const float*)d_in[7];
    const float* ad2 = (const float*)d_in[8];
    const float* b2  = (const float*)d_in[9];

    float* out   = (float*)d_out;
    float* alpha = out + (size_t)N_NODES * C2;   // [ET, 4] final output region

    float* ws      = (float*)d_ws;
    float* out1    = ws;                          // 12,800,000 f
    float* a_src1  = out1 + 12800000;             // 200,000 f
    float* a_dst1  = a_src1 + 200000;             // 200,000 f
    float* a_src2  = a_dst1 + 200000;             // 50,000 f
    float* a_dst2  = a_src2 + 50000;              // 50,000 f
    float* al1_csr = a_dst2 + 50000;              // 3,400,000 f
    float* a2_csr  = al1_csr + 3400000;           // 850,000 f
    float* W2p     = a2_csr + 850000;             // 16,384 f
    unsigned* h1bf = (unsigned*)(W2p + 16384);    // 6,400,000 u (50000x256 bf16)
    unsigned* h2bf = h1bf + 6400000;              // 1,600,000 u (50000x64 bf16)
    int*   deg     = (int*)(h2bf + 1600000);      // 50,000 i
    int*   offs    = deg + 50000;                 // 50,001 i
    int*   cursor  = offs + 50001;                // 50,000 i
    int*   bsum    = cursor + 50000;              // 256 i
    int*   csr_e   = bsum + 256;                  // 850,000 i
    int*   csr_s   = csr_e + 850000;              // 850,000 i

    const int TB = 256;
    const int EB = (ET + TB - 1) / TB;

    // --- CSR build ---
    fill_int_kernel<<<(N_NODES + TB - 1) / TB, TB, 0, stream>>>(deg, N_NODES, 0);
    hist_kernel<<<EB, TB, 0, stream>>>(ei, deg);
    scan_block_kernel<<<NSCAN_B, TB, 0, stream>>>(deg, offs, bsum);
    scan_top_kernel<<<1, TB, 0, stream>>>(bsum);
    scan_add_kernel<<<NSCAN_B, TB, 0, stream>>>(offs, cursor, bsum);
    scatter_kernel<<<EB, TB, 0, stream>>>(ei, cursor, csr_e, csr_s);

    pad_w2_kernel<<<(256 * C2P + TB - 1) / TB, TB, 0, stream>>>(W2, W2p);

    // --- layer 1 ---
    gemm_bf_kernel<<<dim3((N_NODES + BM - 1) / BM, HC1 / BN), TB, 0, stream>>>(
        x, W1, (unsigned short*)h1bf, N_NODES, HC1, 256);
    att_dots1_kernel<<<N_NODES, TB, 0, stream>>>((const unsigned short*)h1bf, as1, ad1,
                                                 a_src1, a_dst1);
    softmax1_csr_kernel<<<N_NODES, TB, 0, stream>>>(offs, csr_e, csr_s, a_src1, a_dst1,
                                                    alpha, al1_csr);
    agg1_csr_kernel<<<N_NODES, 128, 0, stream>>>(offs, csr_s, al1_csr, h1bf, b1, out1);

    // --- layer 2 ---
    gemm_bf_kernel<<<dim3((N_NODES + BM - 1) / BM, C2P / BN), TB, 0, stream>>>(
        out1, W2p, (unsigned short*)h2bf, N_NODES, C2P, 256);
    att_dots2_kernel<<<(N_NODES + 3) / 4, TB, 0, stream>>>((const unsigned short*)h2bf,
                                                           as2, ad2, a_src2, a_dst2);
    softmax2_csr_kernel<<<(N_NODES + 3) / 4, TB, 0, stream>>>(offs, csr_s, a_src2, a_dst2, a2_csr);
    agg2_lsm_kernel<<<(N_NODES + 3) / 4, TB, 0, stream>>>(offs, csr_s, a2_csr, h2bf, b2, out);
}

// Round 5
// 453.339 us; speedup vs baseline: 2.9721x; 1.2154x over previous
//
#include <hip/hip_runtime.h>
#include <math.h>

#define N_NODES 50000
#define HC1 256      // 4 heads * 64 ch
#define H1 4
#define C2 40
#define C2P 64       // padded
#define E0 800000
#define ET 850000
#define NEG_SLOPE 0.2f
#define EPS_A 1e-16f

typedef __bf16 bf16x8 __attribute__((ext_vector_type(8)));
typedef float f32x4 __attribute__((ext_vector_type(4)));
typedef unsigned short u16x8 __attribute__((ext_vector_type(8)));

// ---------------- bf16 helpers (RNE) ----------------

__device__ inline unsigned short f2bf(float f) {
    unsigned u = __float_as_uint(f);
    return (unsigned short)((u + 0x7FFFu + ((u >> 16) & 1u)) >> 16);
}
__device__ inline float bf2f(unsigned short h) { return __uint_as_float(((unsigned)h) << 16); }
__device__ inline float bf_lo(unsigned q) { return __uint_as_float(q << 16); }
__device__ inline float bf_hi(unsigned q) { return __uint_as_float(q & 0xFFFF0000u); }

// ---------------- utility ----------------

__global__ void fill_int_kernel(int* __restrict__ p, int n, int v) {
    int i = blockIdx.x * blockDim.x + threadIdx.x;
    if (i < n) p[i] = v;
}

__device__ inline int edge_src(const int* __restrict__ ei, int e) {
    return (e < E0) ? ei[e] : (e - E0);
}
__device__ inline int edge_dst(const int* __restrict__ ei, int e) {
    return (e < E0) ? ei[E0 + e] : (e - E0);
}

// ---------------- converts ----------------

__global__ void f32_to_bf16_kernel(const float* __restrict__ src,
                                   unsigned short* __restrict__ dst, int n4) {
    int i = blockIdx.x * blockDim.x + threadIdx.x;
    if (i >= n4) return;
    float4 v = ((const float4*)src)[i];
    ushort4 w;
    w.x = f2bf(v.x); w.y = f2bf(v.y); w.z = f2bf(v.z); w.w = f2bf(v.w);
    ((ushort4*)dst)[i] = w;
}

// W1 [256][256] -> W1t bf16 [n][k]
__global__ void w1_transpose_kernel(const float* __restrict__ W1,
                                    unsigned short* __restrict__ Wt) {
    int tid = blockIdx.x * blockDim.x + threadIdx.x;
    if (tid >= 256 * 256) return;
    int n = tid >> 8, k = tid & 255;
    Wt[tid] = f2bf(W1[k * 256 + n]);
}

// W2 [256][40] -> W2t bf16 [64][256], rows >= 40 zero
__global__ void w2_transpose_pad_kernel(const float* __restrict__ W2,
                                        unsigned short* __restrict__ Wt) {
    int tid = blockIdx.x * blockDim.x + threadIdx.x;
    if (tid >= 64 * 256) return;
    int n = tid >> 8, k = tid & 255;
    Wt[tid] = (n < C2) ? f2bf(W2[k * C2 + n]) : (unsigned short)0;
}

// ---------------- CSR build ----------------

__global__ void hist_kernel(const int* __restrict__ ei, int* __restrict__ deg) {
    int e = blockIdx.x * blockDim.x + threadIdx.x;
    if (e >= ET) return;
    atomicAdd(&deg[edge_dst(ei, e)], 1);
}

__global__ __launch_bounds__(256) void scan_block_kernel(const int* __restrict__ deg,
                                                         int* __restrict__ excl,
                                                         int* __restrict__ bsum) {
    __shared__ int tmp[256];
    int t = threadIdx.x;
    int i = blockIdx.x * 256 + t;
    int v = (i < N_NODES) ? deg[i] : 0;
    tmp[t] = v;
    __syncthreads();
#pragma unroll
    for (int o = 1; o < 256; o <<= 1) {
        int x = (t >= o) ? tmp[t - o] : 0;
        __syncthreads();
        tmp[t] += x;
        __syncthreads();
    }
    if (i < N_NODES) excl[i] = tmp[t] - v;
    if (t == 255) bsum[blockIdx.x] = tmp[255];
}

#define NSCAN_B 196   // ceil(50000/256)

__global__ __launch_bounds__(256) void scan_top_kernel(int* __restrict__ bsum) {
    __shared__ int tmp[256];
    int t = threadIdx.x;
    int v = (t < NSCAN_B) ? bsum[t] : 0;
    tmp[t] = v;
    __syncthreads();
#pragma unroll
    for (int o = 1; o < 256; o <<= 1) {
        int x = (t >= o) ? tmp[t - o] : 0;
        __syncthreads();
        tmp[t] += x;
        __syncthreads();
    }
    if (t < NSCAN_B) bsum[t] = tmp[t] - v;   // exclusive
}

__global__ __launch_bounds__(256) void scan_add_kernel(int* __restrict__ offsets,
                                                       int* __restrict__ cursor,
                                                       const int* __restrict__ bsum) {
    int i = blockIdx.x * 256 + threadIdx.x;
    if (i < N_NODES) {
        int v = offsets[i] + bsum[blockIdx.x];
        offsets[i] = v;
        cursor[i] = v;
    }
    if (i == 0) offsets[N_NODES] = ET;
}

__global__ void scatter_kernel(const int* __restrict__ ei, int* __restrict__ cursor,
                               int* __restrict__ csr_e, int* __restrict__ csr_s) {
    int e = blockIdx.x * blockDim.x + threadIdx.x;
    if (e >= ET) return;
    int d = edge_dst(ei, e);
    int pos = atomicAdd(&cursor[d], 1);
    csr_e[pos] = e;
    csr_s[pos] = edge_src(ei, e);
}

// ---------------- MFMA GEMM: Cbf[M,Nc] = bf16( Abf[M,256] * Bt[Nc,256]^T ) ------------
// A, Bt bf16 row-major; K = 256 fixed. Wave tile 64x64 (4x4 of 16x16x32 mfma).
// LDS row stride 40 bf16 (80 B) -> 2-way bank aliasing only (free).

template <int TBM, int TBN, int WROWS, int WCOLS>
__global__ __launch_bounds__(256) void gemm_mfma_kernel(const unsigned short* __restrict__ Abf,
                                                        const unsigned short* __restrict__ Bt,
                                                        unsigned short* __restrict__ Cbf,
                                                        int M, int Nc) {
    static_assert(TBM == WROWS * 64 && TBN == WCOLS * 64, "tile");
    constexpr int LDK = 40;
    __shared__ alignas(16) unsigned short As[TBM * LDK];
    __shared__ alignas(16) unsigned short Bs[TBN * LDK];
    const int t = threadIdx.x;
    const int lane = t & 63;
    const int w = t >> 6;
    const int quad = lane >> 4;
    const int l16 = lane & 15;
    const int wm = (w / WCOLS) * 64;
    const int wn = (w % WCOLS) * 64;
    const int bm = blockIdx.x * TBM;
    const int bn = blockIdx.y * TBN;

    f32x4 acc[4][4] = {};

    for (int k0 = 0; k0 < 256; k0 += 32) {
        __syncthreads();
#pragma unroll
        for (int i = 0; i < TBM / 64; ++i) {
            int idx = t + i * 256;
            int row = idx >> 2, seg = idx & 3;
            u16x8 v = {};
            if (bm + row < M)
                v = *(const u16x8*)(Abf + (size_t)(bm + row) * 256 + k0 + seg * 8);
            *(u16x8*)&As[row * LDK + seg * 8] = v;
        }
#pragma unroll
        for (int i = 0; i < TBN / 64; ++i) {
            int idx = t + i * 256;
            int row = idx >> 2, seg = idx & 3;
            u16x8 v = *(const u16x8*)(Bt + (size_t)(bn + row) * 256 + k0 + seg * 8);
            *(u16x8*)&Bs[row * LDK + seg * 8] = v;
        }
        __syncthreads();

        bf16x8 af[4], bfr[4];
#pragma unroll
        for (int mi = 0; mi < 4; ++mi)
            af[mi] = *(const bf16x8*)&As[(wm + mi * 16 + l16) * LDK + quad * 8];
#pragma unroll
        for (int ni = 0; ni < 4; ++ni)
            bfr[ni] = *(const bf16x8*)&Bs[(wn + ni * 16 + l16) * LDK + quad * 8];
#pragma unroll
        for (int mi = 0; mi < 4; ++mi)
#pragma unroll
            for (int ni = 0; ni < 4; ++ni)
                acc[mi][ni] = __builtin_amdgcn_mfma_f32_16x16x32_bf16(
                    af[mi], bfr[ni], acc[mi][ni], 0, 0, 0);
    }

    // C/D layout: col = lane&15, row = quad*4 + r
#pragma unroll
    for (int mi = 0; mi < 4; ++mi) {
#pragma unroll
        for (int ni = 0; ni < 4; ++ni) {
#pragma unroll
            for (int r = 0; r < 4; ++r) {
                int row = bm + wm + mi * 16 + quad * 4 + r;
                int col = bn + wn + ni * 16 + l16;
                if (row < M)
                    Cbf[(size_t)row * Nc + col] = f2bf(acc[mi][ni][r]);
            }
        }
    }
}

// ---------------- layer 1 ----------------

__global__ __launch_bounds__(256) void att_dots1_kernel(const unsigned short* __restrict__ h1bf,
                                                        const float* __restrict__ as_,
                                                        const float* __restrict__ ad_,
                                                        float* __restrict__ a_src,
                                                        float* __restrict__ a_dst) {
    int n = blockIdx.x;
    int t = threadIdx.x;
    float hv = bf2f(h1bf[(size_t)n * HC1 + t]);
    float vs = hv * as_[t];
    float vd = hv * ad_[t];
    for (int o = 32; o; o >>= 1) { vs += __shfl_down(vs, o); vd += __shfl_down(vd, o); }
    if ((t & 63) == 0) {
        int hd = t >> 6;
        a_src[n * H1 + hd] = vs;
        a_dst[n * H1 + hd] = vd;
    }
}

#define ELC 4
__global__ __launch_bounds__(256) void softmax1_csr_kernel(const int* __restrict__ off,
                                                           const int* __restrict__ csr_e,
                                                           const int* __restrict__ csr_s,
                                                           const float* __restrict__ a_src,
                                                           const float* __restrict__ a_dst,
                                                           float* __restrict__ alpha,
                                                           float* __restrict__ alpha_csr) {
    int d = blockIdx.x;
    int t = threadIdx.x;
    int hd = t >> 6;
    int lane = t & 63;
    int beg = off[d], end = off[d + 1];
    float ad = a_dst[d * H1 + hd];

    float elc[ELC];
    float mx = -INFINITY;
    int c = 0;
    for (int idx = beg + lane; idx < end; idx += 64, ++c) {
        int s = csr_s[idx];
        float el = a_src[s * H1 + hd] + ad;
        el = el > 0.f ? el : NEG_SLOPE * el;
        if (c < ELC) elc[c] = el;
        mx = fmaxf(mx, el);
    }
#pragma unroll
    for (int o = 32; o; o >>= 1) mx = fmaxf(mx, __shfl_xor(mx, o));

    float sum = 0.f;
    c = 0;
    for (int idx = beg + lane; idx < end; idx += 64, ++c) {
        float el;
        if (c < ELC) el = elc[c];
        else {
            el = a_src[csr_s[idx] * H1 + hd] + ad;
            el = el > 0.f ? el : NEG_SLOPE * el;
        }
        sum += expf(el - mx);
    }
#pragma unroll
    for (int o = 32; o; o >>= 1) sum += __shfl_xor(sum, o);
    float inv = 1.f / (sum + EPS_A);

    c = 0;
    for (int idx = beg + lane; idx < end; idx += 64, ++c) {
        float el;
        if (c < ELC) el = elc[c];
        else {
            el = a_src[csr_s[idx] * H1 + hd] + ad;
            el = el > 0.f ? el : NEG_SLOPE * el;
        }
        float a = expf(el - mx) * inv;
        alpha[csr_e[idx] * H1 + hd] = a;
        alpha_csr[(size_t)idx * H1 + hd] = a;
    }
}

// gather aggregation from bf16 h1: 128 thr = one dst, thread t -> channels 2t,2t+1.
// Writes out1 in bf16 (packed u32) for the MFMA GEMM2. Fused bias+ELU.
#define CH1 64
__global__ __launch_bounds__(128) void agg1_csr_kernel(const int* __restrict__ off,
                                                       const int* __restrict__ csr_s,
                                                       const float* __restrict__ alpha_csr,
                                                       const unsigned* __restrict__ h1bf,
                                                       const float* __restrict__ b1,
                                                       unsigned* __restrict__ out1bf) {
    __shared__ int   s_src[CH1];
    __shared__ float s_al[CH1][H1];
    int d = blockIdx.x;
    int t = threadIdx.x;              // 0..127
    int head = t >> 5;                // channel 2t -> head (2t)>>6 = t>>5
    int beg = off[d], end = off[d + 1];
    float acc0 = 0.f, acc1 = 0.f;
    for (int cb = beg; cb < end; cb += CH1) {
        int cnt = min(CH1, end - cb);
        __syncthreads();
        if (t < cnt) {
            s_src[t] = csr_s[cb + t];
            *(float4*)&s_al[t][0] = *(const float4*)&alpha_csr[(size_t)(cb + t) * H1];
        }
        __syncthreads();
        int j = 0;
        for (; j + 4 <= cnt; j += 4) {
            int s0 = s_src[j], s1 = s_src[j + 1], s2 = s_src[j + 2], s3 = s_src[j + 3];
            float a0 = s_al[j][head], a1 = s_al[j + 1][head];
            float a2 = s_al[j + 2][head], a3 = s_al[j + 3][head];
            unsigned q0 = h1bf[(size_t)s0 * 128 + t];
            unsigned q1 = h1bf[(size_t)s1 * 128 + t];
            unsigned q2 = h1bf[(size_t)s2 * 128 + t];
            unsigned q3 = h1bf[(size_t)s3 * 128 + t];
            acc0 += a0 * bf_lo(q0) + a1 * bf_lo(q1) + a2 * bf_lo(q2) + a3 * bf_lo(q3);
            acc1 += a0 * bf_hi(q0) + a1 * bf_hi(q1) + a2 * bf_hi(q2) + a3 * bf_hi(q3);
        }
        for (; j < cnt; ++j) {
            unsigned q = h1bf[(size_t)s_src[j] * 128 + t];
            float a = s_al[j][head];
            acc0 += a * bf_lo(q);
            acc1 += a * bf_hi(q);
        }
    }
    float2 bb = *(const float2*)&b1[2 * t];
    float v0 = acc0 + bb.x, v1 = acc1 + bb.y;
    v0 = v0 > 0.f ? v0 : expm1f(v0);
    v1 = v1 > 0.f ? v1 : expm1f(v1);
    out1bf[(size_t)d * 128 + t] = ((unsigned)f2bf(v1) << 16) | (unsigned)f2bf(v0);
}

// ---------------- layer 2 ----------------

__global__ __launch_bounds__(256) void att_dots2_kernel(const unsigned short* __restrict__ h2bf,
                                                        const float* __restrict__ as2,
                                                        const float* __restrict__ ad2,
                                                        float* __restrict__ a_src,
                                                        float* __restrict__ a_dst) {
    int t = threadIdx.x;
    int lane = t & 63;
    int n = blockIdx.x * 4 + (t >> 6);
    float vs = 0.f, vd = 0.f;
    if (n < N_NODES && lane < C2) {
        float hv = bf2f(h2bf[(size_t)n * C2P + lane]);
        vs = hv * as2[lane];
        vd = hv * ad2[lane];
    }
    for (int o = 32; o; o >>= 1) { vs += __shfl_down(vs, o); vd += __shfl_down(vd, o); }
    if (n < N_NODES && lane == 0) { a_src[n] = vs; a_dst[n] = vd; }
}

__global__ __launch_bounds__(256) void softmax2_csr_kernel(const int* __restrict__ off,
                                                           const int* __restrict__ csr_s,
                                                           const float* __restrict__ a_src,
                                                           const float* __restrict__ a_dst,
                                                           float* __restrict__ a2_csr) {
    int t = threadIdx.x;
    int lane = t & 63;
    int d = blockIdx.x * 4 + (t >> 6);
    if (d >= N_NODES) return;
    int beg = off[d], end = off[d + 1];
    float ad = a_dst[d];

    float elc[ELC];
    float mx = -INFINITY;
    int c = 0;
    for (int idx = beg + lane; idx < end; idx += 64, ++c) {
        float el = a_src[csr_s[idx]] + ad;
        el = el > 0.f ? el : NEG_SLOPE * el;
        if (c < ELC) elc[c] = el;
        mx = fmaxf(mx, el);
    }
#pragma unroll
    for (int o = 32; o; o >>= 1) mx = fmaxf(mx, __shfl_xor(mx, o));

    float sum = 0.f;
    c = 0;
    for (int idx = beg + lane; idx < end; idx += 64, ++c) {
        float el;
        if (c < ELC) el = elc[c];
        else {
            el = a_src[csr_s[idx]] + ad;
            el = el > 0.f ? el : NEG_SLOPE * el;
        }
        sum += expf(el - mx);
    }
#pragma unroll
    for (int o = 32; o; o >>= 1) sum += __shfl_xor(sum, o);
    float inv = 1.f / (sum + EPS_A);

    c = 0;
    for (int idx = beg + lane; idx < end; idx += 64, ++c) {
        float el;
        if (c < ELC) el = elc[c];
        else {
            el = a_src[csr_s[idx]] + ad;
            el = el > 0.f ? el : NEG_SLOPE * el;
        }
        a2_csr[idx] = expf(el - mx) * inv;
    }
}

// aggregation + bias + log_softmax fused, bf16 gathers: wave = dst.
__global__ __launch_bounds__(256) void agg2_lsm_kernel(const int* __restrict__ off,
                                                       const int* __restrict__ csr_s,
                                                       const float* __restrict__ a2_csr,
                                                       const unsigned* __restrict__ h2bf,
                                                       const float* __restrict__ b2,
                                                       float* __restrict__ out) {
    int t = threadIdx.x;
    int lane = t & 63;
    int half = lane >> 5;
    int li = lane & 31;
    int d = blockIdx.x * 4 + (t >> 6);
    if (d >= N_NODES) return;
    int beg = off[d], end = off[d + 1];
    float acc0 = 0.f, acc1 = 0.f;
    for (int cb = beg; cb < end; cb += 64) {
        int cnt = min(64, end - cb);
        int my_s = 0; float my_a = 0.f;
        if (lane < cnt) {
            my_s = csr_s[cb + lane];
            my_a = a2_csr[cb + lane];
        }
        for (int j = 0; j < cnt; j += 2) {
            int jj = j + half;
            int s = __shfl(my_s, jj);
            float a = __shfl(my_a, jj);
            if (jj < cnt) {
                unsigned q = h2bf[(size_t)s * 32 + li];
                acc0 += a * bf_lo(q);
                acc1 += a * bf_hi(q);
            }
        }
    }
    acc0 += __shfl_xor(acc0, 32);
    acc1 += __shfl_xor(acc1, 32);
    bool act = li < 20;
    float v0 = act ? acc0 + b2[2 * li]     : -INFINITY;
    float v1 = act ? acc1 + b2[2 * li + 1] : -INFINITY;
    float mx = fmaxf(v0, v1);
#pragma unroll
    for (int o = 16; o; o >>= 1) mx = fmaxf(mx, __shfl_xor(mx, o));
    float ex = act ? expf(v0 - mx) + expf(v1 - mx) : 0.f;
#pragma unroll
    for (int o = 16; o; o >>= 1) ex += __shfl_xor(ex, o);
    float ls = logf(ex);
    if (act && half == 0)
        *(float2*)&out[(size_t)d * C2 + 2 * li] = make_float2(v0 - mx - ls, v1 - mx - ls);
}

// ---------------- launcher ----------------

extern "C" void kernel_launch(void* const* d_in, const int* in_sizes, int n_in,
                              void* d_out, int out_size, void* d_ws, size_t ws_size,
                              hipStream_t stream) {
    const float* x   = (const float*)d_in[0];
    const int*   ei  = (const int*)d_in[1];
    const float* W1  = (const float*)d_in[2];
    const float* as1 = (const float*)d_in[3];
    const float* ad1 = (const float*)d_in[4];
    const float* b1  = (const float*)d_in[5];
    const float* W2  = (const float*)d_in[6];
    const float* as2 = (const float*)d_in[7];
    const float* ad2 = (const float*)d_in[8];
    const float* b2  = (const float*)d_in[9];

    float* out   = (float*)d_out;
    float* alpha = out + (size_t)N_NODES * C2;   // [ET, 4] final output region

    unsigned* u32   = (unsigned*)d_ws;
    unsigned* h1bf  = u32;                        // 6,400,000 u32 (50000x256 bf16)
    unsigned* xbf   = h1bf + 6400000;             // 6,400,000 u32; ALIASES out1bf
    unsigned* h2bf  = xbf + 6400000;              // 1,600,000 u32 (50000x64 bf16)
    unsigned* w1t   = h2bf + 1600000;             // 32,768 u32 (256x256 bf16, [n][k])
    unsigned* w2t   = w1t + 32768;                // 8,192 u32 (64x256 bf16, [n][k])
    float* a_src1   = (float*)(w2t + 8192);       // 200,000 f
    float* a_dst1   = a_src1 + 200000;            // 200,000 f
    float* a_src2   = a_dst1 + 200000;            // 50,000 f
    float* a_dst2   = a_src2 + 50000;             // 50,000 f
    float* al1_csr  = a_dst2 + 50000;             // 3,400,000 f
    float* a2_csr   = al1_csr + 3400000;          // 850,000 f
    int*   deg      = (int*)(a2_csr + 850000);    // 50,000 i
    int*   offs     = deg + 50000;                // 50,001 i
    int*   cursor   = offs + 50001;               // 50,000 i
    int*   bsum     = cursor + 50000;             // 256 i
    int*   csr_e    = bsum + 256;                 // 850,000 i
    int*   csr_s    = csr_e + 850000;             // 850,000 i
    unsigned* out1bf = xbf;                       // alias: xbf dead after GEMM1

    const int TB = 256;
    const int EB = (ET + TB - 1) / TB;

    // --- CSR build ---
    fill_int_kernel<<<(N_NODES + TB - 1) / TB, TB, 0, stream>>>(deg, N_NODES, 0);
    hist_kernel<<<EB, TB, 0, stream>>>(ei, deg);
    scan_block_kernel<<<NSCAN_B, TB, 0, stream>>>(deg, offs, bsum);
    scan_top_kernel<<<1, TB, 0, stream>>>(bsum);
    scan_add_kernel<<<NSCAN_B, TB, 0, stream>>>(offs, cursor, bsum);
    scatter_kernel<<<EB, TB, 0, stream>>>(ei, cursor, csr_e, csr_s);

    // --- converts ---
    f32_to_bf16_kernel<<<(3200000 + TB - 1) / TB, TB, 0, stream>>>(
        x, (unsigned short*)xbf, 3200000);
    w1_transpose_kernel<<<(65536 + TB - 1) / TB, TB, 0, stream>>>(W1, (unsigned short*)w1t);
    w2_transpose_pad_kernel<<<(16384 + TB - 1) / TB, TB, 0, stream>>>(W2, (unsigned short*)w2t);

    // --- layer 1 ---
    gemm_mfma_kernel<128, 128, 2, 2><<<dim3((N_NODES + 127) / 128, 2), TB, 0, stream>>>(
        (const unsigned short*)xbf, (const unsigned short*)w1t,
        (unsigned short*)h1bf, N_NODES, HC1);
    att_dots1_kernel<<<N_NODES, TB, 0, stream>>>((const unsigned short*)h1bf, as1, ad1,
                                                 a_src1, a_dst1);
    softmax1_csr_kernel<<<N_NODES, TB, 0, stream>>>(offs, csr_e, csr_s, a_src1, a_dst1,
                                                    alpha, al1_csr);
    agg1_csr_kernel<<<N_NODES, 128, 0, stream>>>(offs, csr_s, al1_csr, h1bf, b1, out1bf);

    // --- layer 2 ---
    gemm_mfma_kernel<256, 64, 4, 1><<<dim3((N_NODES + 255) / 256, 1), TB, 0, stream>>>(
        (const unsigned short*)out1bf, (const unsigned short*)w2t,
        (unsigned short*)h2bf, N_NODES, C2P);
    att_dots2_kernel<<<(N_NODES + 3) / 4, TB, 0, stream>>>((const unsigned short*)h2bf,
                                                           as2, ad2, a_src2, a_dst2);
    softmax2_csr_kernel<<<(N_NODES + 3) / 4, TB, 0, stream>>>(offs, csr_s, a_src2, a_dst2, a2_csr);
    agg2_lsm_kernel<<<(N_NODES + 3) / 4, TB, 0, stream>>>(offs, csr_s, a2_csr, h2bf, b2, out);
}

// Round 6
// 423.507 us; speedup vs baseline: 3.1815x; 1.0704x over previous
//
#include <hip/hip_runtime.h>
#include <math.h>

#define N_NODES 50000
#define HC1 256      // 4 heads * 64 ch
#define H1 4
#define C2 40
#define C2P 64       // padded
#define E0 800000
#define ET 850000
#define NEG_SLOPE 0.2f
#define EPS_A 1e-16f

typedef __bf16 bf16x8 __attribute__((ext_vector_type(8)));
typedef float f32x4 __attribute__((ext_vector_type(4)));
typedef unsigned short u16x8 __attribute__((ext_vector_type(8)));

// ---------------- bf16 helpers (RNE) ----------------

__device__ inline unsigned short f2bf(float f) {
    unsigned u = __float_as_uint(f);
    return (unsigned short)((u + 0x7FFFu + ((u >> 16) & 1u)) >> 16);
}
__device__ inline float bf2f(unsigned short h) { return __uint_as_float(((unsigned)h) << 16); }
__device__ inline float bf_lo(unsigned q) { return __uint_as_float(q << 16); }
__device__ inline float bf_hi(unsigned q) { return __uint_as_float(q & 0xFFFF0000u); }

// ---------------- utility ----------------

__global__ void fill_int_kernel(int* __restrict__ p, int n, int v) {
    int i = blockIdx.x * blockDim.x + threadIdx.x;
    if (i < n) p[i] = v;
}

__device__ inline int edge_src(const int* __restrict__ ei, int e) {
    return (e < E0) ? ei[e] : (e - E0);
}
__device__ inline int edge_dst(const int* __restrict__ ei, int e) {
    return (e < E0) ? ei[E0 + e] : (e - E0);
}

// ---------------- converts ----------------

__global__ void f32_to_bf16_kernel(const float* __restrict__ src,
                                   unsigned short* __restrict__ dst, int n4) {
    int i = blockIdx.x * blockDim.x + threadIdx.x;
    if (i >= n4) return;
    float4 v = ((const float4*)src)[i];
    ushort4 w;
    w.x = f2bf(v.x); w.y = f2bf(v.y); w.z = f2bf(v.z); w.w = f2bf(v.w);
    ((ushort4*)dst)[i] = w;
}

// W1 [256][256] -> W1t bf16 [n][k]
__global__ void w1_transpose_kernel(const float* __restrict__ W1,
                                    unsigned short* __restrict__ Wt) {
    int tid = blockIdx.x * blockDim.x + threadIdx.x;
    if (tid >= 256 * 256) return;
    int n = tid >> 8, k = tid & 255;
    Wt[tid] = f2bf(W1[k * 256 + n]);
}

// W2 [256][40] -> W2t bf16 [64][256], rows >= 40 zero
__global__ void w2_transpose_pad_kernel(const float* __restrict__ W2,
                                        unsigned short* __restrict__ Wt) {
    int tid = blockIdx.x * blockDim.x + threadIdx.x;
    if (tid >= 64 * 256) return;
    int n = tid >> 8, k = tid & 255;
    Wt[tid] = (n < C2) ? f2bf(W2[k * C2 + n]) : (unsigned short)0;
}

// ---------------- CSR build ----------------

__global__ void hist_kernel(const int* __restrict__ ei, int* __restrict__ deg) {
    int e = blockIdx.x * blockDim.x + threadIdx.x;
    if (e >= ET) return;
    atomicAdd(&deg[edge_dst(ei, e)], 1);
}

__global__ __launch_bounds__(256) void scan_block_kernel(const int* __restrict__ deg,
                                                         int* __restrict__ excl,
                                                         int* __restrict__ bsum) {
    __shared__ int tmp[256];
    int t = threadIdx.x;
    int i = blockIdx.x * 256 + t;
    int v = (i < N_NODES) ? deg[i] : 0;
    tmp[t] = v;
    __syncthreads();
#pragma unroll
    for (int o = 1; o < 256; o <<= 1) {
        int x = (t >= o) ? tmp[t - o] : 0;
        __syncthreads();
        tmp[t] += x;
        __syncthreads();
    }
    if (i < N_NODES) excl[i] = tmp[t] - v;
    if (t == 255) bsum[blockIdx.x] = tmp[255];
}

#define NSCAN_B 196   // ceil(50000/256)

__global__ __launch_bounds__(256) void scan_top_kernel(int* __restrict__ bsum) {
    __shared__ int tmp[256];
    int t = threadIdx.x;
    int v = (t < NSCAN_B) ? bsum[t] : 0;
    tmp[t] = v;
    __syncthreads();
#pragma unroll
    for (int o = 1; o < 256; o <<= 1) {
        int x = (t >= o) ? tmp[t - o] : 0;
        __syncthreads();
        tmp[t] += x;
        __syncthreads();
    }
    if (t < NSCAN_B) bsum[t] = tmp[t] - v;   // exclusive
}

__global__ __launch_bounds__(256) void scan_add_kernel(int* __restrict__ offsets,
                                                       int* __restrict__ cursor,
                                                       const int* __restrict__ bsum) {
    int i = blockIdx.x * 256 + threadIdx.x;
    if (i < N_NODES) {
        int v = offsets[i] + bsum[blockIdx.x];
        offsets[i] = v;
        cursor[i] = v;
    }
    if (i == 0) offsets[N_NODES] = ET;
}

// writes (edge id, src id) as one int2 in CSR order
__global__ void scatter_kernel(const int* __restrict__ ei, int* __restrict__ cursor,
                               int2* __restrict__ csr_es) {
    int e = blockIdx.x * blockDim.x + threadIdx.x;
    if (e >= ET) return;
    int d = edge_dst(ei, e);
    int pos = atomicAdd(&cursor[d], 1);
    csr_es[pos] = make_int2(e, edge_src(ei, e));
}

// ---------------- MFMA GEMM + attention-dot epilogue ----------------
// Cbf[M,Nc] = bf16( Abf[M,256] * Bt[Nc,256]^T ); K = 256.
// Epilogue: a_src_o[row*hstride+head] = sum_col acc*att_s[col] (head = wave col-base/64).
// Wave tile 64x64 (4x4 of 16x16x32 mfma). LDS stride 40 bf16 -> 2-way aliasing (free).

template <int TBM, int TBN, int WROWS, int WCOLS>
__global__ __launch_bounds__(256) void gemm_mfma_kernel(const unsigned short* __restrict__ Abf,
                                                        const unsigned short* __restrict__ Bt,
                                                        unsigned short* __restrict__ Cbf,
                                                        const float* __restrict__ att_s,
                                                        const float* __restrict__ att_d,
                                                        float* __restrict__ a_src_o,
                                                        float* __restrict__ a_dst_o,
                                                        int M, int Nc, int attN, int hstride) {
    static_assert(TBM == WROWS * 64 && TBN == WCOLS * 64, "tile");
    constexpr int LDK = 40;
    __shared__ alignas(16) unsigned short As[TBM * LDK];
    __shared__ alignas(16) unsigned short Bs[TBN * LDK];
    const int t = threadIdx.x;
    const int lane = t & 63;
    const int w = t >> 6;
    const int quad = lane >> 4;
    const int l16 = lane & 15;
    const int wm = (w / WCOLS) * 64;
    const int wn = (w % WCOLS) * 64;
    const int bm = blockIdx.x * TBM;
    const int bn = blockIdx.y * TBN;

    f32x4 acc[4][4] = {};

    for (int k0 = 0; k0 < 256; k0 += 32) {
        __syncthreads();
#pragma unroll
        for (int i = 0; i < TBM / 64; ++i) {
            int idx = t + i * 256;
            int row = idx >> 2, seg = idx & 3;
            u16x8 v = {};
            if (bm + row < M)
                v = *(const u16x8*)(Abf + (size_t)(bm + row) * 256 + k0 + seg * 8);
            *(u16x8*)&As[row * LDK + seg * 8] = v;
        }
#pragma unroll
        for (int i = 0; i < TBN / 64; ++i) {
            int idx = t + i * 256;
            int row = idx >> 2, seg = idx & 3;
            u16x8 v = *(const u16x8*)(Bt + (size_t)(bn + row) * 256 + k0 + seg * 8);
            *(u16x8*)&Bs[row * LDK + seg * 8] = v;
        }
        __syncthreads();

        bf16x8 af[4], bfr[4];
#pragma unroll
        for (int mi = 0; mi < 4; ++mi)
            af[mi] = *(const bf16x8*)&As[(wm + mi * 16 + l16) * LDK + quad * 8];
#pragma unroll
        for (int ni = 0; ni < 4; ++ni)
            bfr[ni] = *(const bf16x8*)&Bs[(wn + ni * 16 + l16) * LDK + quad * 8];
#pragma unroll
        for (int mi = 0; mi < 4; ++mi)
#pragma unroll
            for (int ni = 0; ni < 4; ++ni)
                acc[mi][ni] = __builtin_amdgcn_mfma_f32_16x16x32_bf16(
                    af[mi], bfr[ni], acc[mi][ni], 0, 0, 0);
    }

    // C/D layout: col = lane&15, row = quad*4 + r
#pragma unroll
    for (int mi = 0; mi < 4; ++mi)
#pragma unroll
        for (int ni = 0; ni < 4; ++ni)
#pragma unroll
            for (int r = 0; r < 4; ++r) {
                int row = bm + wm + mi * 16 + quad * 4 + r;
                int col = bn + wn + ni * 16 + l16;
                if (row < M)
                    Cbf[(size_t)row * Nc + col] = f2bf(acc[mi][ni][r]);
            }

    // ---- attention-dot epilogue ----
    float asc[4], adc[4];
#pragma unroll
    for (int ni = 0; ni < 4; ++ni) {
        int col = bn + wn + ni * 16 + l16;
        bool valid = col < attN;
        asc[ni] = valid ? att_s[col] : 0.f;
        adc[ni] = valid ? att_d[col] : 0.f;
    }
    float vs[16], vd[16];
#pragma unroll
    for (int mi = 0; mi < 4; ++mi)
#pragma unroll
        for (int r = 0; r < 4; ++r) {
            float s = 0.f, dd = 0.f;
#pragma unroll
            for (int ni = 0; ni < 4; ++ni) {
                s += acc[mi][ni][r] * asc[ni];
                dd += acc[mi][ni][r] * adc[ni];
            }
            vs[mi * 4 + r] = s;
            vd[mi * 4 + r] = dd;
        }
    // butterfly all-reduce across l16: lane l16 ends holding row i = l16 (i = mi*4+r)
#pragma unroll
    for (int k = 0; k < 4; ++k) {
        const int o = 1 << k;
        const int b = (l16 >> k) & 1;
#pragma unroll
        for (int j = 0; j < (8 >> k); ++j) {
            float lo = vs[2 * j], hi = vs[2 * j + 1];
            float keep = b ? hi : lo, send = b ? lo : hi;
            vs[j] = keep + __shfl_xor(send, o);
            lo = vd[2 * j]; hi = vd[2 * j + 1];
            keep = b ? hi : lo; send = b ? lo : hi;
            vd[j] = keep + __shfl_xor(send, o);
        }
    }
    {
        int mi = l16 >> 2, r = l16 & 3;
        int row = bm + wm + mi * 16 + quad * 4 + r;
        int head = (bn + wn) >> 6;
        if (row < M) {
            a_src_o[(size_t)row * hstride + head] = vs[0];
            a_dst_o[(size_t)row * hstride + head] = vd[0];
        }
    }
}

// ---------------- layer 1 fused: per-dst softmax (4 heads) + aggregation ----------------
// Block = one dst, 256 thr. Wave hd computes head hd's alpha (reg-cached logits,
// LDS cap 512 edges, streamed fallback beyond). Writes alpha output (edge order)
// and aggregates h1 (bf16, packed 2ch/thread) with fused bias+ELU -> out1 bf16.

#define DCAP 512
__global__ __launch_bounds__(256) void l1_fused_kernel(const int* __restrict__ off,
                                                       const int2* __restrict__ csr_es,
                                                       const float* __restrict__ a_src,
                                                       const float* __restrict__ a_dst,
                                                       const unsigned* __restrict__ h1bf,
                                                       const float* __restrict__ b1,
                                                       float* __restrict__ alpha_out,
                                                       unsigned* __restrict__ out1bf) {
    __shared__ int   s_src[DCAP];
    __shared__ float s_al[DCAP][5];    // stride 5 -> conflict-free
    __shared__ float s_stat[4][2];     // mx, inv per head (for deg>DCAP fallback)
    __shared__ float s_comb[2][128][2];
    int d = blockIdx.x;
    int t = threadIdx.x;
    int hd = t >> 6, lane = t & 63;
    int beg = off[d], end = off[d + 1];
    int deg = end - beg;
    float ad = a_dst[d * H1 + hd];

    float elc[8];
    float mx = -INFINITY;
    int c = 0;
    for (int idx = beg + lane; idx < end; idx += 64, ++c) {
        int2 es = csr_es[idx];
        int j = idx - beg;
        if (hd == 0 && j < DCAP) s_src[j] = es.y;
        float el = a_src[es.y * H1 + hd] + ad;
        el = el > 0.f ? el : NEG_SLOPE * el;
        if (c < 8) elc[c] = el;
        mx = fmaxf(mx, el);
    }
#pragma unroll
    for (int o = 32; o; o >>= 1) mx = fmaxf(mx, __shfl_xor(mx, o));

    float sum = 0.f;
    c = 0;
    for (int idx = beg + lane; idx < end; idx += 64, ++c) {
        float el;
        if (c < 8) el = elc[c];
        else {
            int2 es = csr_es[idx];
            el = a_src[es.y * H1 + hd] + ad;
            el = el > 0.f ? el : NEG_SLOPE * el;
        }
        sum += expf(el - mx);
    }
#pragma unroll
    for (int o = 32; o; o >>= 1) sum += __shfl_xor(sum, o);
    float inv = 1.f / (sum + EPS_A);
    if (lane == 0) { s_stat[hd][0] = mx; s_stat[hd][1] = inv; }

    c = 0;
    for (int idx = beg + lane; idx < end; idx += 64, ++c) {
        int2 es = csr_es[idx];
        float el;
        if (c < 8) el = elc[c];
        else {
            el = a_src[es.y * H1 + hd] + ad;
            el = el > 0.f ? el : NEG_SLOPE * el;
        }
        float a = expf(el - mx) * inv;
        alpha_out[(size_t)es.x * H1 + hd] = a;
        int j = idx - beg;
        if (j < DCAP) s_al[j][hd] = a;
    }
    __syncthreads();

    // aggregation: 2 half-blocks = 2 edge streams; thread tt -> channels 2tt,2tt+1
    int tt = t & 127, eo = t >> 7, head = tt >> 5;
    float acc0 = 0.f, acc1 = 0.f;
    int n = min(deg, DCAP);
    int j = eo;
    for (; j + 6 < n; j += 8) {
        int s0 = s_src[j], s1 = s_src[j + 2], s2 = s_src[j + 4], s3 = s_src[j + 6];
        float a0 = s_al[j][head], a1 = s_al[j + 2][head];
        float a2 = s_al[j + 4][head], a3 = s_al[j + 6][head];
        unsigned q0 = h1bf[(size_t)s0 * 128 + tt];
        unsigned q1 = h1bf[(size_t)s1 * 128 + tt];
        unsigned q2 = h1bf[(size_t)s2 * 128 + tt];
        unsigned q3 = h1bf[(size_t)s3 * 128 + tt];
        acc0 += a0 * bf_lo(q0) + a1 * bf_lo(q1) + a2 * bf_lo(q2) + a3 * bf_lo(q3);
        acc1 += a0 * bf_hi(q0) + a1 * bf_hi(q1) + a2 * bf_hi(q2) + a3 * bf_hi(q3);
    }
    for (; j < n; j += 2) {
        unsigned q = h1bf[(size_t)s_src[j] * 128 + tt];
        float a = s_al[j][head];
        acc0 += a * bf_lo(q);
        acc1 += a * bf_hi(q);
    }
    // rare fallback: deg > DCAP (never for random E=800K graph, correctness only)
    for (int jj = DCAP + eo; jj < deg; jj += 2) {
        int2 es = csr_es[beg + jj];
        float el = a_src[es.y * H1 + head] + a_dst[d * H1 + head];
        el = el > 0.f ? el : NEG_SLOPE * el;
        float a = expf(el - s_stat[head][0]) * s_stat[head][1];
        unsigned q = h1bf[(size_t)es.y * 128 + tt];
        acc0 += a * bf_lo(q);
        acc1 += a * bf_hi(q);
    }
    s_comb[eo][tt][0] = acc0;
    s_comb[eo][tt][1] = acc1;
    __syncthreads();
    if (t < 128) {
        float2 bb = *(const float2*)&b1[2 * t];
        float v0 = s_comb[0][t][0] + s_comb[1][t][0] + bb.x;
        float v1 = s_comb[0][t][1] + s_comb[1][t][1] + bb.y;
        v0 = v0 > 0.f ? v0 : expm1f(v0);
        v1 = v1 > 0.f ? v1 : expm1f(v1);
        out1bf[(size_t)d * 128 + t] = ((unsigned)f2bf(v1) << 16) | (unsigned)f2bf(v0);
    }
}

// ---------------- layer 2 fused: softmax + aggregation + bias + log_softmax ----------------
// Wave = one dst (4 per block). alpha stays in registers, broadcast via shfl.

__global__ __launch_bounds__(256) void l2_fused_kernel(const int* __restrict__ off,
                                                       const int2* __restrict__ csr_es,
                                                       const float* __restrict__ a_src,
                                                       const float* __restrict__ a_dst,
                                                       const unsigned* __restrict__ h2bf,
                                                       const float* __restrict__ b2,
                                                       float* __restrict__ out) {
    int t = threadIdx.x;
    int lane = t & 63;
    int d = blockIdx.x * 4 + (t >> 6);
    if (d >= N_NODES) return;
    int beg = off[d], end = off[d + 1];
    int deg = end - beg;
    float ad = a_dst[d];
    int nch = (deg + 63) >> 6;

    float elc[4]; int sc[4];
    float mx = -INFINITY;
    for (int cc = 0; cc < nch; ++cc) {
        int idx = beg + cc * 64 + lane;
        float el = -INFINITY; int s = 0;
        if (idx < end) {
            int2 es = csr_es[idx];
            s = es.y;
            el = a_src[s] + ad;
            el = el > 0.f ? el : NEG_SLOPE * el;
        }
        if (cc < 4) { elc[cc] = el; sc[cc] = s; }
        mx = fmaxf(mx, el);
    }
#pragma unroll
    for (int o = 32; o; o >>= 1) mx = fmaxf(mx, __shfl_xor(mx, o));

    float sum = 0.f;
    for (int cc = 0; cc < nch; ++cc) {
        float el;
        if (cc < 4) el = elc[cc];
        else {
            int idx = beg + cc * 64 + lane;
            el = -INFINITY;
            if (idx < end) {
                int2 es = csr_es[idx];
                el = a_src[es.y] + ad;
                el = el > 0.f ? el : NEG_SLOPE * el;
            }
        }
        sum += expf(el - mx);   // exp(-inf - mx) = 0 for inactive lanes
    }
#pragma unroll
    for (int o = 32; o; o >>= 1) sum += __shfl_xor(sum, o);
    float inv = 1.f / (sum + EPS_A);

    int half = lane >> 5, li = lane & 31;
    float acc0 = 0.f, acc1 = 0.f;
    for (int cc = 0; cc < nch; ++cc) {
        int cnt = min(64, deg - cc * 64);
        int my_s; float my_a;
        if (cc < 4) {
            my_s = sc[cc];
            my_a = expf(elc[cc] - mx) * inv;
        } else {
            int idx = beg + cc * 64 + lane;
            my_s = 0; my_a = 0.f;
            if (idx < end) {
                int2 es = csr_es[idx];
                my_s = es.y;
                float el = a_src[es.y] + ad;
                el = el > 0.f ? el : NEG_SLOPE * el;
                my_a = expf(el - mx) * inv;
            }
        }
        for (int j = 0; j < cnt; j += 2) {
            int jj = j + half;
            int s = __shfl(my_s, jj);
            float a = __shfl(my_a, jj);
            if (jj < cnt) {
                unsigned q = h2bf[(size_t)s * 32 + li];
                acc0 += a * bf_lo(q);
                acc1 += a * bf_hi(q);
            }
        }
    }
    acc0 += __shfl_xor(acc0, 32);
    acc1 += __shfl_xor(acc1, 32);
    bool act = li < 20;
    float v0 = act ? acc0 + b2[2 * li]     : -INFINITY;
    float v1 = act ? acc1 + b2[2 * li + 1] : -INFINITY;
    float mmx = fmaxf(v0, v1);
#pragma unroll
    for (int o = 16; o; o >>= 1) mmx = fmaxf(mmx, __shfl_xor(mmx, o));
    float ex = act ? expf(v0 - mmx) + expf(v1 - mmx) : 0.f;
#pragma unroll
    for (int o = 16; o; o >>= 1) ex += __shfl_xor(ex, o);
    float ls = logf(ex);
    if (act && half == 0)
        *(float2*)&out[(size_t)d * C2 + 2 * li] = make_float2(v0 - mmx - ls, v1 - mmx - ls);
}

// ---------------- launcher ----------------

extern "C" void kernel_launch(void* const* d_in, const int* in_sizes, int n_in,
                              void* d_out, int out_size, void* d_ws, size_t ws_size,
                              hipStream_t stream) {
    const float* x   = (const float*)d_in[0];
    const int*   ei  = (const int*)d_in[1];
    const float* W1  = (const float*)d_in[2];
    const float* as1 = (const float*)d_in[3];
    const float* ad1 = (const float*)d_in[4];
    const float* b1  = (const float*)d_in[5];
    const float* W2  = (const float*)d_in[6];
    const float* as2 = (const float*)d_in[7];
    const float* ad2 = (const float*)d_in[8];
    const float* b2  = (const float*)d_in[9];

    float* out   = (float*)d_out;
    float* alpha = out + (size_t)N_NODES * C2;    // [ET, 4] final output region

    unsigned* u32    = (unsigned*)d_ws;
    unsigned* h1bf   = u32;                       // 6,400,000 u32 (50000x256 bf16)
    unsigned* xbf    = h1bf + 6400000;            // 6,400,000 u32; ALIASES out1bf
    unsigned* h2bf   = xbf + 6400000;             // 1,600,000 u32 (50000x64 bf16)
    unsigned* w1t    = h2bf + 1600000;            // 32,768 u32
    unsigned* w2t    = w1t + 32768;               // 8,192 u32
    float* a_src1    = (float*)(w2t + 8192);      // 200,000 f
    float* a_dst1    = a_src1 + 200000;           // 200,000 f
    float* a_src2    = a_dst1 + 200000;           // 50,000 f
    float* a_dst2    = a_src2 + 50000;            // 50,000 f
    int*   deg       = (int*)(a_dst2 + 50000);    // 50,000 i
    int*   offs      = deg + 50000;               // 50,001 i
    int*   cursor    = offs + 50001;              // 50,000 i
    int*   bsum      = cursor + 50000;            // 256 i + 1 pad
    int2*  csr_es    = (int2*)(bsum + 257);       // 850,000 int2 (8B-aligned)
    unsigned* out1bf = xbf;                       // alias: xbf dead after GEMM1

    const int TB = 256;
    const int EB = (ET + TB - 1) / TB;

    // --- CSR build ---
    fill_int_kernel<<<(N_NODES + TB - 1) / TB, TB, 0, stream>>>(deg, N_NODES, 0);
    hist_kernel<<<EB, TB, 0, stream>>>(ei, deg);
    scan_block_kernel<<<NSCAN_B, TB, 0, stream>>>(deg, offs, bsum);
    scan_top_kernel<<<1, TB, 0, stream>>>(bsum);
    scan_add_kernel<<<NSCAN_B, TB, 0, stream>>>(offs, cursor, bsum);
    scatter_kernel<<<EB, TB, 0, stream>>>(ei, cursor, csr_es);

    // --- converts ---
    f32_to_bf16_kernel<<<(3200000 + TB - 1) / TB, TB, 0, stream>>>(
        x, (unsigned short*)xbf, 3200000);
    w1_transpose_kernel<<<(65536 + TB - 1) / TB, TB, 0, stream>>>(W1, (unsigned short*)w1t);
    w2_transpose_pad_kernel<<<(16384 + TB - 1) / TB, TB, 0, stream>>>(W2, (unsigned short*)w2t);

    // --- layer 1 ---
    gemm_mfma_kernel<128, 128, 2, 2><<<dim3((N_NODES + 127) / 128, 2), TB, 0, stream>>>(
        (const unsigned short*)xbf, (const unsigned short*)w1t, (unsigned short*)h1bf,
        as1, ad1, a_src1, a_dst1, N_NODES, HC1, 256, H1);
    l1_fused_kernel<<<N_NODES, TB, 0, stream>>>(offs, csr_es, a_src1, a_dst1,
                                                h1bf, b1, alpha, out1bf);

    // --- layer 2 ---
    gemm_mfma_kernel<256, 64, 4, 1><<<dim3((N_NODES + 255) / 256, 1), TB, 0, stream>>>(
        (const unsigned short*)out1bf, (const unsigned short*)w2t, (unsigned short*)h2bf,
        as2, ad2, a_src2, a_dst2, N_NODES, C2P, C2, 1);
    l2_fused_kernel<<<(N_NODES + 3) / 4, TB, 0, stream>>>(offs, csr_es, a_src2, a_dst2,
                                                          h2bf, b2, out);
}

// Round 7
// 414.195 us; speedup vs baseline: 3.2530x; 1.0225x over previous
//
#include <hip/hip_runtime.h>
#include <math.h>

#define N_NODES 50000
#define HC1 256      // 4 heads * 64 ch
#define H1 4
#define C2 40
#define C2P 64       // padded
#define E0 800000
#define ET 850000
#define NEG_SLOPE 0.2f
#define EPS_A 1e-16f

typedef __bf16 bf16x8 __attribute__((ext_vector_type(8)));
typedef float f32x4 __attribute__((ext_vector_type(4)));
typedef unsigned short u16x8 __attribute__((ext_vector_type(8)));

// ---------------- bf16 helpers (RNE) ----------------

__device__ inline unsigned short f2bf(float f) {
    unsigned u = __float_as_uint(f);
    return (unsigned short)((u + 0x7FFFu + ((u >> 16) & 1u)) >> 16);
}
__device__ inline float bf2f(unsigned short h) { return __uint_as_float(((unsigned)h) << 16); }
__device__ inline float bf_lo(unsigned q) { return __uint_as_float(q << 16); }
__device__ inline float bf_hi(unsigned q) { return __uint_as_float(q & 0xFFFF0000u); }

// ---------------- utility ----------------

__global__ void fill_int_kernel(int* __restrict__ p, int n, int v) {
    int i = blockIdx.x * blockDim.x + threadIdx.x;
    if (i < n) p[i] = v;
}

__device__ inline int edge_src(const int* __restrict__ ei, int e) {
    return (e < E0) ? ei[e] : (e - E0);
}
__device__ inline int edge_dst(const int* __restrict__ ei, int e) {
    return (e < E0) ? ei[E0 + e] : (e - E0);
}

// ---------------- converts ----------------

__global__ void f32_to_bf16_kernel(const float* __restrict__ src,
                                   unsigned short* __restrict__ dst, int n4) {
    int i = blockIdx.x * blockDim.x + threadIdx.x;
    if (i >= n4) return;
    float4 v = ((const float4*)src)[i];
    ushort4 w;
    w.x = f2bf(v.x); w.y = f2bf(v.y); w.z = f2bf(v.z); w.w = f2bf(v.w);
    ((ushort4*)dst)[i] = w;
}

// W1 [256][256] -> W1t bf16 [n][k]
__global__ void w1_transpose_kernel(const float* __restrict__ W1,
                                    unsigned short* __restrict__ Wt) {
    int tid = blockIdx.x * blockDim.x + threadIdx.x;
    if (tid >= 256 * 256) return;
    int n = tid >> 8, k = tid & 255;
    Wt[tid] = f2bf(W1[k * 256 + n]);
}

// W2 [256][40] -> W2t bf16 [64][256], rows >= 40 zero
__global__ void w2_transpose_pad_kernel(const float* __restrict__ W2,
                                        unsigned short* __restrict__ Wt) {
    int tid = blockIdx.x * blockDim.x + threadIdx.x;
    if (tid >= 64 * 256) return;
    int n = tid >> 8, k = tid & 255;
    Wt[tid] = (n < C2) ? f2bf(W2[k * C2 + n]) : (unsigned short)0;
}

// ---------------- CSR build ----------------

__global__ void hist_kernel(const int* __restrict__ ei, int* __restrict__ deg) {
    int e = blockIdx.x * blockDim.x + threadIdx.x;
    if (e >= ET) return;
    atomicAdd(&deg[edge_dst(ei, e)], 1);
}

__global__ __launch_bounds__(256) void scan_block_kernel(const int* __restrict__ deg,
                                                         int* __restrict__ excl,
                                                         int* __restrict__ bsum) {
    __shared__ int tmp[256];
    int t = threadIdx.x;
    int i = blockIdx.x * 256 + t;
    int v = (i < N_NODES) ? deg[i] : 0;
    tmp[t] = v;
    __syncthreads();
#pragma unroll
    for (int o = 1; o < 256; o <<= 1) {
        int x = (t >= o) ? tmp[t - o] : 0;
        __syncthreads();
        tmp[t] += x;
        __syncthreads();
    }
    if (i < N_NODES) excl[i] = tmp[t] - v;
    if (t == 255) bsum[blockIdx.x] = tmp[255];
}

#define NSCAN_B 196   // ceil(50000/256)

__global__ __launch_bounds__(256) void scan_top_kernel(int* __restrict__ bsum) {
    __shared__ int tmp[256];
    int t = threadIdx.x;
    int v = (t < NSCAN_B) ? bsum[t] : 0;
    tmp[t] = v;
    __syncthreads();
#pragma unroll
    for (int o = 1; o < 256; o <<= 1) {
        int x = (t >= o) ? tmp[t - o] : 0;
        __syncthreads();
        tmp[t] += x;
        __syncthreads();
    }
    if (t < NSCAN_B) bsum[t] = tmp[t] - v;   // exclusive
}

__global__ __launch_bounds__(256) void scan_add_kernel(int* __restrict__ offsets,
                                                       int* __restrict__ cursor,
                                                       const int* __restrict__ bsum) {
    int i = blockIdx.x * 256 + threadIdx.x;
    if (i < N_NODES) {
        int v = offsets[i] + bsum[blockIdx.x];
        offsets[i] = v;
        cursor[i] = v;
    }
    if (i == 0) offsets[N_NODES] = ET;
}

// writes (edge id, src id) as one int2 in CSR order
__global__ void scatter_kernel(const int* __restrict__ ei, int* __restrict__ cursor,
                               int2* __restrict__ csr_es) {
    int e = blockIdx.x * blockDim.x + threadIdx.x;
    if (e >= ET) return;
    int d = edge_dst(ei, e);
    int pos = atomicAdd(&cursor[d], 1);
    csr_es[pos] = make_int2(e, edge_src(ei, e));
}

// ---------------- MFMA GEMM + attention-dot epilogue ----------------
// Cbf[M,Nc] = bf16( Abf[M,256] * Bt[Nc,256]^T ); K = 256.
// Epilogue: a_src_o[row*hstride+head] = sum_col acc*att_s[col] (head = wave col-base/64).
// Wave tile 64x64 (4x4 of 16x16x32 mfma). LDS stride 40 bf16 -> 2-way aliasing (free).

template <int TBM, int TBN, int WROWS, int WCOLS>
__global__ __launch_bounds__(256) void gemm_mfma_kernel(const unsigned short* __restrict__ Abf,
                                                        const unsigned short* __restrict__ Bt,
                                                        unsigned short* __restrict__ Cbf,
                                                        const float* __restrict__ att_s,
                                                        const float* __restrict__ att_d,
                                                        float* __restrict__ a_src_o,
                                                        float* __restrict__ a_dst_o,
                                                        int M, int Nc, int attN, int hstride) {
    static_assert(TBM == WROWS * 64 && TBN == WCOLS * 64, "tile");
    constexpr int LDK = 40;
    __shared__ alignas(16) unsigned short As[TBM * LDK];
    __shared__ alignas(16) unsigned short Bs[TBN * LDK];
    const int t = threadIdx.x;
    const int lane = t & 63;
    const int w = t >> 6;
    const int quad = lane >> 4;
    const int l16 = lane & 15;
    const int wm = (w / WCOLS) * 64;
    const int wn = (w % WCOLS) * 64;
    const int bm = blockIdx.x * TBM;
    const int bn = blockIdx.y * TBN;

    f32x4 acc[4][4] = {};

    for (int k0 = 0; k0 < 256; k0 += 32) {
        __syncthreads();
#pragma unroll
        for (int i = 0; i < TBM / 64; ++i) {
            int idx = t + i * 256;
            int row = idx >> 2, seg = idx & 3;
            u16x8 v = {};
            if (bm + row < M)
                v = *(const u16x8*)(Abf + (size_t)(bm + row) * 256 + k0 + seg * 8);
            *(u16x8*)&As[row * LDK + seg * 8] = v;
        }
#pragma unroll
        for (int i = 0; i < TBN / 64; ++i) {
            int idx = t + i * 256;
            int row = idx >> 2, seg = idx & 3;
            u16x8 v = *(const u16x8*)(Bt + (size_t)(bn + row) * 256 + k0 + seg * 8);
            *(u16x8*)&Bs[row * LDK + seg * 8] = v;
        }
        __syncthreads();

        bf16x8 af[4], bfr[4];
#pragma unroll
        for (int mi = 0; mi < 4; ++mi)
            af[mi] = *(const bf16x8*)&As[(wm + mi * 16 + l16) * LDK + quad * 8];
#pragma unroll
        for (int ni = 0; ni < 4; ++ni)
            bfr[ni] = *(const bf16x8*)&Bs[(wn + ni * 16 + l16) * LDK + quad * 8];
#pragma unroll
        for (int mi = 0; mi < 4; ++mi)
#pragma unroll
            for (int ni = 0; ni < 4; ++ni)
                acc[mi][ni] = __builtin_amdgcn_mfma_f32_16x16x32_bf16(
                    af[mi], bfr[ni], acc[mi][ni], 0, 0, 0);
    }

    // C/D layout: col = lane&15, row = quad*4 + r
#pragma unroll
    for (int mi = 0; mi < 4; ++mi)
#pragma unroll
        for (int ni = 0; ni < 4; ++ni)
#pragma unroll
            for (int r = 0; r < 4; ++r) {
                int row = bm + wm + mi * 16 + quad * 4 + r;
                int col = bn + wn + ni * 16 + l16;
                if (row < M)
                    Cbf[(size_t)row * Nc + col] = f2bf(acc[mi][ni][r]);
            }

    // ---- attention-dot epilogue ----
    float asc[4], adc[4];
#pragma unroll
    for (int ni = 0; ni < 4; ++ni) {
        int col = bn + wn + ni * 16 + l16;
        bool valid = col < attN;
        asc[ni] = valid ? att_s[col] : 0.f;
        adc[ni] = valid ? att_d[col] : 0.f;
    }
    float vs[16], vd[16];
#pragma unroll
    for (int mi = 0; mi < 4; ++mi)
#pragma unroll
        for (int r = 0; r < 4; ++r) {
            float s = 0.f, dd = 0.f;
#pragma unroll
            for (int ni = 0; ni < 4; ++ni) {
                s += acc[mi][ni][r] * asc[ni];
                dd += acc[mi][ni][r] * adc[ni];
            }
            vs[mi * 4 + r] = s;
            vd[mi * 4 + r] = dd;
        }
    // butterfly all-reduce across l16: lane l16 ends holding row i = l16 (i = mi*4+r)
#pragma unroll
    for (int k = 0; k < 4; ++k) {
        const int o = 1 << k;
        const int b = (l16 >> k) & 1;
#pragma unroll
        for (int j = 0; j < (8 >> k); ++j) {
            float lo = vs[2 * j], hi = vs[2 * j + 1];
            float keep = b ? hi : lo, send = b ? lo : hi;
            vs[j] = keep + __shfl_xor(send, o);
            lo = vd[2 * j]; hi = vd[2 * j + 1];
            keep = b ? hi : lo; send = b ? lo : hi;
            vd[j] = keep + __shfl_xor(send, o);
        }
    }
    {
        int mi = l16 >> 2, r = l16 & 3;
        int row = bm + wm + mi * 16 + quad * 4 + r;
        int head = (bn + wn) >> 6;
        if (row < M) {
            a_src_o[(size_t)row * hstride + head] = vs[0];
            a_dst_o[(size_t)row * hstride + head] = vd[0];
        }
    }
}

// ---------------- layer 1 fused: per-dst softmax (4 heads) + aggregation ----------------
// Block = one dst, 256 thr. Wave hd = head hd. Two passes only: max, then p=exp into
// per-head LDS planes. Alpha emitted as ONE float4 store per edge (p*inv). Aggregation
// accumulates unnormalized p*h, scaled by inv once per channel at the end. Fused
// bias + ELU -> out1 bf16.

#define DCAP 512
__global__ __launch_bounds__(256) void l1_fused_kernel(const int* __restrict__ off,
                                                       const int2* __restrict__ csr_es,
                                                       const float* __restrict__ a_src,
                                                       const float* __restrict__ a_dst,
                                                       const unsigned* __restrict__ h1bf,
                                                       const float* __restrict__ b1,
                                                       float* __restrict__ alpha_out,
                                                       unsigned* __restrict__ out1bf) {
    __shared__ int   s_src[DCAP];
    __shared__ int   s_eid[DCAP];
    __shared__ float s_al[H1][DCAP];   // unnormalized p, per head plane
    __shared__ float s_stat[H1][2];    // mx, inv per head
    __shared__ float s_comb[2][128][2];
    int d = blockIdx.x;
    int t = threadIdx.x;
    int hd = t >> 6, lane = t & 63;
    int beg = off[d], end = off[d + 1];
    int deg = end - beg;
    float ad = a_dst[d * H1 + hd];

    float elc[8];
    float mx = -INFINITY;
    int c = 0;
    for (int idx = beg + lane; idx < end; idx += 64, ++c) {
        int2 es = csr_es[idx];
        int j = idx - beg;
        if (hd == 0 && j < DCAP) { s_src[j] = es.y; s_eid[j] = es.x; }
        float el = a_src[es.y * H1 + hd] + ad;
        el = el > 0.f ? el : NEG_SLOPE * el;
        if (c < 8) elc[c] = el;
        mx = fmaxf(mx, el);
    }
#pragma unroll
    for (int o = 32; o; o >>= 1) mx = fmaxf(mx, __shfl_xor(mx, o));

    float sum = 0.f;
    c = 0;
    for (int idx = beg + lane; idx < end; idx += 64, ++c) {
        float el;
        if (c < 8) el = elc[c];
        else {
            int2 es = csr_es[idx];
            el = a_src[es.y * H1 + hd] + ad;
            el = el > 0.f ? el : NEG_SLOPE * el;
        }
        float p = __expf(el - mx);
        int j = idx - beg;
        if (j < DCAP) s_al[hd][j] = p;
        sum += p;
    }
#pragma unroll
    for (int o = 32; o; o >>= 1) sum += __shfl_xor(sum, o);
    float inv = 1.f / (sum + EPS_A);
    if (lane == 0) { s_stat[hd][0] = mx; s_stat[hd][1] = inv; }
    __syncthreads();

    // alpha output: one float4 (all 4 heads) per edge
    int n = min(deg, DCAP);
    {
        float i0 = s_stat[0][1], i1 = s_stat[1][1], i2 = s_stat[2][1], i3 = s_stat[3][1];
        for (int j = t; j < n; j += 256) {
            float4 a4 = make_float4(s_al[0][j] * i0, s_al[1][j] * i1,
                                    s_al[2][j] * i2, s_al[3][j] * i3);
            *(float4*)&alpha_out[(size_t)s_eid[j] * H1] = a4;
        }
    }
    // rare fallback alpha for j >= DCAP (deg > 512 never happens for this graph)
    for (int idx = beg + DCAP + lane; idx < end; idx += 64) {
        int2 es = csr_es[idx];
        float el = a_src[es.y * H1 + hd] + ad;
        el = el > 0.f ? el : NEG_SLOPE * el;
        alpha_out[(size_t)es.x * H1 + hd] = __expf(el - mx) * inv;
    }

    // aggregation: 2 half-blocks = 2 edge streams; thread tt -> channels 2tt,2tt+1
    int tt = t & 127, eo = t >> 7, head = tt >> 5;
    float acc0 = 0.f, acc1 = 0.f;
    int j = eo;
    for (; j + 6 < n; j += 8) {
        int s0 = s_src[j], s1 = s_src[j + 2], s2 = s_src[j + 4], s3 = s_src[j + 6];
        float a0 = s_al[head][j], a1 = s_al[head][j + 2];
        float a2 = s_al[head][j + 4], a3 = s_al[head][j + 6];
        unsigned q0 = h1bf[(size_t)s0 * 128 + tt];
        unsigned q1 = h1bf[(size_t)s1 * 128 + tt];
        unsigned q2 = h1bf[(size_t)s2 * 128 + tt];
        unsigned q3 = h1bf[(size_t)s3 * 128 + tt];
        acc0 += a0 * bf_lo(q0) + a1 * bf_lo(q1) + a2 * bf_lo(q2) + a3 * bf_lo(q3);
        acc1 += a0 * bf_hi(q0) + a1 * bf_hi(q1) + a2 * bf_hi(q2) + a3 * bf_hi(q3);
    }
    for (; j < n; j += 2) {
        unsigned q = h1bf[(size_t)s_src[j] * 128 + tt];
        float a = s_al[head][j];
        acc0 += a * bf_lo(q);
        acc1 += a * bf_hi(q);
    }
    // rare fallback agg (unnormalized p, consistent with end-scaling)
    for (int jj = DCAP + eo; jj < deg; jj += 2) {
        int2 es = csr_es[beg + jj];
        float el = a_src[es.y * H1 + head] + a_dst[d * H1 + head];
        el = el > 0.f ? el : NEG_SLOPE * el;
        float p = __expf(el - s_stat[head][0]);
        unsigned q = h1bf[(size_t)es.y * 128 + tt];
        acc0 += p * bf_lo(q);
        acc1 += p * bf_hi(q);
    }
    s_comb[eo][tt][0] = acc0;
    s_comb[eo][tt][1] = acc1;
    __syncthreads();
    if (t < 128) {
        float invh = s_stat[t >> 5][1];
        float2 bb = *(const float2*)&b1[2 * t];
        float v0 = (s_comb[0][t][0] + s_comb[1][t][0]) * invh + bb.x;
        float v1 = (s_comb[0][t][1] + s_comb[1][t][1]) * invh + bb.y;
        v0 = v0 > 0.f ? v0 : __expf(v0) - 1.f;
        v1 = v1 > 0.f ? v1 : __expf(v1) - 1.f;
        out1bf[(size_t)d * 128 + t] = ((unsigned)f2bf(v1) << 16) | (unsigned)f2bf(v0);
    }
}

// ---------------- layer 2 fused: softmax + aggregation + bias + log_softmax ----------------
// Wave = one dst (4 per block). p cached in registers (deg<=256), broadcast via shfl,
// normalization deferred to after the edge loop.

__global__ __launch_bounds__(256) void l2_fused_kernel(const int* __restrict__ off,
                                                       const int2* __restrict__ csr_es,
                                                       const float* __restrict__ a_src,
                                                       const float* __restrict__ a_dst,
                                                       const unsigned* __restrict__ h2bf,
                                                       const float* __restrict__ b2,
                                                       float* __restrict__ out) {
    int t = threadIdx.x;
    int lane = t & 63;
    int d = blockIdx.x * 4 + (t >> 6);
    if (d >= N_NODES) return;
    int beg = off[d], end = off[d + 1];
    int deg = end - beg;
    float ad = a_dst[d];
    int nch = (deg + 63) >> 6;

    float elc[4]; int sc[4];
    float mx = -INFINITY;
    for (int cc = 0; cc < nch; ++cc) {
        int idx = beg + cc * 64 + lane;
        float el = -INFINITY; int s = 0;
        if (idx < end) {
            int2 es = csr_es[idx];
            s = es.y;
            el = a_src[s] + ad;
            el = el > 0.f ? el : NEG_SLOPE * el;
        }
        if (cc < 4) { elc[cc] = el; sc[cc] = s; }
        mx = fmaxf(mx, el);
    }
#pragma unroll
    for (int o = 32; o; o >>= 1) mx = fmaxf(mx, __shfl_xor(mx, o));

    float sum = 0.f;
    for (int cc = 0; cc < nch; ++cc) {
        float p;
        if (cc < 4) {
            p = __expf(elc[cc] - mx);   // exp(-inf) = 0 for inactive lanes
            elc[cc] = p;
        } else {
            int idx = beg + cc * 64 + lane;
            float el = -INFINITY;
            if (idx < end) {
                int2 es = csr_es[idx];
                el = a_src[es.y] + ad;
                el = el > 0.f ? el : NEG_SLOPE * el;
            }
            p = __expf(el - mx);
        }
        sum += p;
    }
#pragma unroll
    for (int o = 32; o; o >>= 1) sum += __shfl_xor(sum, o);
    float inv = 1.f / (sum + EPS_A);

    int half = lane >> 5, li = lane & 31;
    float acc0 = 0.f, acc1 = 0.f;
    for (int cc = 0; cc < nch; ++cc) {
        int cnt = min(64, deg - cc * 64);
        int my_s; float my_a;
        if (cc < 4) {
            my_s = sc[cc];
            my_a = elc[cc];
        } else {
            int idx = beg + cc * 64 + lane;
            my_s = 0; my_a = 0.f;
            if (idx < end) {
                int2 es = csr_es[idx];
                my_s = es.y;
                float el = a_src[es.y] + ad;
                el = el > 0.f ? el : NEG_SLOPE * el;
                my_a = __expf(el - mx);
            }
        }
        for (int j = 0; j < cnt; j += 2) {
            int jj = j + half;
            int s = __shfl(my_s, jj);
            float a = __shfl(my_a, jj);
            if (jj < cnt) {
                unsigned q = h2bf[(size_t)s * 32 + li];
                acc0 += a * bf_lo(q);
                acc1 += a * bf_hi(q);
            }
        }
    }
    acc0 += __shfl_xor(acc0, 32);
    acc1 += __shfl_xor(acc1, 32);
    acc0 *= inv;
    acc1 *= inv;
    bool act = li < 20;
    float v0 = act ? acc0 + b2[2 * li]     : -INFINITY;
    float v1 = act ? acc1 + b2[2 * li + 1] : -INFINITY;
    float mmx = fmaxf(v0, v1);
#pragma unroll
    for (int o = 16; o; o >>= 1) mmx = fmaxf(mmx, __shfl_xor(mmx, o));
    float ex = act ? __expf(v0 - mmx) + __expf(v1 - mmx) : 0.f;
#pragma unroll
    for (int o = 16; o; o >>= 1) ex += __shfl_xor(ex, o);
    float ls = __logf(ex);
    if (act && half == 0)
        *(float2*)&out[(size_t)d * C2 + 2 * li] = make_float2(v0 - mmx - ls, v1 - mmx - ls);
}

// ---------------- launcher ----------------

extern "C" void kernel_launch(void* const* d_in, const int* in_sizes, int n_in,
                              void* d_out, int out_size, void* d_ws, size_t ws_size,
                              hipStream_t stream) {
    const float* x   = (const float*)d_in[0];
    const int*   ei  = (const int*)d_in[1];
    const float* W1  = (const float*)d_in[2];
    const float* as1 = (const float*)d_in[3];
    const float* ad1 = (const float*)d_in[4];
    const float* b1  = (const float*)d_in[5];
    const float* W2  = (const float*)d_in[6];
    const float* as2 = (const float*)d_in[7];
    const float* ad2 = (const float*)d_in[8];
    const float* b2  = (const float*)d_in[9];

    float* out   = (float*)d_out;
    float* alpha = out + (size_t)N_NODES * C2;    // [ET, 4] final output region

    unsigned* u32    = (unsigned*)d_ws;
    unsigned* h1bf   = u32;                       // 6,400,000 u32 (50000x256 bf16)
    unsigned* xbf    = h1bf + 6400000;            // 6,400,000 u32; ALIASES out1bf
    unsigned* h2bf   = xbf + 6400000;             // 1,600,000 u32 (50000x64 bf16)
    unsigned* w1t    = h2bf + 1600000;            // 32,768 u32
    unsigned* w2t    = w1t + 32768;               // 8,192 u32
    float* a_src1    = (float*)(w2t + 8192);      // 200,000 f
    float* a_dst1    = a_src1 + 200000;           // 200,000 f
    float* a_src2    = a_dst1 + 200000;           // 50,000 f
    float* a_dst2    = a_src2 + 50000;            // 50,000 f
    int*   deg       = (int*)(a_dst2 + 50000);    // 50,000 i
    int*   offs      = deg + 50000;               // 50,001 i
    int*   cursor    = offs + 50001;              // 50,000 i
    int*   bsum      = cursor + 50000;            // 256 i + 1 pad
    int2*  csr_es    = (int2*)(bsum + 257);       // 850,000 int2 (8B-aligned)
    unsigned* out1bf = xbf;                       // alias: xbf dead after GEMM1

    const int TB = 256;
    const int EB = (ET + TB - 1) / TB;

    // --- CSR build ---
    fill_int_kernel<<<(N_NODES + TB - 1) / TB, TB, 0, stream>>>(deg, N_NODES, 0);
    hist_kernel<<<EB, TB, 0, stream>>>(ei, deg);
    scan_block_kernel<<<NSCAN_B, TB, 0, stream>>>(deg, offs, bsum);
    scan_top_kernel<<<1, TB, 0, stream>>>(bsum);
    scan_add_kernel<<<NSCAN_B, TB, 0, stream>>>(offs, cursor, bsum);
    scatter_kernel<<<EB, TB, 0, stream>>>(ei, cursor, csr_es);

    // --- converts ---
    f32_to_bf16_kernel<<<(3200000 + TB - 1) / TB, TB, 0, stream>>>(
        x, (unsigned short*)xbf, 3200000);
    w1_transpose_kernel<<<(65536 + TB - 1) / TB, TB, 0, stream>>>(W1, (unsigned short*)w1t);
    w2_transpose_pad_kernel<<<(16384 + TB - 1) / TB, TB, 0, stream>>>(W2, (unsigned short*)w2t);

    // --- layer 1 ---
    gemm_mfma_kernel<128, 128, 2, 2><<<dim3((N_NODES + 127) / 128, 2), TB, 0, stream>>>(
        (const unsigned short*)xbf, (const unsigned short*)w1t, (unsigned short*)h1bf,
        as1, ad1, a_src1, a_dst1, N_NODES, HC1, 256, H1);
    l1_fused_kernel<<<N_NODES, TB, 0, stream>>>(offs, csr_es, a_src1, a_dst1,
                                                h1bf, b1, alpha, out1bf);

    // --- layer 2 ---
    gemm_mfma_kernel<256, 64, 4, 1><<<dim3((N_NODES + 255) / 256, 1), TB, 0, stream>>>(
        (const unsigned short*)out1bf, (const unsigned short*)w2t, (unsigned short*)h2bf,
        as2, ad2, a_src2, a_dst2, N_NODES, C2P, C2, 1);
    l2_fused_kernel<<<(N_NODES + 3) / 4, TB, 0, stream>>>(offs, csr_es, a_src2, a_dst2,
                                                          h2bf, b2, out);
}

// Round 10
// 381.997 us; speedup vs baseline: 3.5272x; 1.0843x over previous
//
#include <hip/hip_runtime.h>
#include <math.h>

#define N_NODES 50000
#define HC1 256      // 4 heads * 64 ch
#define H1 4
#define C2 40
#define C2P 64       // padded
#define E0 800000
#define ET 850000
#define NEG_SLOPE 0.2f
#define EPS_A 1e-16f

typedef __bf16 bf16x8 __attribute__((ext_vector_type(8)));
typedef float f32x4 __attribute__((ext_vector_type(4)));
typedef unsigned short u16x8 __attribute__((ext_vector_type(8)));

// ---------------- bf16 helpers (RNE) ----------------

__device__ inline unsigned short f2bf(float f) {
    unsigned u = __float_as_uint(f);
    return (unsigned short)((u + 0x7FFFu + ((u >> 16) & 1u)) >> 16);
}
__device__ inline float bf_lo(unsigned q) { return __uint_as_float(q << 16); }
__device__ inline float bf_hi(unsigned q) { return __uint_as_float(q & 0xFFFF0000u); }

// ---------------- utility ----------------

__global__ void fill_int_kernel(int* __restrict__ p, int n, int v) {
    int i = blockIdx.x * blockDim.x + threadIdx.x;
    if (i < n) p[i] = v;
}

__device__ inline int edge_src(const int* __restrict__ ei, int e) {
    return (e < E0) ? ei[e] : (e - E0);
}
__device__ inline int edge_dst(const int* __restrict__ ei, int e) {
    return (e < E0) ? ei[E0 + e] : (e - E0);
}

// ---------------- merged converts: x -> bf16, W1^T -> bf16, W2^T(padded) -> bf16 -------

#define CV_X 3200000          // float4 groups of x
#define CV_W1 65536
#define CV_W2 16384

__global__ void convert_all_kernel(const float* __restrict__ x,
                                   const float* __restrict__ W1,
                                   const float* __restrict__ W2,
                                   ushort4* __restrict__ xbf,
                                   unsigned short* __restrict__ w1t,
                                   unsigned short* __restrict__ w2t) {
    int tid = blockIdx.x * blockDim.x + threadIdx.x;
    if (tid < CV_X) {
        float4 v = ((const float4*)x)[tid];
        ushort4 w;
        w.x = f2bf(v.x); w.y = f2bf(v.y); w.z = f2bf(v.z); w.w = f2bf(v.w);
        xbf[tid] = w;
    } else if (tid < CV_X + CV_W1) {
        int i = tid - CV_X;
        int n = i >> 8, k = i & 255;
        w1t[i] = f2bf(W1[k * 256 + n]);
    } else if (tid < CV_X + CV_W1 + CV_W2) {
        int i = tid - CV_X - CV_W1;
        int n = i >> 8, k = i & 255;
        w2t[i] = (n < C2) ? f2bf(W2[k * C2 + n]) : (unsigned short)0;
    }
}

// ---------------- CSR build ----------------

__global__ void hist_kernel(const int* __restrict__ ei, int* __restrict__ deg) {
    int e = blockIdx.x * blockDim.x + threadIdx.x;
    if (e >= ET) return;
    atomicAdd(&deg[edge_dst(ei, e)], 1);
}

__global__ __launch_bounds__(256) void scan_block_kernel(const int* __restrict__ deg,
                                                         int* __restrict__ excl,
                                                         int* __restrict__ bsum) {
    __shared__ int tmp[256];
    int t = threadIdx.x;
    int i = blockIdx.x * 256 + t;
    int v = (i < N_NODES) ? deg[i] : 0;
    tmp[t] = v;
    __syncthreads();
#pragma unroll
    for (int o = 1; o < 256; o <<= 1) {
        int x = (t >= o) ? tmp[t - o] : 0;
        __syncthreads();
        tmp[t] += x;
        __syncthreads();
    }
    if (i < N_NODES) excl[i] = tmp[t] - v;
    if (t == 255) bsum[blockIdx.x] = tmp[255];
}

#define NSCAN_B 196   // ceil(50000/256)

__global__ __launch_bounds__(256) void scan_top_kernel(int* __restrict__ bsum) {
    __shared__ int tmp[256];
    int t = threadIdx.x;
    int v = (t < NSCAN_B) ? bsum[t] : 0;
    tmp[t] = v;
    __syncthreads();
#pragma unroll
    for (int o = 1; o < 256; o <<= 1) {
        int x = (t >= o) ? tmp[t - o] : 0;
        __syncthreads();
        tmp[t] += x;
        __syncthreads();
    }
    if (t < NSCAN_B) bsum[t] = tmp[t] - v;   // exclusive
}

__global__ __launch_bounds__(256) void scan_add_kernel(int* __restrict__ offsets,
                                                       int* __restrict__ cursor,
                                                       const int* __restrict__ bsum) {
    int i = blockIdx.x * 256 + threadIdx.x;
    if (i < N_NODES) {
        int v = offsets[i] + bsum[blockIdx.x];
        offsets[i] = v;
        cursor[i] = v;
    }
    if (i == 0) offsets[N_NODES] = ET;
}

// writes (edge id, src id) as one int2 in CSR order
__global__ void scatter_kernel(const int* __restrict__ ei, int* __restrict__ cursor,
                               int2* __restrict__ csr_es) {
    int e = blockIdx.x * blockDim.x + threadIdx.x;
    if (e >= ET) return;
    int d = edge_dst(ei, e);
    int pos = atomicAdd(&cursor[d], 1);
    csr_es[pos] = make_int2(e, edge_src(ei, e));
}

// ---------------- MFMA GEMM + attention-dot epilogue ----------------
// Cbf[M,Nc] = bf16( Abf[M,256] * Bt[Nc,256]^T ); K = 256.
// Epilogue: a_src_o[row*hstride+head] = sum_col acc*att_s[col] (head = wave col-base/64).
// Wave tile 64x64 (4x4 of 16x16x32 mfma). LDS stride 40 bf16 -> 2-way aliasing (free).

template <int TBM, int TBN, int WROWS, int WCOLS>
__global__ __launch_bounds__(256) void gemm_mfma_kernel(const unsigned short* __restrict__ Abf,
                                                        const unsigned short* __restrict__ Bt,
                                                        unsigned short* __restrict__ Cbf,
                                                        const float* __restrict__ att_s,
                                                        const float* __restrict__ att_d,
                                                        float* __restrict__ a_src_o,
                                                        float* __restrict__ a_dst_o,
                                                        int M, int Nc, int attN, int hstride) {
    static_assert(TBM == WROWS * 64 && TBN == WCOLS * 64, "tile");
    constexpr int LDK = 40;
    __shared__ alignas(16) unsigned short As[TBM * LDK];
    __shared__ alignas(16) unsigned short Bs[TBN * LDK];
    const int t = threadIdx.x;
    const int lane = t & 63;
    const int w = t >> 6;
    const int quad = lane >> 4;
    const int l16 = lane & 15;
    const int wm = (w / WCOLS) * 64;
    const int wn = (w % WCOLS) * 64;
    const int bm = blockIdx.x * TBM;
    const int bn = blockIdx.y * TBN;

    f32x4 acc[4][4] = {};

    for (int k0 = 0; k0 < 256; k0 += 32) {
        __syncthreads();
#pragma unroll
        for (int i = 0; i < TBM / 64; ++i) {
            int idx = t + i * 256;
            int row = idx >> 2, seg = idx & 3;
            u16x8 v = {};
            if (bm + row < M)
                v = *(const u16x8*)(Abf + (size_t)(bm + row) * 256 + k0 + seg * 8);
            *(u16x8*)&As[row * LDK + seg * 8] = v;
        }
#pragma unroll
        for (int i = 0; i < TBN / 64; ++i) {
            int idx = t + i * 256;
            int row = idx >> 2, seg = idx & 3;
            u16x8 v = *(const u16x8*)(Bt + (size_t)(bn + row) * 256 + k0 + seg * 8);
            *(u16x8*)&Bs[row * LDK + seg * 8] = v;
        }
        __syncthreads();

        bf16x8 af[4], bfr[4];
#pragma unroll
        for (int mi = 0; mi < 4; ++mi)
            af[mi] = *(const bf16x8*)&As[(wm + mi * 16 + l16) * LDK + quad * 8];
#pragma unroll
        for (int ni = 0; ni < 4; ++ni)
            bfr[ni] = *(const bf16x8*)&Bs[(wn + ni * 16 + l16) * LDK + quad * 8];
#pragma unroll
        for (int mi = 0; mi < 4; ++mi)
#pragma unroll
            for (int ni = 0; ni < 4; ++ni)
                acc[mi][ni] = __builtin_amdgcn_mfma_f32_16x16x32_bf16(
                    af[mi], bfr[ni], acc[mi][ni], 0, 0, 0);
    }

    // C/D layout: col = lane&15, row = quad*4 + r
#pragma unroll
    for (int mi = 0; mi < 4; ++mi)
#pragma unroll
        for (int ni = 0; ni < 4; ++ni)
#pragma unroll
            for (int r = 0; r < 4; ++r) {
                int row = bm + wm + mi * 16 + quad * 4 + r;
                int col = bn + wn + ni * 16 + l16;
                if (row < M)
                    Cbf[(size_t)row * Nc + col] = f2bf(acc[mi][ni][r]);
            }

    // ---- attention-dot epilogue ----
    float asc[4], adc[4];
#pragma unroll
    for (int ni = 0; ni < 4; ++ni) {
        int col = bn + wn + ni * 16 + l16;
        bool valid = col < attN;
        asc[ni] = valid ? att_s[col] : 0.f;
        adc[ni] = valid ? att_d[col] : 0.f;
    }
    float vs[16], vd[16];
#pragma unroll
    for (int mi = 0; mi < 4; ++mi)
#pragma unroll
        for (int r = 0; r < 4; ++r) {
            float s = 0.f, dd = 0.f;
#pragma unroll
            for (int ni = 0; ni < 4; ++ni) {
                s += acc[mi][ni][r] * asc[ni];
                dd += acc[mi][ni][r] * adc[ni];
            }
            vs[mi * 4 + r] = s;
            vd[mi * 4 + r] = dd;
        }
    // butterfly all-reduce across l16: lane l16 ends holding row i = l16 (i = mi*4+r)
#pragma unroll
    for (int k = 0; k < 4; ++k) {
        const int o = 1 << k;
        const int b = (l16 >> k) & 1;
#pragma unroll
        for (int j = 0; j < (8 >> k); ++j) {
            float lo = vs[2 * j], hi = vs[2 * j + 1];
            float keep = b ? hi : lo, send = b ? lo : hi;
            vs[j] = keep + __shfl_xor(send, o);
            lo = vd[2 * j]; hi = vd[2 * j + 1];
            keep = b ? hi : lo; send = b ? lo : hi;
            vd[j] = keep + __shfl_xor(send, o);
        }
    }
    {
        int mi = l16 >> 2, r = l16 & 3;
        int row = bm + wm + mi * 16 + quad * 4 + r;
        int head = (bn + wn) >> 6;
        if (row < M) {
            a_src_o[(size_t)row * hstride + head] = vs[0];
            a_dst_o[(size_t)row * hstride + head] = vd[0];
        }
    }
}

// ---------------- layer 1 fused: wave-per-dst softmax (4 heads) + aggregation ----------
// Wave = one dst (4/block). Lane j = edge j: one float4 a_src load covers all 4 heads.
// Capped butterfly reductions are valid ONLY within the first ceil-pow2(deg) xor-group;
// lane 0 is always in-group, so we BROADCAST lane 0's result to all 64 lanes after each
// reduction (this was the R8/R9 bug: out-of-group lanes kept mx=-INF, sum=0 -> inv=1e16).
// Alpha emitted as one float4 store per edge. (s, alpha4) staged in wave-private LDS
// (single barrier); aggregation: lane li handles channels 4li..4li+3, alpha via LDS
// broadcast. deg > 64 handled by a barrier-free shfl fallback (never taken here).

__global__ __launch_bounds__(256) void l1_fused_kernel(const int* __restrict__ off,
                                                       const int2* __restrict__ csr_es,
                                                       const float4* __restrict__ a_src4,
                                                       const float4* __restrict__ a_dst4,
                                                       const unsigned* __restrict__ h1bf,
                                                       const float* __restrict__ b1,
                                                       float4* __restrict__ alpha_out4,
                                                       unsigned* __restrict__ out1bf) {
    __shared__ int    s_w[4][64];
    __shared__ float4 a_w[4][64];
    int t = threadIdx.x;
    int w = t >> 6, lane = t & 63;
    int d = blockIdx.x * 4 + w;          // 50000 = 4*12500, always valid
    int beg = off[d], end = off[d + 1];
    int deg = end - beg;
    int nch = (deg + 63) >> 6;
    int cnt0 = min(deg, 64);
    bool act0 = lane < cnt0;
    float4 ad4 = a_dst4[d];

    // ---- pass 1: logits (chunk 0 cached in regs), 4-head max ----
    int2  es0 = make_int2(0, 0);
    float4 l0 = make_float4(-INFINITY, -INFINITY, -INFINITY, -INFINITY);
    float4 mx = l0;
    for (int cc = 0; cc < nch; ++cc) {
        int idx = beg + cc * 64 + lane;
        float4 l = make_float4(-INFINITY, -INFINITY, -INFINITY, -INFINITY);
        int2 es = make_int2(0, 0);
        if (idx < end) {
            es = csr_es[idx];
            float4 as4 = a_src4[es.y];
            l.x = as4.x + ad4.x; l.x = l.x > 0.f ? l.x : NEG_SLOPE * l.x;
            l.y = as4.y + ad4.y; l.y = l.y > 0.f ? l.y : NEG_SLOPE * l.y;
            l.z = as4.z + ad4.z; l.z = l.z > 0.f ? l.z : NEG_SLOPE * l.z;
            l.w = as4.w + ad4.w; l.w = l.w > 0.f ? l.w : NEG_SLOPE * l.w;
        }
        if (cc == 0) { es0 = es; l0 = l; }
        mx.x = fmaxf(mx.x, l.x); mx.y = fmaxf(mx.y, l.y);
        mx.z = fmaxf(mx.z, l.z); mx.w = fmaxf(mx.w, l.w);
    }
    int rdeg = cnt0;
    for (int o = 1; o < rdeg; o <<= 1) {
        mx.x = fmaxf(mx.x, __shfl_xor(mx.x, o));
        mx.y = fmaxf(mx.y, __shfl_xor(mx.y, o));
        mx.z = fmaxf(mx.z, __shfl_xor(mx.z, o));
        mx.w = fmaxf(mx.w, __shfl_xor(mx.w, o));
    }
    // broadcast lane 0's (correct) result to all lanes
    mx.x = __shfl(mx.x, 0); mx.y = __shfl(mx.y, 0);
    mx.z = __shfl(mx.z, 0); mx.w = __shfl(mx.w, 0);

    // ---- pass 2: p = exp(l - mx), 4-head sum (inactive lanes contribute 0) ----
    float4 p0 = make_float4(0.f, 0.f, 0.f, 0.f);
    if (act0) {
        p0.x = __expf(l0.x - mx.x); p0.y = __expf(l0.y - mx.y);
        p0.z = __expf(l0.z - mx.z); p0.w = __expf(l0.w - mx.w);
    }
    float4 sum = p0;
    for (int cc = 1; cc < nch; ++cc) {
        int idx = beg + cc * 64 + lane;
        if (idx < end) {
            int2 es = csr_es[idx];
            float4 as4 = a_src4[es.y];
            float4 l;
            l.x = as4.x + ad4.x; l.x = l.x > 0.f ? l.x : NEG_SLOPE * l.x;
            l.y = as4.y + ad4.y; l.y = l.y > 0.f ? l.y : NEG_SLOPE * l.y;
            l.z = as4.z + ad4.z; l.z = l.z > 0.f ? l.z : NEG_SLOPE * l.z;
            l.w = as4.w + ad4.w; l.w = l.w > 0.f ? l.w : NEG_SLOPE * l.w;
            sum.x += __expf(l.x - mx.x); sum.y += __expf(l.y - mx.y);
            sum.z += __expf(l.z - mx.z); sum.w += __expf(l.w - mx.w);
        }
    }
    for (int o = 1; o < rdeg; o <<= 1) {
        sum.x += __shfl_xor(sum.x, o);
        sum.y += __shfl_xor(sum.y, o);
        sum.z += __shfl_xor(sum.z, o);
        sum.w += __shfl_xor(sum.w, o);
    }
    sum.x = __shfl(sum.x, 0); sum.y = __shfl(sum.y, 0);
    sum.z = __shfl(sum.z, 0); sum.w = __shfl(sum.w, 0);
    float4 inv;
    inv.x = 1.f / (sum.x + EPS_A); inv.y = 1.f / (sum.y + EPS_A);
    inv.z = 1.f / (sum.z + EPS_A); inv.w = 1.f / (sum.w + EPS_A);

    // ---- chunk 0: alpha store + LDS stage ----
    float4 al0;
    al0.x = p0.x * inv.x; al0.y = p0.y * inv.y;
    al0.z = p0.z * inv.z; al0.w = p0.w * inv.w;
    if (act0) {
        alpha_out4[es0.x] = al0;
        s_w[w][lane] = es0.y;
        a_w[w][lane] = al0;
    }
    __syncthreads();   // executed unconditionally by all 4 waves, exactly once

    // ---- aggregation: lane li -> channels 4li..4li+3 (head = li>>4) ----
    int head = lane >> 4;
    int base2 = 2 * lane;
    const float* aw = (const float*)&a_w[w][0];
    float4 acc = make_float4(0.f, 0.f, 0.f, 0.f);
    int j = 0;
    for (; j + 4 <= cnt0; j += 4) {
        int s0 = s_w[w][j], s1 = s_w[w][j + 1], s2 = s_w[w][j + 2], s3 = s_w[w][j + 3];
        float A0 = aw[4 * j + head], A1 = aw[4 * j + 4 + head];
        float A2 = aw[4 * j + 8 + head], A3 = aw[4 * j + 12 + head];
        uint2 q0 = *(const uint2*)&h1bf[(size_t)s0 * 128 + base2];
        uint2 q1 = *(const uint2*)&h1bf[(size_t)s1 * 128 + base2];
        uint2 q2 = *(const uint2*)&h1bf[(size_t)s2 * 128 + base2];
        uint2 q3 = *(const uint2*)&h1bf[(size_t)s3 * 128 + base2];
        acc.x += A0 * bf_lo(q0.x) + A1 * bf_lo(q1.x) + A2 * bf_lo(q2.x) + A3 * bf_lo(q3.x);
        acc.y += A0 * bf_hi(q0.x) + A1 * bf_hi(q1.x) + A2 * bf_hi(q2.x) + A3 * bf_hi(q3.x);
        acc.z += A0 * bf_lo(q0.y) + A1 * bf_lo(q1.y) + A2 * bf_lo(q2.y) + A3 * bf_lo(q3.y);
        acc.w += A0 * bf_hi(q0.y) + A1 * bf_hi(q1.y) + A2 * bf_hi(q2.y) + A3 * bf_hi(q3.y);
    }
    for (; j < cnt0; ++j) {
        int s = s_w[w][j];
        float A = aw[4 * j + head];
        uint2 q = *(const uint2*)&h1bf[(size_t)s * 128 + base2];
        acc.x += A * bf_lo(q.x); acc.y += A * bf_hi(q.x);
        acc.z += A * bf_lo(q.y); acc.w += A * bf_hi(q.y);
    }

    // ---- rare fallback: chunks >= 1 (deg > 64), barrier-free shfl broadcast ----
    for (int cc = 1; cc < nch; ++cc) {
        int idx = beg + cc * 64 + lane;
        int ms = 0;
        float4 ma = make_float4(0.f, 0.f, 0.f, 0.f);
        if (idx < end) {
            int2 es = csr_es[idx];
            ms = es.y;
            float4 as4 = a_src4[es.y];
            float4 l;
            l.x = as4.x + ad4.x; l.x = l.x > 0.f ? l.x : NEG_SLOPE * l.x;
            l.y = as4.y + ad4.y; l.y = l.y > 0.f ? l.y : NEG_SLOPE * l.y;
            l.z = as4.z + ad4.z; l.z = l.z > 0.f ? l.z : NEG_SLOPE * l.z;
            l.w = as4.w + ad4.w; l.w = l.w > 0.f ? l.w : NEG_SLOPE * l.w;
            ma.x = __expf(l.x - mx.x) * inv.x;
            ma.y = __expf(l.y - mx.y) * inv.y;
            ma.z = __expf(l.z - mx.z) * inv.z;
            ma.w = __expf(l.w - mx.w) * inv.w;
            alpha_out4[es.x] = ma;
        }
        int cnt = min(64, deg - cc * 64);
        for (int jj = 0; jj < cnt; ++jj) {
            int s = __shfl(ms, jj);
            float h0 = __shfl(ma.x, jj), h1 = __shfl(ma.y, jj);
            float h2 = __shfl(ma.z, jj), h3 = __shfl(ma.w, jj);
            float A = (head & 2) ? ((head & 1) ? h3 : h2) : ((head & 1) ? h1 : h0);
            uint2 q = *(const uint2*)&h1bf[(size_t)s * 128 + base2];
            acc.x += A * bf_lo(q.x); acc.y += A * bf_hi(q.x);
            acc.z += A * bf_lo(q.y); acc.w += A * bf_hi(q.y);
        }
    }

    // ---- epilogue: bias + ELU -> bf16 packed ----
    float4 bb = *(const float4*)&b1[4 * lane];
    float v0 = acc.x + bb.x, v1 = acc.y + bb.y, v2 = acc.z + bb.z, v3 = acc.w + bb.w;
    v0 = v0 > 0.f ? v0 : __expf(v0) - 1.f;
    v1 = v1 > 0.f ? v1 : __expf(v1) - 1.f;
    v2 = v2 > 0.f ? v2 : __expf(v2) - 1.f;
    v3 = v3 > 0.f ? v3 : __expf(v3) - 1.f;
    uint2 qo;
    qo.x = ((unsigned)f2bf(v1) << 16) | (unsigned)f2bf(v0);
    qo.y = ((unsigned)f2bf(v3) << 16) | (unsigned)f2bf(v2);
    *(uint2*)&out1bf[(size_t)d * 128 + base2] = qo;
}

// ---------------- layer 2 fused: softmax + aggregation + bias + log_softmax ----------------
// Wave = one dst (4 per block). Same lane-0 broadcast fix after capped reductions:
// inv is consumed by ALL lanes (lane = channel owner), so out-of-group lanes must not
// keep their partial sum=0 -> inv=1e16 (the R9 bug: garbage on classes 32..39 for
// deg<=16 nodes).

__global__ __launch_bounds__(256) void l2_fused_kernel(const int* __restrict__ off,
                                                       const int2* __restrict__ csr_es,
                                                       const float* __restrict__ a_src,
                                                       const float* __restrict__ a_dst,
                                                       const unsigned* __restrict__ h2bf,
                                                       const float* __restrict__ b2,
                                                       float* __restrict__ out) {
    int t = threadIdx.x;
    int lane = t & 63;
    int d = blockIdx.x * 4 + (t >> 6);
    if (d >= N_NODES) return;
    int beg = off[d], end = off[d + 1];
    int deg = end - beg;
    float ad = a_dst[d];
    int nch = (deg + 63) >> 6;

    float elc[4]; int sc[4];
    float mx = -INFINITY;
    for (int cc = 0; cc < nch; ++cc) {
        int idx = beg + cc * 64 + lane;
        float el = -INFINITY; int s = 0;
        if (idx < end) {
            int2 es = csr_es[idx];
            s = es.y;
            el = a_src[s] + ad;
            el = el > 0.f ? el : NEG_SLOPE * el;
        }
        if (cc < 4) { elc[cc] = el; sc[cc] = s; }
        mx = fmaxf(mx, el);
    }
    int rdeg = min(deg, 64);
    for (int o = 1; o < rdeg; o <<= 1) mx = fmaxf(mx, __shfl_xor(mx, o));
    mx = __shfl(mx, 0);   // broadcast correct max to all lanes

    float sum = 0.f;
    for (int cc = 0; cc < nch; ++cc) {
        int idx = beg + cc * 64 + lane;
        float p = 0.f;
        if (cc < 4) {
            p = (idx < end) ? __expf(elc[cc] - mx) : 0.f;
            elc[cc] = p;
        } else if (idx < end) {
            int2 es = csr_es[idx];
            float el = a_src[es.y] + ad;
            el = el > 0.f ? el : NEG_SLOPE * el;
            p = __expf(el - mx);
        }
        sum += p;
    }
    for (int o = 1; o < rdeg; o <<= 1) sum += __shfl_xor(sum, o);
    sum = __shfl(sum, 0); // broadcast correct sum to all lanes
    float inv = 1.f / (sum + EPS_A);

    int half = lane >> 5, li = lane & 31;
    float acc0 = 0.f, acc1 = 0.f;
    for (int cc = 0; cc < nch; ++cc) {
        int cnt = min(64, deg - cc * 64);
        int my_s; float my_a;
        if (cc < 4) {
            my_s = sc[cc];
            my_a = elc[cc];
        } else {
            int idx = beg + cc * 64 + lane;
            my_s = 0; my_a = 0.f;
            if (idx < end) {
                int2 es = csr_es[idx];
                my_s = es.y;
                float el = a_src[es.y] + ad;
                el = el > 0.f ? el : NEG_SLOPE * el;
                my_a = __expf(el - mx);
            }
        }
        for (int j = 0; j < cnt; j += 2) {
            int jj = j + half;
            int s = __shfl(my_s, jj);
            float a = __shfl(my_a, jj);
            if (jj < cnt) {
                unsigned q = h2bf[(size_t)s * 32 + li];
                acc0 += a * bf_lo(q);
                acc1 += a * bf_hi(q);
            }
        }
    }
    acc0 += __shfl_xor(acc0, 32);
    acc1 += __shfl_xor(acc1, 32);
    acc0 *= inv;
    acc1 *= inv;
    bool act = li < 20;
    float v0 = act ? acc0 + b2[2 * li]     : -INFINITY;
    float v1 = act ? acc1 + b2[2 * li + 1] : -INFINITY;
    float mmx = fmaxf(v0, v1);
#pragma unroll
    for (int o = 16; o; o >>= 1) mmx = fmaxf(mmx, __shfl_xor(mmx, o));
    float ex = act ? __expf(v0 - mmx) + __expf(v1 - mmx) : 0.f;
#pragma unroll
    for (int o = 16; o; o >>= 1) ex += __shfl_xor(ex, o);
    float ls = __logf(ex);
    if (act && half == 0)
        *(float2*)&out[(size_t)d * C2 + 2 * li] = make_float2(v0 - mmx - ls, v1 - mmx - ls);
}

// ---------------- launcher ----------------

extern "C" void kernel_launch(void* const* d_in, const int* in_sizes, int n_in,
                              void* d_out, int out_size, void* d_ws, size_t ws_size,
                              hipStream_t stream) {
    const float* x   = (const float*)d_in[0];
    const int*   ei  = (const int*)d_in[1];
    const float* W1  = (const float*)d_in[2];
    const float* as1 = (const float*)d_in[3];
    const float* ad1 = (const float*)d_in[4];
    const float* b1  = (const float*)d_in[5];
    const float* W2  = (const float*)d_in[6];
    const float* as2 = (const float*)d_in[7];
    const float* ad2 = (const float*)d_in[8];
    const float* b2  = (const float*)d_in[9];

    float* out   = (float*)d_out;
    float* alpha = out + (size_t)N_NODES * C2;    // [ET, 4] final output region

    unsigned* u32    = (unsigned*)d_ws;
    unsigned* h1bf   = u32;                       // 6,400,000 u32 (50000x256 bf16)
    unsigned* xbf    = h1bf + 6400000;            // 6,400,000 u32; ALIASES out1bf
    unsigned* h2bf   = xbf + 6400000;             // 1,600,000 u32 (50000x64 bf16)
    unsigned* w1t    = h2bf + 1600000;            // 32,768 u32
    unsigned* w2t    = w1t + 32768;               // 8,192 u32
    float* a_src1    = (float*)(w2t + 8192);      // 200,000 f (16B-aligned)
    float* a_dst1    = a_src1 + 200000;           // 200,000 f
    float* a_src2    = a_dst1 + 200000;           // 50,000 f
    float* a_dst2    = a_src2 + 50000;            // 50,000 f
    int*   deg       = (int*)(a_dst2 + 50000);    // 50,000 i
    int*   offs      = deg + 50000;               // 50,001 i
    int*   cursor    = offs + 50001;              // 50,000 i
    int*   bsum      = cursor + 50000;            // 256 i + 1 pad
    int2*  csr_es    = (int2*)(bsum + 257);       // 850,000 int2 (8B-aligned)
    unsigned* out1bf = xbf;                       // alias: xbf dead after GEMM1

    const int TB = 256;
    const int EB = (ET + TB - 1) / TB;

    // --- CSR build ---
    fill_int_kernel<<<(N_NODES + TB - 1) / TB, TB, 0, stream>>>(deg, N_NODES, 0);
    hist_kernel<<<EB, TB, 0, stream>>>(ei, deg);
    scan_block_kernel<<<NSCAN_B, TB, 0, stream>>>(deg, offs, bsum);
    scan_top_kernel<<<1, TB, 0, stream>>>(bsum);
    scan_add_kernel<<<NSCAN_B, TB, 0, stream>>>(offs, cursor, bsum);
    scatter_kernel<<<EB, TB, 0, stream>>>(ei, cursor, csr_es);

    // --- converts (merged) ---
    convert_all_kernel<<<(CV_X + CV_W1 + CV_W2 + TB - 1) / TB, TB, 0, stream>>>(
        x, W1, W2, (ushort4*)xbf, (unsigned short*)w1t, (unsigned short*)w2t);

    // --- layer 1 ---
    gemm_mfma_kernel<128, 128, 2, 2><<<dim3((N_NODES + 127) / 128, 2), TB, 0, stream>>>(
        (const unsigned short*)xbf, (const unsigned short*)w1t, (unsigned short*)h1bf,
        as1, ad1, a_src1, a_dst1, N_NODES, HC1, 256, H1);
    l1_fused_kernel<<<N_NODES / 4, TB, 0, stream>>>(offs, csr_es,
                                                    (const float4*)a_src1,
                                                    (const float4*)a_dst1,
                                                    h1bf, b1, (float4*)alpha, out1bf);

    // --- layer 2 ---
    gemm_mfma_kernel<256, 64, 4, 1><<<dim3((N_NODES + 255) / 256, 1), TB, 0, stream>>>(
        (const unsigned short*)out1bf, (const unsigned short*)w2t, (unsigned short*)h2bf,
        as2, ad2, a_src2, a_dst2, N_NODES, C2P, C2, 1);
    l2_fused_kernel<<<(N_NODES + 3) / 4, TB, 0, stream>>>(offs, csr_es, a_src2, a_dst2,
                                                          h2bf, b2, out);
}

// Round 11
// 365.914 us; speedup vs baseline: 3.6822x; 1.0440x over previous
//
#include <hip/hip_runtime.h>
#include <math.h>

#define N_NODES 50000
#define HC1 256      // 4 heads * 64 ch
#define H1 4
#define C2 40
#define C2P 64       // padded
#define E0 800000
#define ET 850000
#define NEG_SLOPE 0.2f
#define EPS_A 1e-16f

typedef __bf16 bf16x8 __attribute__((ext_vector_type(8)));
typedef float f32x4 __attribute__((ext_vector_type(4)));
typedef unsigned short u16x8 __attribute__((ext_vector_type(8)));

// ---------------- bf16 helpers (RNE) ----------------

__device__ inline unsigned short f2bf(float f) {
    unsigned u = __float_as_uint(f);
    return (unsigned short)((u + 0x7FFFu + ((u >> 16) & 1u)) >> 16);
}
__device__ inline float bf_lo(unsigned q) { return __uint_as_float(q << 16); }
__device__ inline float bf_hi(unsigned q) { return __uint_as_float(q & 0xFFFF0000u); }

// ---------------- utility ----------------

__device__ inline int edge_src(const int* __restrict__ ei, int e) {
    return (e < E0) ? ei[e] : (e - E0);
}
__device__ inline int edge_dst(const int* __restrict__ ei, int e) {
    return (e < E0) ? ei[E0 + e] : (e - E0);
}

// ------- merged prep: x -> bf16, W1^T -> bf16, W2^T(padded) -> bf16, deg = 0 -------

#define CV_X 3200000          // float4 groups of x
#define CV_W1 65536
#define CV_W2 16384
#define CV_TOT (CV_X + CV_W1 + CV_W2 + N_NODES)

__global__ void convert_all_kernel(const float* __restrict__ x,
                                   const float* __restrict__ W1,
                                   const float* __restrict__ W2,
                                   ushort4* __restrict__ xbf,
                                   unsigned short* __restrict__ w1t,
                                   unsigned short* __restrict__ w2t,
                                   int* __restrict__ deg) {
    int tid = blockIdx.x * blockDim.x + threadIdx.x;
    if (tid < CV_X) {
        float4 v = ((const float4*)x)[tid];
        ushort4 w;
        w.x = f2bf(v.x); w.y = f2bf(v.y); w.z = f2bf(v.z); w.w = f2bf(v.w);
        xbf[tid] = w;
    } else if (tid < CV_X + CV_W1) {
        int i = tid - CV_X;
        int n = i >> 8, k = i & 255;
        w1t[i] = f2bf(W1[k * 256 + n]);
    } else if (tid < CV_X + CV_W1 + CV_W2) {
        int i = tid - CV_X - CV_W1;
        int n = i >> 8, k = i & 255;
        w2t[i] = (n < C2) ? f2bf(W2[k * C2 + n]) : (unsigned short)0;
    } else if (tid < CV_TOT) {
        deg[tid - CV_X - CV_W1 - CV_W2] = 0;
    }
}

// ---------------- CSR build ----------------

__global__ void hist_kernel(const int* __restrict__ ei, int* __restrict__ deg) {
    int e = blockIdx.x * blockDim.x + threadIdx.x;
    if (e >= ET) return;
    atomicAdd(&deg[edge_dst(ei, e)], 1);
}

__global__ __launch_bounds__(256) void scan_block_kernel(const int* __restrict__ deg,
                                                         int* __restrict__ excl,
                                                         int* __restrict__ bsum) {
    __shared__ int tmp[256];
    int t = threadIdx.x;
    int i = blockIdx.x * 256 + t;
    int v = (i < N_NODES) ? deg[i] : 0;
    tmp[t] = v;
    __syncthreads();
#pragma unroll
    for (int o = 1; o < 256; o <<= 1) {
        int x = (t >= o) ? tmp[t - o] : 0;
        __syncthreads();
        tmp[t] += x;
        __syncthreads();
    }
    if (i < N_NODES) excl[i] = tmp[t] - v;
    if (t == 255) bsum[blockIdx.x] = tmp[255];
}

#define NSCAN_B 196   // ceil(50000/256)

__global__ __launch_bounds__(256) void scan_top_kernel(int* __restrict__ bsum) {
    __shared__ int tmp[256];
    int t = threadIdx.x;
    int v = (t < NSCAN_B) ? bsum[t] : 0;
    tmp[t] = v;
    __syncthreads();
#pragma unroll
    for (int o = 1; o < 256; o <<= 1) {
        int x = (t >= o) ? tmp[t - o] : 0;
        __syncthreads();
        tmp[t] += x;
        __syncthreads();
    }
    if (t < NSCAN_B) bsum[t] = tmp[t] - v;   // exclusive
}

__global__ __launch_bounds__(256) void scan_add_kernel(int* __restrict__ offsets,
                                                       int* __restrict__ cursor,
                                                       const int* __restrict__ bsum) {
    int i = blockIdx.x * 256 + threadIdx.x;
    if (i < N_NODES) {
        int v = offsets[i] + bsum[blockIdx.x];
        offsets[i] = v;
        cursor[i] = v;
    }
    if (i == 0) offsets[N_NODES] = ET;
}

// writes (edge id, src id) as one int2 in CSR order
__global__ void scatter_kernel(const int* __restrict__ ei, int* __restrict__ cursor,
                               int2* __restrict__ csr_es) {
    int e = blockIdx.x * blockDim.x + threadIdx.x;
    if (e >= ET) return;
    int d = edge_dst(ei, e);
    int pos = atomicAdd(&cursor[d], 1);
    csr_es[pos] = make_int2(e, edge_src(ei, e));
}

// ---------------- MFMA GEMM + attention-dot epilogue ----------------
// Cbf[M,Nc] = bf16( Abf[M,256] * Bt[Nc,256]^T ); K = 256.
// Epilogue: a_src_o[row*hstride+head] = sum_col acc*att_s[col] (head = wave col-base/64).
// Wave tile 64x64 (4x4 of 16x16x32 mfma). LDS stride 40 bf16 -> 2-way aliasing (free).

template <int TBM, int TBN, int WROWS, int WCOLS>
__global__ __launch_bounds__(256) void gemm_mfma_kernel(const unsigned short* __restrict__ Abf,
                                                        const unsigned short* __restrict__ Bt,
                                                        unsigned short* __restrict__ Cbf,
                                                        const float* __restrict__ att_s,
                                                        const float* __restrict__ att_d,
                                                        float* __restrict__ a_src_o,
                                                        float* __restrict__ a_dst_o,
                                                        int M, int Nc, int attN, int hstride) {
    static_assert(TBM == WROWS * 64 && TBN == WCOLS * 64, "tile");
    constexpr int LDK = 40;
    __shared__ alignas(16) unsigned short As[TBM * LDK];
    __shared__ alignas(16) unsigned short Bs[TBN * LDK];
    const int t = threadIdx.x;
    const int lane = t & 63;
    const int w = t >> 6;
    const int quad = lane >> 4;
    const int l16 = lane & 15;
    const int wm = (w / WCOLS) * 64;
    const int wn = (w % WCOLS) * 64;
    const int bm = blockIdx.x * TBM;
    const int bn = blockIdx.y * TBN;

    f32x4 acc[4][4] = {};

    for (int k0 = 0; k0 < 256; k0 += 32) {
        __syncthreads();
#pragma unroll
        for (int i = 0; i < TBM / 64; ++i) {
            int idx = t + i * 256;
            int row = idx >> 2, seg = idx & 3;
            u16x8 v = {};
            if (bm + row < M)
                v = *(const u16x8*)(Abf + (size_t)(bm + row) * 256 + k0 + seg * 8);
            *(u16x8*)&As[row * LDK + seg * 8] = v;
        }
#pragma unroll
        for (int i = 0; i < TBN / 64; ++i) {
            int idx = t + i * 256;
            int row = idx >> 2, seg = idx & 3;
            u16x8 v = *(const u16x8*)(Bt + (size_t)(bn + row) * 256 + k0 + seg * 8);
            *(u16x8*)&Bs[row * LDK + seg * 8] = v;
        }
        __syncthreads();

        bf16x8 af[4], bfr[4];
#pragma unroll
        for (int mi = 0; mi < 4; ++mi)
            af[mi] = *(const bf16x8*)&As[(wm + mi * 16 + l16) * LDK + quad * 8];
#pragma unroll
        for (int ni = 0; ni < 4; ++ni)
            bfr[ni] = *(const bf16x8*)&Bs[(wn + ni * 16 + l16) * LDK + quad * 8];
#pragma unroll
        for (int mi = 0; mi < 4; ++mi)
#pragma unroll
            for (int ni = 0; ni < 4; ++ni)
                acc[mi][ni] = __builtin_amdgcn_mfma_f32_16x16x32_bf16(
                    af[mi], bfr[ni], acc[mi][ni], 0, 0, 0);
    }

    // C/D layout: col = lane&15, row = quad*4 + r
#pragma unroll
    for (int mi = 0; mi < 4; ++mi)
#pragma unroll
        for (int ni = 0; ni < 4; ++ni)
#pragma unroll
            for (int r = 0; r < 4; ++r) {
                int row = bm + wm + mi * 16 + quad * 4 + r;
                int col = bn + wn + ni * 16 + l16;
                if (row < M)
                    Cbf[(size_t)row * Nc + col] = f2bf(acc[mi][ni][r]);
            }

    // ---- attention-dot epilogue ----
    float asc[4], adc[4];
#pragma unroll
    for (int ni = 0; ni < 4; ++ni) {
        int col = bn + wn + ni * 16 + l16;
        bool valid = col < attN;
        asc[ni] = valid ? att_s[col] : 0.f;
        adc[ni] = valid ? att_d[col] : 0.f;
    }
    float vs[16], vd[16];
#pragma unroll
    for (int mi = 0; mi < 4; ++mi)
#pragma unroll
        for (int r = 0; r < 4; ++r) {
            float s = 0.f, dd = 0.f;
#pragma unroll
            for (int ni = 0; ni < 4; ++ni) {
                s += acc[mi][ni][r] * asc[ni];
                dd += acc[mi][ni][r] * adc[ni];
            }
            vs[mi * 4 + r] = s;
            vd[mi * 4 + r] = dd;
        }
    // butterfly all-reduce across l16: lane l16 ends holding row i = l16 (i = mi*4+r)
#pragma unroll
    for (int k = 0; k < 4; ++k) {
        const int o = 1 << k;
        const int b = (l16 >> k) & 1;
#pragma unroll
        for (int j = 0; j < (8 >> k); ++j) {
            float lo = vs[2 * j], hi = vs[2 * j + 1];
            float keep = b ? hi : lo, send = b ? lo : hi;
            vs[j] = keep + __shfl_xor(send, o);
            lo = vd[2 * j]; hi = vd[2 * j + 1];
            keep = b ? hi : lo; send = b ? lo : hi;
            vd[j] = keep + __shfl_xor(send, o);
        }
    }
    {
        int mi = l16 >> 2, r = l16 & 3;
        int row = bm + wm + mi * 16 + quad * 4 + r;
        int head = (bn + wn) >> 6;
        if (row < M) {
            a_src_o[(size_t)row * hstride + head] = vs[0];
            a_dst_o[(size_t)row * hstride + head] = vd[0];
        }
    }
}

// ---------------- layer 1 fused: wave-per-dst softmax (4 heads) + aggregation ----------
// Wave = one dst (4/block). Softmax: lane j = edge j, one float4 a_src load = 4 heads.
// Capped butterflies + LANE-0 BROADCAST (out-of-group lanes hold garbage otherwise).
// Aggregation: half hf = edges j+hf (step 2); lane li = channels 8li..8li+7 via one
// uint4 (16 B) load; halves combined by shfl_xor(32). Alpha: one float4 store/edge.
// deg > 64: barrier-free shfl fallback (never taken for this graph).

__global__ __launch_bounds__(256) void l1_fused_kernel(const int* __restrict__ off,
                                                       const int2* __restrict__ csr_es,
                                                       const float4* __restrict__ a_src4,
                                                       const float4* __restrict__ a_dst4,
                                                       const unsigned* __restrict__ h1bf,
                                                       const float* __restrict__ b1,
                                                       float4* __restrict__ alpha_out4,
                                                       unsigned* __restrict__ out1bf) {
    __shared__ int    s_w[4][64];
    __shared__ float4 a_w[4][64];
    int t = threadIdx.x;
    int w = t >> 6, lane = t & 63;
    int d = blockIdx.x * 4 + w;          // 50000 = 4*12500, always valid
    int beg = off[d], end = off[d + 1];
    int deg = end - beg;
    int nch = (deg + 63) >> 6;
    int cnt0 = min(deg, 64);
    bool act0 = lane < cnt0;
    float4 ad4 = a_dst4[d];

    // ---- pass 1: logits (chunk 0 cached in regs), 4-head max ----
    int2  es0 = make_int2(0, 0);
    float4 l0 = make_float4(-INFINITY, -INFINITY, -INFINITY, -INFINITY);
    float4 mx = l0;
    for (int cc = 0; cc < nch; ++cc) {
        int idx = beg + cc * 64 + lane;
        float4 l = make_float4(-INFINITY, -INFINITY, -INFINITY, -INFINITY);
        int2 es = make_int2(0, 0);
        if (idx < end) {
            es = csr_es[idx];
            float4 as4 = a_src4[es.y];
            l.x = as4.x + ad4.x; l.x = l.x > 0.f ? l.x : NEG_SLOPE * l.x;
            l.y = as4.y + ad4.y; l.y = l.y > 0.f ? l.y : NEG_SLOPE * l.y;
            l.z = as4.z + ad4.z; l.z = l.z > 0.f ? l.z : NEG_SLOPE * l.z;
            l.w = as4.w + ad4.w; l.w = l.w > 0.f ? l.w : NEG_SLOPE * l.w;
        }
        if (cc == 0) { es0 = es; l0 = l; }
        mx.x = fmaxf(mx.x, l.x); mx.y = fmaxf(mx.y, l.y);
        mx.z = fmaxf(mx.z, l.z); mx.w = fmaxf(mx.w, l.w);
    }
    int rdeg = cnt0;
    for (int o = 1; o < rdeg; o <<= 1) {
        mx.x = fmaxf(mx.x, __shfl_xor(mx.x, o));
        mx.y = fmaxf(mx.y, __shfl_xor(mx.y, o));
        mx.z = fmaxf(mx.z, __shfl_xor(mx.z, o));
        mx.w = fmaxf(mx.w, __shfl_xor(mx.w, o));
    }
    mx.x = __shfl(mx.x, 0); mx.y = __shfl(mx.y, 0);
    mx.z = __shfl(mx.z, 0); mx.w = __shfl(mx.w, 0);

    // ---- pass 2: p = exp(l - mx), 4-head sum (inactive lanes contribute 0) ----
    float4 p0 = make_float4(0.f, 0.f, 0.f, 0.f);
    if (act0) {
        p0.x = __expf(l0.x - mx.x); p0.y = __expf(l0.y - mx.y);
        p0.z = __expf(l0.z - mx.z); p0.w = __expf(l0.w - mx.w);
    }
    float4 sum = p0;
    for (int cc = 1; cc < nch; ++cc) {
        int idx = beg + cc * 64 + lane;
        if (idx < end) {
            int2 es = csr_es[idx];
            float4 as4 = a_src4[es.y];
            float4 l;
            l.x = as4.x + ad4.x; l.x = l.x > 0.f ? l.x : NEG_SLOPE * l.x;
            l.y = as4.y + ad4.y; l.y = l.y > 0.f ? l.y : NEG_SLOPE * l.y;
            l.z = as4.z + ad4.z; l.z = l.z > 0.f ? l.z : NEG_SLOPE * l.z;
            l.w = as4.w + ad4.w; l.w = l.w > 0.f ? l.w : NEG_SLOPE * l.w;
            sum.x += __expf(l.x - mx.x); sum.y += __expf(l.y - mx.y);
            sum.z += __expf(l.z - mx.z); sum.w += __expf(l.w - mx.w);
        }
    }
    for (int o = 1; o < rdeg; o <<= 1) {
        sum.x += __shfl_xor(sum.x, o);
        sum.y += __shfl_xor(sum.y, o);
        sum.z += __shfl_xor(sum.z, o);
        sum.w += __shfl_xor(sum.w, o);
    }
    sum.x = __shfl(sum.x, 0); sum.y = __shfl(sum.y, 0);
    sum.z = __shfl(sum.z, 0); sum.w = __shfl(sum.w, 0);
    float4 inv;
    inv.x = 1.f / (sum.x + EPS_A); inv.y = 1.f / (sum.y + EPS_A);
    inv.z = 1.f / (sum.z + EPS_A); inv.w = 1.f / (sum.w + EPS_A);

    // ---- chunk 0: alpha store + LDS stage ----
    float4 al0;
    al0.x = p0.x * inv.x; al0.y = p0.y * inv.y;
    al0.z = p0.z * inv.z; al0.w = p0.w * inv.w;
    if (act0) {
        alpha_out4[es0.x] = al0;
        s_w[w][lane] = es0.y;
        a_w[w][lane] = al0;
    }
    __syncthreads();   // executed unconditionally by all 4 waves, exactly once

    // ---- aggregation: half hf -> edges j+hf; lane li -> channels 8li..8li+7 ----
    int hf = lane >> 5, li = lane & 31;
    int headc = li >> 3;
    const float* aw = (const float*)&a_w[w][0];
    float ac[8] = {};
    int j = hf;
    for (; j + 2 < cnt0; j += 4) {
        int s0 = s_w[w][j], s1 = s_w[w][j + 2];
        float A0 = aw[4 * j + headc], A1 = aw[4 * (j + 2) + headc];
        uint4 q0 = *(const uint4*)&h1bf[(size_t)s0 * 128 + 4 * li];
        uint4 q1 = *(const uint4*)&h1bf[(size_t)s1 * 128 + 4 * li];
        ac[0] += A0 * bf_lo(q0.x) + A1 * bf_lo(q1.x);
        ac[1] += A0 * bf_hi(q0.x) + A1 * bf_hi(q1.x);
        ac[2] += A0 * bf_lo(q0.y) + A1 * bf_lo(q1.y);
        ac[3] += A0 * bf_hi(q0.y) + A1 * bf_hi(q1.y);
        ac[4] += A0 * bf_lo(q0.z) + A1 * bf_lo(q1.z);
        ac[5] += A0 * bf_hi(q0.z) + A1 * bf_hi(q1.z);
        ac[6] += A0 * bf_lo(q0.w) + A1 * bf_lo(q1.w);
        ac[7] += A0 * bf_hi(q0.w) + A1 * bf_hi(q1.w);
    }
    for (; j < cnt0; j += 2) {
        int s = s_w[w][j];
        float A = aw[4 * j + headc];
        uint4 q = *(const uint4*)&h1bf[(size_t)s * 128 + 4 * li];
        ac[0] += A * bf_lo(q.x); ac[1] += A * bf_hi(q.x);
        ac[2] += A * bf_lo(q.y); ac[3] += A * bf_hi(q.y);
        ac[4] += A * bf_lo(q.z); ac[5] += A * bf_hi(q.z);
        ac[6] += A * bf_lo(q.w); ac[7] += A * bf_hi(q.w);
    }

    // ---- rare fallback: chunks >= 1 (deg > 64), split by half (no double count) ----
    for (int cc = 1; cc < nch; ++cc) {
        int idx = beg + cc * 64 + lane;
        int ms = 0;
        float4 ma = make_float4(0.f, 0.f, 0.f, 0.f);
        if (idx < end) {
            int2 es = csr_es[idx];
            ms = es.y;
            float4 as4 = a_src4[es.y];
            float4 l;
            l.x = as4.x + ad4.x; l.x = l.x > 0.f ? l.x : NEG_SLOPE * l.x;
            l.y = as4.y + ad4.y; l.y = l.y > 0.f ? l.y : NEG_SLOPE * l.y;
            l.z = as4.z + ad4.z; l.z = l.z > 0.f ? l.z : NEG_SLOPE * l.z;
            l.w = as4.w + ad4.w; l.w = l.w > 0.f ? l.w : NEG_SLOPE * l.w;
            ma.x = __expf(l.x - mx.x) * inv.x;
            ma.y = __expf(l.y - mx.y) * inv.y;
            ma.z = __expf(l.z - mx.z) * inv.z;
            ma.w = __expf(l.w - mx.w) * inv.w;
            alpha_out4[es.x] = ma;
        }
        int cnt = min(64, deg - cc * 64);
        for (int jj = hf; jj < cnt; jj += 2) {
            int s = __shfl(ms, jj);
            float h0 = __shfl(ma.x, jj), h1v = __shfl(ma.y, jj);
            float h2v = __shfl(ma.z, jj), h3 = __shfl(ma.w, jj);
            float A = (headc & 2) ? ((headc & 1) ? h3 : h2v) : ((headc & 1) ? h1v : h0);
            uint4 q = *(const uint4*)&h1bf[(size_t)s * 128 + 4 * li];
            ac[0] += A * bf_lo(q.x); ac[1] += A * bf_hi(q.x);
            ac[2] += A * bf_lo(q.y); ac[3] += A * bf_hi(q.y);
            ac[4] += A * bf_lo(q.z); ac[5] += A * bf_hi(q.z);
            ac[6] += A * bf_lo(q.w); ac[7] += A * bf_hi(q.w);
        }
    }

    // ---- combine halves + epilogue: bias + ELU -> bf16 packed ----
#pragma unroll
    for (int c = 0; c < 8; ++c) ac[c] += __shfl_xor(ac[c], 32);
    if (hf == 0) {
        float4 bb0 = *(const float4*)&b1[8 * li];
        float4 bb1 = *(const float4*)&b1[8 * li + 4];
        float v0 = ac[0] + bb0.x, v1 = ac[1] + bb0.y;
        float v2 = ac[2] + bb0.z, v3 = ac[3] + bb0.w;
        float v4 = ac[4] + bb1.x, v5 = ac[5] + bb1.y;
        float v6 = ac[6] + bb1.z, v7 = ac[7] + bb1.w;
        v0 = v0 > 0.f ? v0 : __expf(v0) - 1.f;
        v1 = v1 > 0.f ? v1 : __expf(v1) - 1.f;
        v2 = v2 > 0.f ? v2 : __expf(v2) - 1.f;
        v3 = v3 > 0.f ? v3 : __expf(v3) - 1.f;
        v4 = v4 > 0.f ? v4 : __expf(v4) - 1.f;
        v5 = v5 > 0.f ? v5 : __expf(v5) - 1.f;
        v6 = v6 > 0.f ? v6 : __expf(v6) - 1.f;
        v7 = v7 > 0.f ? v7 : __expf(v7) - 1.f;
        uint4 qo;
        qo.x = ((unsigned)f2bf(v1) << 16) | (unsigned)f2bf(v0);
        qo.y = ((unsigned)f2bf(v3) << 16) | (unsigned)f2bf(v2);
        qo.z = ((unsigned)f2bf(v5) << 16) | (unsigned)f2bf(v4);
        qo.w = ((unsigned)f2bf(v7) << 16) | (unsigned)f2bf(v6);
        *(uint4*)&out1bf[(size_t)d * 128 + 4 * li] = qo;
    }
}

// ---------------- layer 2 fused: softmax + aggregation + bias + log_softmax ----------------
// Wave = one dst (4/block; 12500*4 = N exactly, no bounds check). Pass 1: max (+lane-0
// broadcast). Pass 2 MERGED with aggregation: unnormalized p staged in wave-private LDS
// (no barrier needed - same-wave DS ops are in-order), aggregation accumulates p*h,
// sum reduced once after the loop, normalization applied to acc at the end.

__global__ __launch_bounds__(256) void l2_fused_kernel(const int* __restrict__ off,
                                                       const int2* __restrict__ csr_es,
                                                       const float* __restrict__ a_src,
                                                       const float* __restrict__ a_dst,
                                                       const unsigned* __restrict__ h2bf,
                                                       const float* __restrict__ b2,
                                                       float* __restrict__ out) {
    __shared__ uint2 sp_w[4][64];
    int t = threadIdx.x;
    int w = t >> 6, lane = t & 63;
    int d = blockIdx.x * 4 + w;
    int beg = off[d], end = off[d + 1];
    int deg = end - beg;
    float ad = a_dst[d];
    int nch = (deg + 63) >> 6;
    int rdeg = min(deg, 64);

    // ---- pass 1: max (chunk 0 logit + src cached in regs) ----
    int s0r = 0; float el0 = -INFINITY;
    float mx = -INFINITY;
    for (int cc = 0; cc < nch; ++cc) {
        int idx = beg + cc * 64 + lane;
        float el = -INFINITY; int s = 0;
        if (idx < end) {
            int2 es = csr_es[idx];
            s = es.y;
            el = a_src[s] + ad;
            el = el > 0.f ? el : NEG_SLOPE * el;
        }
        if (cc == 0) { el0 = el; s0r = s; }
        mx = fmaxf(mx, el);
    }
    for (int o = 1; o < rdeg; o <<= 1) mx = fmaxf(mx, __shfl_xor(mx, o));
    mx = __shfl(mx, 0);   // broadcast correct max to all lanes

    // ---- pass 2 + aggregation (unnormalized p) ----
    int hf = lane >> 5, li = lane & 31;
    float sum = 0.f, acc0 = 0.f, acc1 = 0.f;
    for (int cc = 0; cc < nch; ++cc) {
        int cnt = min(64, deg - cc * 64);
        float p = 0.f; int s = 0;
        if (cc == 0) {
            s = s0r;
            p = (lane < cnt) ? __expf(el0 - mx) : 0.f;
        } else {
            int idx = beg + cc * 64 + lane;
            if (idx < end) {
                int2 es = csr_es[idx];
                s = es.y;
                float el = a_src[s] + ad;
                el = el > 0.f ? el : NEG_SLOPE * el;
                p = __expf(el - mx);
            }
        }
        sum += p;
        if (lane < cnt) sp_w[w][lane] = make_uint2((unsigned)s, __float_as_uint(p));
        // wave-private LDS; same-wave DS ops in order - no barrier
        int j = hf;
        for (; j + 2 < cnt; j += 4) {
            uint2 e0 = sp_w[w][j], e1 = sp_w[w][j + 2];
            float A0 = __uint_as_float(e0.y), A1 = __uint_as_float(e1.y);
            unsigned q0 = h2bf[(size_t)e0.x * 32 + li];
            unsigned q1 = h2bf[(size_t)e1.x * 32 + li];
            acc0 += A0 * bf_lo(q0) + A1 * bf_lo(q1);
            acc1 += A0 * bf_hi(q0) + A1 * bf_hi(q1);
        }
        for (; j < cnt; j += 2) {
            uint2 e0 = sp_w[w][j];
            float A0 = __uint_as_float(e0.y);
            unsigned q = h2bf[(size_t)e0.x * 32 + li];
            acc0 += A0 * bf_lo(q);
            acc1 += A0 * bf_hi(q);
        }
    }
    for (int o = 1; o < rdeg; o <<= 1) sum += __shfl_xor(sum, o);
    sum = __shfl(sum, 0); // broadcast correct sum to all lanes
    float inv = 1.f / (sum + EPS_A);

    acc0 += __shfl_xor(acc0, 32);
    acc1 += __shfl_xor(acc1, 32);
    acc0 *= inv;
    acc1 *= inv;
    bool act = li < 20;
    float v0 = act ? acc0 + b2[2 * li]     : -INFINITY;
    float v1 = act ? acc1 + b2[2 * li + 1] : -INFINITY;
    float mmx = fmaxf(v0, v1);
#pragma unroll
    for (int o = 16; o; o >>= 1) mmx = fmaxf(mmx, __shfl_xor(mmx, o));
    float ex = act ? __expf(v0 - mmx) + __expf(v1 - mmx) : 0.f;
#pragma unroll
    for (int o = 16; o; o >>= 1) ex += __shfl_xor(ex, o);
    float ls = __logf(ex);
    if (act && hf == 0)
        *(float2*)&out[(size_t)d * C2 + 2 * li] = make_float2(v0 - mmx - ls, v1 - mmx - ls);
}

// ---------------- launcher ----------------

extern "C" void kernel_launch(void* const* d_in, const int* in_sizes, int n_in,
                              void* d_out, int out_size, void* d_ws, size_t ws_size,
                              hipStream_t stream) {
    const float* x   = (const float*)d_in[0];
    const int*   ei  = (const int*)d_in[1];
    const float* W1  = (const float*)d_in[2];
    const float* as1 = (const float*)d_in[3];
    const float* ad1 = (const float*)d_in[4];
    const float* b1  = (const float*)d_in[5];
    const float* W2  = (const float*)d_in[6];
    const float* as2 = (const float*)d_in[7];
    const float* ad2 = (const float*)d_in[8];
    const float* b2  = (const float*)d_in[9];

    float* out   = (float*)d_out;
    float* alpha = out + (size_t)N_NODES * C2;    // [ET, 4] final output region

    unsigned* u32    = (unsigned*)d_ws;
    unsigned* h1bf   = u32;                       // 6,400,000 u32 (50000x256 bf16)
    unsigned* xbf    = h1bf + 6400000;            // 6,400,000 u32; ALIASES out1bf
    unsigned* h2bf   = xbf + 6400000;             // 1,600,000 u32 (50000x64 bf16)
    unsigned* w1t    = h2bf + 1600000;            // 32,768 u32
    unsigned* w2t    = w1t + 32768;               // 8,192 u32
    float* a_src1    = (float*)(w2t + 8192);      // 200,000 f (16B-aligned)
    float* a_dst1    = a_src1 + 200000;           // 200,000 f
    float* a_src2    = a_dst1 + 200000;           // 50,000 f
    float* a_dst2    = a_src2 + 50000;            // 50,000 f
    int*   deg       = (int*)(a_dst2 + 50000);    // 50,000 i
    int*   offs      = deg + 50000;               // 50,001 i
    int*   cursor    = offs + 50001;              // 50,000 i
    int*   bsum      = cursor + 50000;            // 256 i + 1 pad
    int2*  csr_es    = (int2*)(bsum + 257);       // 850,000 int2 (8B-aligned)
    unsigned* out1bf = xbf;                       // alias: xbf dead after GEMM1

    const int TB = 256;
    const int EB = (ET + TB - 1) / TB;

    // --- converts + deg zeroing (merged) ---
    convert_all_kernel<<<(CV_TOT + TB - 1) / TB, TB, 0, stream>>>(
        x, W1, W2, (ushort4*)xbf, (unsigned short*)w1t, (unsigned short*)w2t, deg);

    // --- CSR build ---
    hist_kernel<<<EB, TB, 0, stream>>>(ei, deg);
    scan_block_kernel<<<NSCAN_B, TB, 0, stream>>>(deg, offs, bsum);
    scan_top_kernel<<<1, TB, 0, stream>>>(bsum);
    scan_add_kernel<<<NSCAN_B, TB, 0, stream>>>(offs, cursor, bsum);
    scatter_kernel<<<EB, TB, 0, stream>>>(ei, cursor, csr_es);

    // --- layer 1 ---
    gemm_mfma_kernel<128, 128, 2, 2><<<dim3((N_NODES + 127) / 128, 2), TB, 0, stream>>>(
        (const unsigned short*)xbf, (const unsigned short*)w1t, (unsigned short*)h1bf,
        as1, ad1, a_src1, a_dst1, N_NODES, HC1, 256, H1);
    l1_fused_kernel<<<N_NODES / 4, TB, 0, stream>>>(offs, csr_es,
                                                    (const float4*)a_src1,
                                                    (const float4*)a_dst1,
                                                    h1bf, b1, (float4*)alpha, out1bf);

    // --- layer 2 ---
    gemm_mfma_kernel<256, 64, 4, 1><<<dim3((N_NODES + 255) / 256, 1), TB, 0, stream>>>(
        (const unsigned short*)out1bf, (const unsigned short*)w2t, (unsigned short*)h2bf,
        as2, ad2, a_src2, a_dst2, N_NODES, C2P, C2, 1);
    l2_fused_kernel<<<(N_NODES + 3) / 4, TB, 0, stream>>>(offs, csr_es, a_src2, a_dst2,
                                                          h2bf, b2, out);
}